// Round 17
// baseline (83.363 us; speedup 1.0000x reference)
//
#include <hip/hip_runtime.h>
#include <hip/hip_bf16.h>

#define SLEN 2048
#define DMODEL 1024
#define NHEAD 8
#define DHEAD 128
#define BM 64
#define BKT 64
#define QSCALE 0.08838834764831845f  // 1/sqrt(128)

typedef __attribute__((ext_vector_type(4))) float f32x4;
typedef __attribute__((ext_vector_type(8))) _Float16 f16x8;
typedef __attribute__((ext_vector_type(4))) _Float16 f16x4;
typedef __attribute__((ext_vector_type(2))) _Float16 f16x2;

static __device__ __forceinline__ int pk16(float a, float b) {
  f16x2 t; t[0] = (_Float16)a; t[1] = (_Float16)b;
  union { f16x2 h; int i; } u; u.h = t; return u.i;
}
static __device__ __forceinline__ unsigned short f16bits(float x) {
  union { _Float16 h; unsigned short u; } u2; u2.h = (_Float16)x; return u2.u;
}

// ---------------- Kernel 1: gate preactivations via MFMA (R16, verified) ----
__global__ __launch_bounds__(512)
void gates_kernel(const float* __restrict__ q, const float* __restrict__ k,
                  const float* __restrict__ v, const float* __restrict__ igw,
                  const float* __restrict__ fgw, float* __restrict__ gpre) {
  __shared__ float red[8][16][16];
  const int row0 = blockIdx.x * 16;
  const int tid = threadIdx.x;
  const int lane = tid & 63, wid = tid >> 6;
  const int l15 = lane & 15, lg = lane >> 4;
  const f32x4 z4 = {0.f, 0.f, 0.f, 0.f};
  f32x4 acc = z4;
  const float* wbase = (l15 < 8) ? (igw + (size_t)l15 * 3072)
                                 : (fgw + (size_t)(l15 - 8) * 3072);
  #pragma unroll
  for (int ks = 0; ks < 12; ++ks) {
    const int kk = wid * 384 + ks * 32 + lg * 8;   // lane k base
    const int seg = kk >> 10;
    const int col = kk & 1023;
    const float* src = (seg == 0) ? q : (seg == 1) ? k : v;
    const float* xp = src + (size_t)(row0 + l15) * 1024 + col;
    f32x4 a0 = *(const f32x4*)xp;
    f32x4 a1 = *(const f32x4*)(xp + 4);
    f32x4 b0 = *(const f32x4*)(wbase + kk);
    f32x4 b1 = *(const f32x4*)(wbase + kk + 4);
    f16x8 ah, al, bhf, blf;
    #pragma unroll
    for (int e = 0; e < 4; ++e) {
      _Float16 h0 = (_Float16)a0[e], h1 = (_Float16)a1[e];
      ah[e] = h0; ah[e + 4] = h1;
      al[e] = (_Float16)(a0[e] - (float)h0);
      al[e + 4] = (_Float16)(a1[e] - (float)h1);
      _Float16 g0 = (_Float16)b0[e], g1 = (_Float16)b1[e];
      bhf[e] = g0; bhf[e + 4] = g1;
      blf[e] = (_Float16)(b0[e] - (float)g0);
      blf[e + 4] = (_Float16)(b1[e] - (float)g1);
    }
    acc = __builtin_amdgcn_mfma_f32_16x16x32_f16(ah, bhf, acc, 0, 0, 0);
    acc = __builtin_amdgcn_mfma_f32_16x16x32_f16(al, bhf, acc, 0, 0, 0);
    acc = __builtin_amdgcn_mfma_f32_16x16x32_f16(ah, blf, acc, 0, 0, 0);
  }
  #pragma unroll
  for (int r = 0; r < 4; ++r)
    red[wid][lg * 4 + r][l15] = acc[r];
  __syncthreads();
  if (tid < 256) {
    const int xrow = tid >> 4, g = tid & 15;
    float s = 0.f;
    #pragma unroll
    for (int w = 0; w < 8; ++w) s += red[w][xrow][g];
    gpre[(size_t)g * 4096 + row0 + xrow] = s;
  }
}

// ---------------- Kernel 2: scans + chunk maxima (64 and 128) ---------------
__global__ __launch_bounds__(256)
void scan_kernel(const float* __restrict__ gpre, const float* __restrict__ igb,
                 const float* __restrict__ fgb, float* __restrict__ a_out,
                 float* __restrict__ ms_out, float* __restrict__ fl_out,
                 float* __restrict__ mt64, float* __restrict__ mt128,
                 float* __restrict__ Mg_out) {
  const int bh = blockIdx.x;
  const int h = bh & 7;
  const int b = bh >> 3;
  const int tid = threadIdx.x;
  __shared__ double sbd[256];
  __shared__ float sbf[256];
  __shared__ float mt_l[16];
  const int base = b * 2048 + tid * 8;
  const float ig_b = igb[h], fg_b = fgb[h];
  double cs[8];
  float av[8];
  double tot = 0.0;
  #pragma unroll
  for (int e = 0; e < 8; ++e) {
    float x = gpre[(size_t)(8 + h) * 4096 + base + e] + fg_b;
    float l = fminf(x, 0.f) - log1pf(__expf(-fabsf(x)));   // log_sigmoid
    tot += (double)l;
    cs[e] = tot;
  }
  sbd[tid] = tot;
  __syncthreads();
  if (tid == 0) {
    double run = 0.0;
    for (int i = 0; i < 256; ++i) { double t2 = sbd[i]; sbd[i] = run; run += t2; }
  }
  __syncthreads();
  const double excl = sbd[tid];
  float mtot = -3.4e38f;
  #pragma unroll
  for (int e = 0; e < 8; ++e) {
    cs[e] += excl;
    float ig = gpre[(size_t)h * 4096 + base + e] + ig_b;
    av[e] = (float)((double)ig - cs[e]);
    mtot = fmaxf(mtot, av[e]);
  }
  // per-64 and per-128 window maxima
  {
    float w8 = mtot;
    w8 = fmaxf(w8, __shfl_xor(w8, 1));
    w8 = fmaxf(w8, __shfl_xor(w8, 2));
    w8 = fmaxf(w8, __shfl_xor(w8, 4));
    if ((tid & 7) == 0) mt64[bh * 32 + (tid >> 3)] = w8;
    float w16 = fmaxf(w8, __shfl_xor(w8, 8));
    if ((tid & 15) == 0) { mt128[bh * 16 + (tid >> 4)] = w16; mt_l[tid >> 4] = w16; }
  }
  sbf[tid] = mtot;
  __syncthreads();
  if (tid == 0) {
    float run = -3.4e38f;
    for (int i = 0; i < 256; ++i) { float t2 = sbf[i]; sbf[i] = run; run = fmaxf(run, t2); }
    float M = -3.4e38f;
    for (int c = 0; c < 16; ++c) { Mg_out[bh * 16 + c] = M; M = fmaxf(M, mt_l[c]); }
  }
  __syncthreads();
  float run = sbf[tid];
  const int obase = bh * 2048 + tid * 8;
  #pragma unroll
  for (int e = 0; e < 8; ++e) {
    run = fmaxf(run, av[e]);
    a_out[obase + e] = av[e];
    ms_out[obase + e] = run;
    fl_out[obase + e] = __expf(-(float)(cs[e] + (double)run));  // exp(-max_log_D)
  }
}

// ---------------- Kernel P1: per-128-chunk state G[dv][dk] (fp16) + ksum ----
__global__ __launch_bounds__(512)
void p1_kernel(const float* __restrict__ k, const float* __restrict__ v,
               const float* __restrict__ a_g, const float* __restrict__ mt128,
               unsigned short* __restrict__ GXs, float* __restrict__ pkt) {
  __shared__ __align__(16) char pool[33280];
  _Float16* Kts = (_Float16*)pool;             // [128 dk][64 j] 128B rows, swz
  _Float16* Vts = (_Float16*)(pool + 16384);   // [128 dv][64 j]
  float* w_s = (float*)(pool + 32768);         // [128]
  const int c = blockIdx.x, bh = blockIdx.y;
  const int b = bh >> 3, h = bh & 7;
  const int tid = threadIdx.x;
  const int lane = tid & 63, wid = tid >> 6;
  const int l15 = lane & 15, lg = lane >> 4;
  if (tid < 128) w_s[tid] = __expf(a_g[bh * SLEN + c * 128 + tid] - mt128[bh * 16 + c]);
  const f32x4 z4 = {0.f, 0.f, 0.f, 0.f};
  f32x4 acc[8];
  #pragma unroll
  for (int i = 0; i < 8; ++i) acc[i] = z4;
  float ks_acc = 0.f;
  for (int p = 0; p < 2; ++p) {
    const int j0 = c * 128 + p * 64;
    __syncthreads();   // w_s ready (p=0); prior pass reads done (p=1)
    {
      const int d = tid & 127;
      const int jq = tid >> 7;                 // 0..3 (16 j each)
      const size_t rowb = (size_t)(b * SLEN + j0 + jq * 16) * DMODEL + h * DHEAD + d;
      float kv[16], vv[16];
      #pragma unroll
      for (int jj = 0; jj < 16; ++jj) {
        kv[jj] = k[rowb + (size_t)jj * DMODEL] * w_s[p * 64 + jq * 16 + jj];
        vv[jj] = v[rowb + (size_t)jj * DMODEL];
      }
      int ph[8], pv[8];
      #pragma unroll
      for (int pp = 0; pp < 8; ++pp) {
        ph[pp] = pk16(kv[2 * pp], kv[2 * pp + 1]);
        pv[pp] = pk16(vv[2 * pp], vv[2 * pp + 1]);
      }
      const int sw = (d & 7) << 4;
      const int b0 = d * 128 + jq * 32;
      *(f32x4*)((char*)Kts + ((b0 + 0) ^ sw))  = *(f32x4*)&ph[0];
      *(f32x4*)((char*)Kts + ((b0 + 16) ^ sw)) = *(f32x4*)&ph[4];
      *(f32x4*)((char*)Vts + ((b0 + 0) ^ sw))  = *(f32x4*)&pv[0];
      *(f32x4*)((char*)Vts + ((b0 + 16) ^ sw)) = *(f32x4*)&pv[4];
    }
    __syncthreads();
    f16x8 avv[2];
    {
      const int row = wid * 16 + l15;
      const int sw = (l15 & 7) << 4;
      avv[0] = *(const f16x8*)((char*)Vts + row * 128 + ((lg * 16) ^ sw));
      avv[1] = *(const f16x8*)((char*)Vts + row * 128 + ((64 + lg * 16) ^ sw));
    }
    #pragma unroll
    for (int dkt = 0; dkt < 8; ++dkt) {
      const int row = dkt * 16 + l15;
      const int sw = (l15 & 7) << 4;
      #pragma unroll
      for (int ks = 0; ks < 2; ++ks) {
        const int bc = ks * 64 + lg * 16;
        f16x8 bh8 = *(const f16x8*)((char*)Kts + row * 128 + (bc ^ sw));
        acc[dkt] = __builtin_amdgcn_mfma_f32_16x16x32_f16(avv[ks], bh8, acc[dkt], 0, 0, 0);
      }
    }
    if (tid < 128) {   // ksum partial over this pass's 64 j
      const int sw = (tid & 7) << 4;
      #pragma unroll
      for (int g = 0; g < 8; ++g) {
        f16x8 hh = *(const f16x8*)((char*)Kts + tid * 128 + ((g * 16) ^ sw));
        #pragma unroll
        for (int e = 0; e < 8; ++e) ks_acc += (float)hh[e];
      }
    }
  }
  unsigned short* gxs = GXs + (size_t)(bh * 16 + c) * 16384;
  #pragma unroll
  for (int dkt = 0; dkt < 8; ++dkt)
    #pragma unroll
    for (int r = 0; r < 4; ++r)
      gxs[(wid * 16 + lg * 4 + r) * 128 + dkt * 16 + l15] = f16bits(acc[dkt][r]);
  if (tid < 128) pkt[(size_t)(bh * 16 + c) * 128 + tid] = ks_acc;
}

// ---------------- Kernel P2: exclusive prefix states (in-place, fp16) -------
__global__ __launch_bounds__(256)
void p2_kernel(const float* __restrict__ mt128, unsigned short* __restrict__ GXs,
               const float* __restrict__ pkt, float* __restrict__ pkx) {
  const int s = blockIdx.x, bh = blockIdx.y;
  const int tid = threadIdx.x;
  union U8 { uint4 q; _Float16 h[8]; };
  if (s < 8) {
    unsigned short* base = GXs + (size_t)bh * 16 * 16384 + s * 2048 + tid * 8;
    float X[8];
    #pragma unroll
    for (int e = 0; e < 8; ++e) X[e] = 0.f;
    float Mm1 = -3.4e38f;
    for (int c = 0; c < 16; ++c) {
      U8 cu; cu.q = *(const uint4*)(base + (size_t)c * 16384);
      const float mtc = mt128[bh * 16 + c];
      const float Mc = fmaxf(Mm1, mtc);
      const float s1 = __expf(Mm1 - Mc), s2 = __expf(mtc - Mc);
      U8 ou;
      #pragma unroll
      for (int e = 0; e < 8; ++e) ou.h[e] = (_Float16)X[e];
      *(uint4*)(base + (size_t)c * 16384) = ou.q;
      #pragma unroll
      for (int e = 0; e < 8; ++e) X[e] = X[e] * s1 + (float)cu.h[e] * s2;
      Mm1 = Mc;
    }
  } else if (tid < 128) {
    const float* pb = pkt + (size_t)bh * 16 * 128 + tid;
    float X = 0.f, Mm1 = -3.4e38f;
    for (int c = 0; c < 16; ++c) {
      const float g = pb[(size_t)c * 128];
      const float mtc = mt128[bh * 16 + c];
      const float Mc = fmaxf(Mm1, mtc);
      pkx[(size_t)bh * 16 * 128 + (size_t)c * 128 + tid] = X;
      X = X * __expf(Mm1 - Mc) + g * __expf(mtc - Mc);
      Mm1 = Mc;
    }
  }
}

// ---------------- Kernel P3: MERGED pair (t=2c, t=2c+1) per block (R15) -----
// R17: __launch_bounds__(1024, 4) — 4 waves/EU = our exact 1-block/CU
// residency, VGPR cap 128. R16's bare (1024) let the allocator pin VGPR=64
// and spill qh/ql/hacc to scratch (WRITE 27.4MB vs 16.7MB output).
__global__ __launch_bounds__(1024, 4)
void p3_kernel(const float* __restrict__ q, const float* __restrict__ k,
               const float* __restrict__ v, const float* __restrict__ a_g,
               const float* __restrict__ ms_g, const float* __restrict__ fl_g,
               const float* __restrict__ Mg_g, const float* __restrict__ pkx,
               const unsigned short* __restrict__ GXs, float* __restrict__ out) {
  __shared__ __align__(16) char pool[50944];
  _Float16* Ks_hi = (_Float16*)pool;             // [64 j][128 dk] 256B rows
  _Float16* Ks_lo = (_Float16*)(pool + 16384);
  _Float16* Vts   = (_Float16*)(pool + 32768);   // [128 dv][64 j] 128B rows
  float* a_s      = (float*)(pool + 49152);      // [64]
  float* rs_lds   = (float*)(pool + 49408);      // [128][2]
  float* pks      = (float*)(pool + 50432);      // [128]
  float* hex      = (float*)pool;                // epilogue reuse (32KB)

  const int bid = blockIdx.x;
  const int c = bid & 15;
  const int bh = bid >> 4;
  const int b = bh >> 3, h = bh & 7;
  const int tid = threadIdx.x;
  const int lane = tid & 63;
  const int wid = tid >> 6;          // 0..15
  const int tt = wid >> 3;           // 0..1: tile t = 2c+tt
  const int wr = (wid >> 1) & 3;     // 16-row group
  const int wc = wid & 1;            // half split (j in A, dk in B)
  const int l15 = lane & 15;
  const int lg = lane >> 4;
  const int t = 2 * c + tt;
  const int i0 = t * BM;
  const f32x4 z4 = {0.f, 0.f, 0.f, 0.f};

  // ---- Q fragments (QSCALE folded, hi/lo split) ----
  f16x8 qh[4], ql[4];
  {
    const float* qbase = q + (size_t)(b * SLEN + i0 + wr * 16 + l15) * DMODEL + h * DHEAD;
    #pragma unroll
    for (int ks = 0; ks < 4; ++ks) {
      f32x4 x0 = *(const f32x4*)(qbase + ks * 32 + lg * 8);
      f32x4 x1 = *(const f32x4*)(qbase + ks * 32 + lg * 8 + 4);
      f16x8 hi, lo;
      #pragma unroll
      for (int e = 0; e < 4; ++e) {
        float s0 = x0[e] * QSCALE, s1 = x1[e] * QSCALE;
        _Float16 h0 = (_Float16)s0, h1 = (_Float16)s1;
        hi[e] = h0;     hi[e + 4] = h1;
        lo[e] = (_Float16)(s0 - (float)h0);
        lo[e + 4] = (_Float16)(s1 - (float)h1);
      }
      qh[ks] = hi; ql[ks] = lo;
    }
  }
  const float m_reg = ms_g[bh * SLEN + i0 + wr * 16 + l15];
  const float fl_reg = fl_g[bh * SLEN + i0 + wr * 16 + l15];
  const float e_l = __expf(Mg_g[bh * 16 + c] - m_reg);   // 0 at c==0

  f32x4 hacc[8];
  #pragma unroll
  for (int cf = 0; cf < 8; ++cf) hacc[cf] = z4;
  float ps = 0.f;

  // ---- stage X -> LDS once (swizzled; fused load+store) + pks ----
  if (c > 0) {
    const char* gxs = (const char*)(GXs + (size_t)(bh * 16 + c) * 16384);
    const int xrow = tid >> 3;            // 0..127
    const int xcb = (tid & 7) * 32;       // byte col base
    const int sw = (xrow & 7) << 4;
    uint4 g0 = *(const uint4*)(gxs + xrow * 256 + xcb);
    uint4 g1 = *(const uint4*)(gxs + xrow * 256 + xcb + 16);
    *(uint4*)((char*)pool + xrow * 256 + ((xcb + 0) ^ sw)) = g0;
    *(uint4*)((char*)pool + xrow * 256 + ((xcb + 16) ^ sw)) = g1;
  }
  if (tid < 128) pks[tid] = pkx[(size_t)(bh * 16 + c) * 128 + tid];
  __syncthreads();

  // ---- Phase B (both tt): Q*e_l @ X (from LDS), + inter rowsum ----
  if (c > 0) {
    f16x8 qe[2];
    #pragma unroll
    for (int kss = 0; kss < 2; ++kss) {
      const int ks = wc * 2 + kss;
      #pragma unroll
      for (int e = 0; e < 8; ++e)
        qe[kss][e] = (_Float16)(((float)qh[ks][e] + (float)ql[ks][e]) * e_l);
    }
    #pragma unroll
    for (int cf = 0; cf < 8; ++cf) {
      const int row = cf * 16 + l15;
      const int sw = (row & 7) << 4;
      #pragma unroll
      for (int kss = 0; kss < 2; ++kss) {
        const int bc = (wc * 2 + kss) * 64 + lg * 16;
        f16x8 xh = *(const f16x8*)((char*)pool + row * 256 + (bc ^ sw));
        hacc[cf] = __builtin_amdgcn_mfma_f32_16x16x32_f16(qe[kss], xh, hacc[cf], 0, 0, 0);
      }
    }
    if (wc == 0) {   // inter rowsum partial: e_l * (q . pk_excl)
      float dot = 0.f;
      #pragma unroll
      for (int ks = 0; ks < 4; ++ks)
        #pragma unroll
        for (int e = 0; e < 8; ++e)
          dot += ((float)qh[ks][e] + (float)ql[ks][e]) * pks[ks * 32 + lg * 8 + e];
      ps += dot * e_l;
    }
  }

  // ---- Phase A: two 64-wide sub-tiles; wave active iff pss <= tt ----
  #pragma unroll
  for (int pss = 0; pss < 2; ++pss) {
    const int j0 = c * 128 + pss * 64;
    __syncthreads();   // X-LDS / prior-pass reads done before restage

    // ---- stage K raw hi/lo (1024 thr: 8 floats each), swizzled ----
    {
      const int krow = tid >> 4;            // 0..63
      const int kc0 = (tid & 15) * 8;       // float col base
      const float* kp = k + (size_t)(b * SLEN + j0 + krow) * DMODEL + h * DHEAD + kc0;
      char* bh_ = (char*)Ks_hi + krow * 256;
      char* bl_ = (char*)Ks_lo + krow * 256;
      const int sw = (krow & 7) << 4;
      #pragma unroll
      for (int e = 0; e < 2; ++e) {
        f32x4 xv = *(const f32x4*)(kp + e * 4);
        f16x4 hi, lo;
        #pragma unroll
        for (int u = 0; u < 4; ++u) {
          _Float16 hh = (_Float16)xv[u];
          hi[u] = hh; lo[u] = (_Float16)(xv[u] - (float)hh);
        }
        const int bc = (kc0 + e * 4) * 2;
        *(f16x4*)(bh_ + (bc ^ sw)) = hi;
        *(f16x4*)(bl_ + (bc ^ sw)) = lo;
      }
    }
    // ---- stage V (1024 thr: 8 j's each), packed 16B swizzled store ----
    {
      const int d = tid & 127;
      const int jq = tid >> 7;              // 0..7 (8 j each)
      const float* vp = v + (size_t)(b * SLEN + j0 + jq * 8) * DMODEL + h * DHEAD + d;
      float vv[8];
      #pragma unroll
      for (int jj = 0; jj < 8; ++jj)
        vv[jj] = vp[(size_t)jj * DMODEL];
      int pv[4];
      #pragma unroll
      for (int p = 0; p < 4; ++p) pv[p] = pk16(vv[2 * p], vv[2 * p + 1]);
      const int sw = (d & 7) << 4;
      const int b0 = d * 128 + jq * 16;
      *(f32x4*)((char*)Vts + (b0 ^ sw)) = *(f32x4*)&pv[0];
    }
    if (tid < BKT) a_s[tid] = a_g[bh * SLEN + j0 + tid];
    __syncthreads();

    if (pss <= tt) {
      // ---- swapped QK^T (3-leg split) ----
      f32x4 sacc[2];
      sacc[0] = z4; sacc[1] = z4;
      #pragma unroll
      for (int ks = 0; ks < 4; ++ks) {
        const int bc = ks * 64 + lg * 16;
        #pragma unroll
        for (int jfl = 0; jfl < 2; ++jfl) {
          const int arow = wc * 32 + jfl * 16 + l15;
          const int sw = (arow & 7) << 4;
          f16x8 kh8 = *(const f16x8*)((char*)Ks_hi + arow * 256 + (bc ^ sw));
          f16x8 kl8 = *(const f16x8*)((char*)Ks_lo + arow * 256 + (bc ^ sw));
          sacc[jfl] = __builtin_amdgcn_mfma_f32_16x16x32_f16(kh8, qh[ks], sacc[jfl], 0, 0, 0);
          sacc[jfl] = __builtin_amdgcn_mfma_f32_16x16x32_f16(kl8, qh[ks], sacc[jfl], 0, 0, 0);
          sacc[jfl] = __builtin_amdgcn_mfma_f32_16x16x32_f16(kh8, ql[ks], sacc[jfl], 0, 0, 0);
        }
      }
      // ---- decay + mask + rowsum (per-element exp, mask idle off-diag) ----
      float vals[2][4];
      {
        const int iG = i0 + wr * 16 + l15;
        #pragma unroll
        for (int jfl = 0; jfl < 2; ++jfl)
          #pragma unroll
          for (int r = 0; r < 4; ++r) {
            const int jl = wc * 32 + jfl * 16 + lg * 4 + r;
            float e = __expf(fminf(a_s[jl] - m_reg, 0.f));
            float vv = sacc[jfl][r] * e;
            if (j0 + jl > iG) vv = 0.f;
            ps += vv;
            vals[jfl][r] = vv;
          }
      }
      // ---- pack + repack to PV A-frag via bpermute ----
      const int lgand1 = lg & 1;
      const int idxA = (l15 + 16 * (2 * lgand1 + 0)) * 4;
      const int idxB = (l15 + 16 * (2 * lgand1 + 1)) * 4;
      const bool hi_half = ((lane & 63) >= 32);
      int c2[2][2];
      #pragma unroll
      for (int jfl = 0; jfl < 2; ++jfl) {
        c2[jfl][0] = pk16(vals[jfl][0], vals[jfl][1]);
        c2[jfl][1] = pk16(vals[jfl][2], vals[jfl][3]);
      }
      int pa32[4];
      #pragma unroll
      for (int p = 0; p < 4; ++p) {
        const int idx2 = (p < 2) ? idxA : idxB;
        int f0 = __builtin_amdgcn_ds_bpermute(idx2, c2[0][p & 1]);
        int f1 = __builtin_amdgcn_ds_bpermute(idx2, c2[1][p & 1]);
        pa32[p] = hi_half ? f1 : f0;
      }
      union { int i[4]; f16x8 v; } pu;
      pu.i[0] = pa32[0]; pu.i[1] = pa32[1]; pu.i[2] = pa32[2]; pu.i[3] = pa32[3];
      const f16x8 paf = pu.v;

      // ---- PV ----
      const int vbc = wc * 64 + lg * 16;
      #pragma unroll
      for (int cf = 0; cf < 8; ++cf) {
        const int vrow = cf * 16 + l15;
        const int sw = (vrow & 7) << 4;
        f16x8 vb8 = *(const f16x8*)((char*)Vts + vrow * 128 + (vbc ^ sw));
        hacc[cf] = __builtin_amdgcn_mfma_f32_16x16x32_f16(paf, vb8, hacc[cf], 0, 0, 0);
      }
    }
  }
  __syncthreads();   // all LDS reads done before epilogue reuses pool

  // ================= Epilogue (R8-verified, two tt-phases) ==================
  ps += __shfl_xor(ps, 16);
  ps += __shfl_xor(ps, 32);
  if (lane < 16) rs_lds[(tt * 64 + wr * 16 + l15) * 2 + wc] = ps;
  if (tt == 0 && wc == 1) {
    #pragma unroll
    for (int cf = 0; cf < 8; ++cf)
      *(f32x4*)&hex[wr * 2048 + cf * 256 + lane * 4] = hacc[cf];
  }
  __syncthreads();
  if (tt == 0 && wc == 0) {
    #pragma unroll
    for (int cf = 0; cf < 8; ++cf) {
      f32x4 o = *(const f32x4*)&hex[wr * 2048 + cf * 256 + lane * 4];
      hacc[cf][0] += o[0]; hacc[cf][1] += o[1];
      hacc[cf][2] += o[2]; hacc[cf][3] += o[3];
    }
    const float rsum = rs_lds[(wr * 16 + l15) * 2 + 0] + rs_lds[(wr * 16 + l15) * 2 + 1];
    const float inv = 1.0f / (fmaxf(fabsf(rsum), fl_reg) + 1e-6f);
    union { float f; int i; } uc; uc.f = inv;
    float invr[4];
    #pragma unroll
    for (int r = 0; r < 4; ++r) {
      union { float f; int i; } ur;
      ur.i = __builtin_amdgcn_ds_bpermute((lg * 4 + r) * 4, uc.i);
      invr[r] = ur.f;
    }
    #pragma unroll
    for (int r = 0; r < 4; ++r) {
      const size_t orow = (size_t)(b * SLEN + i0 + wr * 16 + lg * 4 + r) * DMODEL + h * DHEAD;
      #pragma unroll
      for (int cf = 0; cf < 8; ++cf)
        out[orow + cf * 16 + l15] = hacc[cf][r] * invr[r];
    }
  }
  __syncthreads();
  if (tt == 1 && wc == 1) {
    #pragma unroll
    for (int cf = 0; cf < 8; ++cf)
      *(f32x4*)&hex[wr * 2048 + cf * 256 + lane * 4] = hacc[cf];
  }
  __syncthreads();
  if (tt == 1 && wc == 0) {
    #pragma unroll
    for (int cf = 0; cf < 8; ++cf) {
      f32x4 o = *(const f32x4*)&hex[wr * 2048 + cf * 256 + lane * 4];
      hacc[cf][0] += o[0]; hacc[cf][1] += o[1];
      hacc[cf][2] += o[2]; hacc[cf][3] += o[3];
    }
    const float rsum = rs_lds[(64 + wr * 16 + l15) * 2 + 0] + rs_lds[(64 + wr * 16 + l15) * 2 + 1];
    const float inv = 1.0f / (fmaxf(fabsf(rsum), fl_reg) + 1e-6f);
    union { float f; int i; } uc; uc.f = inv;
    float invr[4];
    #pragma unroll
    for (int r = 0; r < 4; ++r) {
      union { float f; int i; } ur;
      ur.i = __builtin_amdgcn_ds_bpermute((lg * 4 + r) * 4, uc.i);
      invr[r] = ur.f;
    }
    #pragma unroll
    for (int r = 0; r < 4; ++r) {
      const size_t orow = (size_t)(b * SLEN + i0 + wr * 16 + lg * 4 + r) * DMODEL + h * DHEAD;
      #pragma unroll
      for (int cf = 0; cf < 8; ++cf)
        out[orow + cf * 16 + l15] = hacc[cf][r] * invr[r];
    }
  }
}

// ---------------- Fallback: R8 mlstm_main (verified, ws-light) --------------
__global__ __launch_bounds__(512)
void mlstm_main(const float* __restrict__ q, const float* __restrict__ k,
                const float* __restrict__ v, const float* __restrict__ a_g,
                const float* __restrict__ ms_g, const float* __restrict__ fl_g,
                const float* __restrict__ mt_g, float* __restrict__ out) {
  __shared__ __align__(16) char pool[50176];
  _Float16* Ks_hi = (_Float16*)pool;
  _Float16* Ks_lo = (_Float16*)(pool + 16384);
  _Float16* Vts   = (_Float16*)(pool + 32768);
  float* a_s      = (float*)(pool + 49152);
  float* rs_lds   = (float*)(pool + 49408);
  float* hex      = (float*)pool;

  const int bid = blockIdx.x;
  int t, bh;
  if (bid < 256) { t = 31 - (bid >> 4); bh = bid & 15; }
  else           { t = (bid - 256) >> 4; bh = (bid - 256) & 15; }
  const int b = bh >> 3, h = bh & 7;
  const int i0 = t * BM;
  const int tid = threadIdx.x;
  const int lane = tid & 63;
  const int wid = tid >> 6;
  const int wr = wid >> 1;
  const int wc = wid & 1;
  const int l15 = lane & 15;
  const int lg = lane >> 4;
  const f32x4 z4 = {0.f, 0.f, 0.f, 0.f};

  f16x8 qh[4], ql[4];
  {
    const float* qbase = q + (size_t)(b * SLEN + i0 + wr * 16 + l15) * DMODEL + h * DHEAD;
    #pragma unroll
    for (int ks = 0; ks < 4; ++ks) {
      f32x4 x0 = *(const f32x4*)(qbase + ks * 32 + lg * 8);
      f32x4 x1 = *(const f32x4*)(qbase + ks * 32 + lg * 8 + 4);
      f16x8 hi, lo;
      #pragma unroll
      for (int e = 0; e < 4; ++e) {
        float s0 = x0[e] * QSCALE, s1 = x1[e] * QSCALE;
        _Float16 h0 = (_Float16)s0, h1 = (_Float16)s1;
        hi[e] = h0;     hi[e + 4] = h1;
        lo[e] = (_Float16)(s0 - (float)h0);
        lo[e + 4] = (_Float16)(s1 - (float)h1);
      }
      qh[ks] = hi; ql[ks] = lo;
    }
  }
  const float m_reg = ms_g[bh * SLEN + i0 + wr * 16 + l15];
  const float fl_reg = fl_g[bh * SLEN + i0 + wr * 16 + l15];
  const int lgand1 = lg & 1;
  const int idxA = (l15 + 16 * (2 * lgand1 + 0)) * 4;
  const int idxB = (l15 + 16 * (2 * lgand1 + 1)) * 4;
  const bool hi_half = (lane >= 32);

  f32x4 hacc[8];
  #pragma unroll
  for (int cf = 0; cf < 8; ++cf) hacc[cf] = z4;
  float ps = 0.f;

  const int krow = tid >> 3;
  const int kc0 = (tid & 7) * 16;
  const int vdv = tid & 127;
  const int vjq = tid >> 7;

  for (int jt = 0; jt <= t; ++jt) {
    const int j0 = jt * BKT;
    const bool diag = (jt == t);
    const float mt = mt_g[bh * 32 + jt];
    {
      float es = 1.f;
      if (!diag) es = __expf(a_g[bh * SLEN + j0 + krow] - mt);
      const float* kp = k + (size_t)(b * SLEN + j0 + krow) * DMODEL + h * DHEAD + kc0;
      char* bh_ = (char*)Ks_hi + krow * 256;
      char* bl_ = (char*)Ks_lo + krow * 256;
      const int sw = (krow & 7) << 4;
      #pragma unroll
      for (int e = 0; e < 4; ++e) {
        f32x4 xv = *(const f32x4*)(kp + e * 4);
        f16x4 hi, lo;
        #pragma unroll
        for (int u = 0; u < 4; ++u) {
          float vv = xv[u] * es;
          _Float16 hh = (_Float16)vv;
          hi[u] = hh; lo[u] = (_Float16)(vv - (float)hh);
        }
        const int bc = (kc0 + e * 4) * 2;
        *(f16x4*)(bh_ + (bc ^ sw)) = hi;
        *(f16x4*)(bl_ + (bc ^ sw)) = lo;
      }
    }
    {
      const float* vp = v + (size_t)(b * SLEN + j0 + vjq * 16) * DMODEL + h * DHEAD + vdv;
      float vv[16];
      #pragma unroll
      for (int jj = 0; jj < 16; ++jj)
        vv[jj] = vp[(size_t)jj * DMODEL];
      int pk[8];
      #pragma unroll
      for (int p = 0; p < 8; ++p) pk[p] = pk16(vv[2 * p], vv[2 * p + 1]);
      const int sw = (vdv & 7) << 4;
      *(f32x4*)((char*)Vts + ((vdv * 128 + vjq * 32 + 0) ^ sw)) = *(f32x4*)&pk[0];
      *(f32x4*)((char*)Vts + ((vdv * 128 + vjq * 32 + 16) ^ sw)) = *(f32x4*)&pk[4];
    }
    if (diag && tid < BKT) a_s[tid] = a_g[bh * SLEN + j0 + tid];
    __syncthreads();

    f32x4 sacc[2];
    sacc[0] = z4; sacc[1] = z4;
    #pragma unroll
    for (int ks = 0; ks < 4; ++ks) {
      const int bc = ks * 64 + lg * 16;
      #pragma unroll
      for (int jfl = 0; jfl < 2; ++jfl) {
        const int arow = wc * 32 + jfl * 16 + l15;
        const int sw = (arow & 7) << 4;
        f16x8 kh8 = *(const f16x8*)((char*)Ks_hi + arow * 256 + (bc ^ sw));
        f16x8 kl8 = *(const f16x8*)((char*)Ks_lo + arow * 256 + (bc ^ sw));
        sacc[jfl] = __builtin_amdgcn_mfma_f32_16x16x32_f16(kh8, qh[ks], sacc[jfl], 0, 0, 0);
        sacc[jfl] = __builtin_amdgcn_mfma_f32_16x16x32_f16(kl8, qh[ks], sacc[jfl], 0, 0, 0);
        sacc[jfl] = __builtin_amdgcn_mfma_f32_16x16x32_f16(kh8, ql[ks], sacc[jfl], 0, 0, 0);
      }
    }
    float vals[2][4];
    if (diag) {
      const int iG = i0 + wr * 16 + l15;
      #pragma unroll
      for (int jfl = 0; jfl < 2; ++jfl)
        #pragma unroll
        for (int r = 0; r < 4; ++r) {
          const int jl = wc * 32 + jfl * 16 + lg * 4 + r;
          float e = __expf(fminf(a_s[jl] - m_reg, 0.f));
          float vv = sacc[jfl][r] * e;
          if (j0 + jl > iG) vv = 0.f;
          vals[jfl][r] = vv;
        }
    } else {
      const float em = __expf(fminf(mt - m_reg, 0.f));
      #pragma unroll
      for (int jfl = 0; jfl < 2; ++jfl)
        #pragma unroll
        for (int r = 0; r < 4; ++r)
          vals[jfl][r] = sacc[jfl][r] * em;
    }
    #pragma unroll
    for (int jfl = 0; jfl < 2; ++jfl)
      #pragma unroll
      for (int r = 0; r < 4; ++r) ps += vals[jfl][r];

    int c2[2][2];
    #pragma unroll
    for (int jfl = 0; jfl < 2; ++jfl) {
      c2[jfl][0] = pk16(vals[jfl][0], vals[jfl][1]);
      c2[jfl][1] = pk16(vals[jfl][2], vals[jfl][3]);
    }
    int pa32[4];
    #pragma unroll
    for (int p = 0; p < 4; ++p) {
      const int idx = (p < 2) ? idxA : idxB;
      int f0 = __builtin_amdgcn_ds_bpermute(idx, c2[0][p & 1]);
      int f1 = __builtin_amdgcn_ds_bpermute(idx, c2[1][p & 1]);
      pa32[p] = hi_half ? f1 : f0;
    }
    union { int i[4]; f16x8 v; } pu;
    pu.i[0] = pa32[0]; pu.i[1] = pa32[1]; pu.i[2] = pa32[2]; pu.i[3] = pa32[3];
    const f16x8 paf = pu.v;

    const int vbc = wc * 64 + lg * 16;
    #pragma unroll
    for (int cf = 0; cf < 8; ++cf) {
      const int vrow = cf * 16 + l15;
      const int sw = (vrow & 7) << 4;
      f16x8 vb8 = *(const f16x8*)((char*)Vts + vrow * 128 + (vbc ^ sw));
      hacc[cf] = __builtin_amdgcn_mfma_f32_16x16x32_f16(paf, vb8, hacc[cf], 0, 0, 0);
    }
    __syncthreads();
  }

  ps += __shfl_xor(ps, 16);
  ps += __shfl_xor(ps, 32);
  if (lane < 16) rs_lds[(wr * 16 + l15) * 2 + wc] = ps;
  if (wc == 1) {
    #pragma unroll
    for (int cf = 0; cf < 8; ++cf)
      *(f32x4*)&hex[wr * 2048 + cf * 256 + lane * 4] = hacc[cf];
  }
  __syncthreads();
  if (wc == 0) {
    #pragma unroll
    for (int cf = 0; cf < 8; ++cf) {
      f32x4 o = *(const f32x4*)&hex[wr * 2048 + cf * 256 + lane * 4];
      hacc[cf][0] += o[0]; hacc[cf][1] += o[1];
      hacc[cf][2] += o[2]; hacc[cf][3] += o[3];
    }
    const float rsum = rs_lds[(wr * 16 + l15) * 2 + 0] + rs_lds[(wr * 16 + l15) * 2 + 1];
    const float inv = 1.0f / (fmaxf(fabsf(rsum), fl_reg) + 1e-6f);
    union { float f; int i; } uc; uc.f = inv;
    float invr[4];
    #pragma unroll
    for (int r = 0; r < 4; ++r) {
      union { float f; int i; } ur;
      ur.i = __builtin_amdgcn_ds_bpermute((lg * 4 + r) * 4, uc.i);
      invr[r] = ur.f;
    }
    #pragma unroll
    for (int r = 0; r < 4; ++r) {
      const size_t orow = (size_t)(b * SLEN + i0 + wr * 16 + lg * 4 + r) * DMODEL + h * DHEAD;
      #pragma unroll
      for (int cf = 0; cf < 8; ++cf)
        out[orow + cf * 16 + l15] = hacc[cf][r] * invr[r];
    }
  }
}

// ---------------- Kernel 4: in-place LayerNorm on d_out ---------------------
__global__ __launch_bounds__(256)
void ln_kernel(float* __restrict__ out, const float* __restrict__ gamma) {
  const int row = blockIdx.x;
  const int tid = threadIdx.x;
  float* x = out + (size_t)row * DMODEL;
  f32x4 xv = ((const f32x4*)x)[tid];
  float s = xv[0] + xv[1] + xv[2] + xv[3];
  float qq = xv[0] * xv[0] + xv[1] * xv[1] + xv[2] * xv[2] + xv[3] * xv[3];
  #pragma unroll
  for (int m = 1; m < 64; m <<= 1) { s += __shfl_xor(s, m); qq += __shfl_xor(qq, m); }
  __shared__ float ss[4], sq[4];
  const int wid = tid >> 6;
  if ((tid & 63) == 0) { ss[wid] = s; sq[wid] = qq; }
  __syncthreads();
  s = ss[0] + ss[1] + ss[2] + ss[3];
  qq = sq[0] + sq[1] + sq[2] + sq[3];
  const float mu = s * (1.f / 1024.f);
  const float var = qq * (1.f / 1024.f) - mu * mu;
  const float rstd = rsqrtf(var + 1e-5f);
  f32x4 g = ((const f32x4*)gamma)[tid];
  f32x4 ov;
  ov[0] = (xv[0] - mu) * rstd * g[0];
  ov[1] = (xv[1] - mu) * rstd * g[1];
  ov[2] = (xv[2] - mu) * rstd * g[2];
  ov[3] = (xv[3] - mu) * rstd * g[3];
  ((f32x4*)x)[tid] = ov;
}

extern "C" void kernel_launch(void* const* d_in, const int* in_sizes, int n_in,
                              void* d_out, int out_size, void* d_ws, size_t ws_size,
                              hipStream_t stream) {
  (void)in_sizes; (void)n_in; (void)out_size;
  const float* q   = (const float*)d_in[0];
  const float* k   = (const float*)d_in[1];
  const float* v   = (const float*)d_in[2];
  const float* igw = (const float*)d_in[3];
  const float* igb = (const float*)d_in[4];
  const float* fgw = (const float*)d_in[5];
  const float* fgb = (const float*)d_in[6];
  const float* lns = (const float*)d_in[7];
  float* out = (float*)d_out;

  float* gpre  = (float*)d_ws;           // 65536 f32
  float* a_g   = gpre + 65536;           // 32768
  float* ms_g  = a_g + 32768;            // 32768
  float* fl_g  = ms_g + 32768;           // 32768
  float* mt64  = fl_g + 32768;           // 512   (16 x 32)
  float* mt128 = mt64 + 512;             // 256   (16 x 16)
  float* Mg_g  = mt128 + 256;            // 256
  float* pkt   = Mg_g + 256;             // 32768 (256 x 128)
  float* pkx   = pkt + 32768;            // 32768
  unsigned short* GXs = (unsigned short*)(pkx + 32768);  // 256 x 16384 fp16 = 8MB
  // total ≈ 9.31 MB

  const bool big = ws_size >= (size_t)10 * 1024 * 1024;

  gates_kernel<<<dim3(256), dim3(512), 0, stream>>>(q, k, v, igw, fgw, gpre);
  scan_kernel<<<dim3(16), dim3(256), 0, stream>>>(gpre, igb, fgb, a_g, ms_g, fl_g,
                                                  mt64, mt128, Mg_g);
  if (big) {
    p1_kernel<<<dim3(16, 16), dim3(512), 0, stream>>>(k, v, a_g, mt128, GXs, pkt);
    p2_kernel<<<dim3(9, 16), dim3(256), 0, stream>>>(mt128, GXs, pkt, pkx);
    p3_kernel<<<dim3(256), dim3(1024), 0, stream>>>(q, k, v, a_g, ms_g, fl_g,
                                                    Mg_g, pkx, GXs, out);
  } else {
    mlstm_main<<<dim3(512), dim3(512), 0, stream>>>(q, k, v, a_g, ms_g, fl_g, mt64, out);
  }
  ln_kernel<<<dim3(4096), dim3(256), 0, stream>>>(out, lns);
}

// Round 18
// 82.916 us; speedup vs baseline: 1.0054x; 1.0054x over previous
//
#include <hip/hip_runtime.h>
#include <hip/hip_bf16.h>

#define SLEN 2048
#define DMODEL 1024
#define NHEAD 8
#define DHEAD 128
#define BM 64
#define BKT 64
#define QSCALE 0.08838834764831845f  // 1/sqrt(128)

typedef __attribute__((ext_vector_type(4))) float f32x4;
typedef __attribute__((ext_vector_type(8))) _Float16 f16x8;
typedef __attribute__((ext_vector_type(4))) _Float16 f16x4;
typedef __attribute__((ext_vector_type(2))) _Float16 f16x2;

static __device__ __forceinline__ int pk16(float a, float b) {
  f16x2 t; t[0] = (_Float16)a; t[1] = (_Float16)b;
  union { f16x2 h; int i; } u; u.h = t; return u.i;
}
static __device__ __forceinline__ unsigned short f16bits(float x) {
  union { _Float16 h; unsigned short u; } u2; u2.h = (_Float16)x; return u2.u;
}

// ---------------- Kernel 1: gate preactivations via MFMA (R16, verified) ----
__global__ __launch_bounds__(512)
void gates_kernel(const float* __restrict__ q, const float* __restrict__ k,
                  const float* __restrict__ v, const float* __restrict__ igw,
                  const float* __restrict__ fgw, float* __restrict__ gpre) {
  __shared__ float red[8][16][16];
  const int row0 = blockIdx.x * 16;
  const int tid = threadIdx.x;
  const int lane = tid & 63, wid = tid >> 6;
  const int l15 = lane & 15, lg = lane >> 4;
  const f32x4 z4 = {0.f, 0.f, 0.f, 0.f};
  f32x4 acc = z4;
  const float* wbase = (l15 < 8) ? (igw + (size_t)l15 * 3072)
                                 : (fgw + (size_t)(l15 - 8) * 3072);
  #pragma unroll
  for (int ks = 0; ks < 12; ++ks) {
    const int kk = wid * 384 + ks * 32 + lg * 8;   // lane k base
    const int seg = kk >> 10;
    const int col = kk & 1023;
    const float* src = (seg == 0) ? q : (seg == 1) ? k : v;
    const float* xp = src + (size_t)(row0 + l15) * 1024 + col;
    f32x4 a0 = *(const f32x4*)xp;
    f32x4 a1 = *(const f32x4*)(xp + 4);
    f32x4 b0 = *(const f32x4*)(wbase + kk);
    f32x4 b1 = *(const f32x4*)(wbase + kk + 4);
    f16x8 ah, al, bhf, blf;
    #pragma unroll
    for (int e = 0; e < 4; ++e) {
      _Float16 h0 = (_Float16)a0[e], h1 = (_Float16)a1[e];
      ah[e] = h0; ah[e + 4] = h1;
      al[e] = (_Float16)(a0[e] - (float)h0);
      al[e + 4] = (_Float16)(a1[e] - (float)h1);
      _Float16 g0 = (_Float16)b0[e], g1 = (_Float16)b1[e];
      bhf[e] = g0; bhf[e + 4] = g1;
      blf[e] = (_Float16)(b0[e] - (float)g0);
      blf[e + 4] = (_Float16)(b1[e] - (float)g1);
    }
    acc = __builtin_amdgcn_mfma_f32_16x16x32_f16(ah, bhf, acc, 0, 0, 0);
    acc = __builtin_amdgcn_mfma_f32_16x16x32_f16(al, bhf, acc, 0, 0, 0);
    acc = __builtin_amdgcn_mfma_f32_16x16x32_f16(ah, blf, acc, 0, 0, 0);
  }
  #pragma unroll
  for (int r = 0; r < 4; ++r)
    red[wid][lg * 4 + r][l15] = acc[r];
  __syncthreads();
  if (tid < 256) {
    const int xrow = tid >> 4, g = tid & 15;
    float s = 0.f;
    #pragma unroll
    for (int w = 0; w < 8; ++w) s += red[w][xrow][g];
    gpre[(size_t)g * 4096 + row0 + xrow] = s;
  }
}

// ---------------- Kernel 2: scans + chunk maxima (64 and 128) ---------------
__global__ __launch_bounds__(256)
void scan_kernel(const float* __restrict__ gpre, const float* __restrict__ igb,
                 const float* __restrict__ fgb, float* __restrict__ a_out,
                 float* __restrict__ ms_out, float* __restrict__ fl_out,
                 float* __restrict__ mt64, float* __restrict__ mt128,
                 float* __restrict__ Mg_out) {
  const int bh = blockIdx.x;
  const int h = bh & 7;
  const int b = bh >> 3;
  const int tid = threadIdx.x;
  __shared__ double sbd[256];
  __shared__ float sbf[256];
  __shared__ float mt_l[16];
  const int base = b * 2048 + tid * 8;
  const float ig_b = igb[h], fg_b = fgb[h];
  double cs[8];
  float av[8];
  double tot = 0.0;
  #pragma unroll
  for (int e = 0; e < 8; ++e) {
    float x = gpre[(size_t)(8 + h) * 4096 + base + e] + fg_b;
    float l = fminf(x, 0.f) - log1pf(__expf(-fabsf(x)));   // log_sigmoid
    tot += (double)l;
    cs[e] = tot;
  }
  sbd[tid] = tot;
  __syncthreads();
  if (tid == 0) {
    double run = 0.0;
    for (int i = 0; i < 256; ++i) { double t2 = sbd[i]; sbd[i] = run; run += t2; }
  }
  __syncthreads();
  const double excl = sbd[tid];
  float mtot = -3.4e38f;
  #pragma unroll
  for (int e = 0; e < 8; ++e) {
    cs[e] += excl;
    float ig = gpre[(size_t)h * 4096 + base + e] + ig_b;
    av[e] = (float)((double)ig - cs[e]);
    mtot = fmaxf(mtot, av[e]);
  }
  // per-64 and per-128 window maxima
  {
    float w8 = mtot;
    w8 = fmaxf(w8, __shfl_xor(w8, 1));
    w8 = fmaxf(w8, __shfl_xor(w8, 2));
    w8 = fmaxf(w8, __shfl_xor(w8, 4));
    if ((tid & 7) == 0) mt64[bh * 32 + (tid >> 3)] = w8;
    float w16 = fmaxf(w8, __shfl_xor(w8, 8));
    if ((tid & 15) == 0) { mt128[bh * 16 + (tid >> 4)] = w16; mt_l[tid >> 4] = w16; }
  }
  sbf[tid] = mtot;
  __syncthreads();
  if (tid == 0) {
    float run = -3.4e38f;
    for (int i = 0; i < 256; ++i) { float t2 = sbf[i]; sbf[i] = run; run = fmaxf(run, t2); }
    float M = -3.4e38f;
    for (int c = 0; c < 16; ++c) { Mg_out[bh * 16 + c] = M; M = fmaxf(M, mt_l[c]); }
  }
  __syncthreads();
  float run = sbf[tid];
  const int obase = bh * 2048 + tid * 8;
  #pragma unroll
  for (int e = 0; e < 8; ++e) {
    run = fmaxf(run, av[e]);
    a_out[obase + e] = av[e];
    ms_out[obase + e] = run;
    fl_out[obase + e] = __expf(-(float)(cs[e] + (double)run));  // exp(-max_log_D)
  }
}

// ---------------- Kernel P1: per-128-chunk state G[dv][dk] (fp16) + ksum ----
__global__ __launch_bounds__(512)
void p1_kernel(const float* __restrict__ k, const float* __restrict__ v,
               const float* __restrict__ a_g, const float* __restrict__ mt128,
               unsigned short* __restrict__ GXs, float* __restrict__ pkt) {
  __shared__ __align__(16) char pool[33280];
  _Float16* Kts = (_Float16*)pool;             // [128 dk][64 j] 128B rows, swz
  _Float16* Vts = (_Float16*)(pool + 16384);   // [128 dv][64 j]
  float* w_s = (float*)(pool + 32768);         // [128]
  const int c = blockIdx.x, bh = blockIdx.y;
  const int b = bh >> 3, h = bh & 7;
  const int tid = threadIdx.x;
  const int lane = tid & 63, wid = tid >> 6;
  const int l15 = lane & 15, lg = lane >> 4;
  if (tid < 128) w_s[tid] = __expf(a_g[bh * SLEN + c * 128 + tid] - mt128[bh * 16 + c]);
  const f32x4 z4 = {0.f, 0.f, 0.f, 0.f};
  f32x4 acc[8];
  #pragma unroll
  for (int i = 0; i < 8; ++i) acc[i] = z4;
  float ks_acc = 0.f;
  for (int p = 0; p < 2; ++p) {
    const int j0 = c * 128 + p * 64;
    __syncthreads();   // w_s ready (p=0); prior pass reads done (p=1)
    {
      const int d = tid & 127;
      const int jq = tid >> 7;                 // 0..3 (16 j each)
      const size_t rowb = (size_t)(b * SLEN + j0 + jq * 16) * DMODEL + h * DHEAD + d;
      float kv[16], vv[16];
      #pragma unroll
      for (int jj = 0; jj < 16; ++jj) {
        kv[jj] = k[rowb + (size_t)jj * DMODEL] * w_s[p * 64 + jq * 16 + jj];
        vv[jj] = v[rowb + (size_t)jj * DMODEL];
      }
      int ph[8], pv[8];
      #pragma unroll
      for (int pp = 0; pp < 8; ++pp) {
        ph[pp] = pk16(kv[2 * pp], kv[2 * pp + 1]);
        pv[pp] = pk16(vv[2 * pp], vv[2 * pp + 1]);
      }
      const int sw = (d & 7) << 4;
      const int b0 = d * 128 + jq * 32;
      *(f32x4*)((char*)Kts + ((b0 + 0) ^ sw))  = *(f32x4*)&ph[0];
      *(f32x4*)((char*)Kts + ((b0 + 16) ^ sw)) = *(f32x4*)&ph[4];
      *(f32x4*)((char*)Vts + ((b0 + 0) ^ sw))  = *(f32x4*)&pv[0];
      *(f32x4*)((char*)Vts + ((b0 + 16) ^ sw)) = *(f32x4*)&pv[4];
    }
    __syncthreads();
    f16x8 avv[2];
    {
      const int row = wid * 16 + l15;
      const int sw = (l15 & 7) << 4;
      avv[0] = *(const f16x8*)((char*)Vts + row * 128 + ((lg * 16) ^ sw));
      avv[1] = *(const f16x8*)((char*)Vts + row * 128 + ((64 + lg * 16) ^ sw));
    }
    #pragma unroll
    for (int dkt = 0; dkt < 8; ++dkt) {
      const int row = dkt * 16 + l15;
      const int sw = (l15 & 7) << 4;
      #pragma unroll
      for (int ks = 0; ks < 2; ++ks) {
        const int bc = ks * 64 + lg * 16;
        f16x8 bh8 = *(const f16x8*)((char*)Kts + row * 128 + (bc ^ sw));
        acc[dkt] = __builtin_amdgcn_mfma_f32_16x16x32_f16(avv[ks], bh8, acc[dkt], 0, 0, 0);
      }
    }
    if (tid < 128) {   // ksum partial over this pass's 64 j
      const int sw = (tid & 7) << 4;
      #pragma unroll
      for (int g = 0; g < 8; ++g) {
        f16x8 hh = *(const f16x8*)((char*)Kts + tid * 128 + ((g * 16) ^ sw));
        #pragma unroll
        for (int e = 0; e < 8; ++e) ks_acc += (float)hh[e];
      }
    }
  }
  unsigned short* gxs = GXs + (size_t)(bh * 16 + c) * 16384;
  #pragma unroll
  for (int dkt = 0; dkt < 8; ++dkt)
    #pragma unroll
    for (int r = 0; r < 4; ++r)
      gxs[(wid * 16 + lg * 4 + r) * 128 + dkt * 16 + l15] = f16bits(acc[dkt][r]);
  if (tid < 128) pkt[(size_t)(bh * 16 + c) * 128 + tid] = ks_acc;
}

// ---------------- Kernel P2: exclusive prefix states (in-place, fp16) -------
__global__ __launch_bounds__(256)
void p2_kernel(const float* __restrict__ mt128, unsigned short* __restrict__ GXs,
               const float* __restrict__ pkt, float* __restrict__ pkx) {
  const int s = blockIdx.x, bh = blockIdx.y;
  const int tid = threadIdx.x;
  union U8 { uint4 q; _Float16 h[8]; };
  if (s < 8) {
    unsigned short* base = GXs + (size_t)bh * 16 * 16384 + s * 2048 + tid * 8;
    float X[8];
    #pragma unroll
    for (int e = 0; e < 8; ++e) X[e] = 0.f;
    float Mm1 = -3.4e38f;
    for (int c = 0; c < 16; ++c) {
      U8 cu; cu.q = *(const uint4*)(base + (size_t)c * 16384);
      const float mtc = mt128[bh * 16 + c];
      const float Mc = fmaxf(Mm1, mtc);
      const float s1 = __expf(Mm1 - Mc), s2 = __expf(mtc - Mc);
      U8 ou;
      #pragma unroll
      for (int e = 0; e < 8; ++e) ou.h[e] = (_Float16)X[e];
      *(uint4*)(base + (size_t)c * 16384) = ou.q;
      #pragma unroll
      for (int e = 0; e < 8; ++e) X[e] = X[e] * s1 + (float)cu.h[e] * s2;
      Mm1 = Mc;
    }
  } else if (tid < 128) {
    const float* pb = pkt + (size_t)bh * 16 * 128 + tid;
    float X = 0.f, Mm1 = -3.4e38f;
    for (int c = 0; c < 16; ++c) {
      const float g = pb[(size_t)c * 128];
      const float mtc = mt128[bh * 16 + c];
      const float Mc = fmaxf(Mm1, mtc);
      pkx[(size_t)bh * 16 * 128 + (size_t)c * 128 + tid] = X;
      X = X * __expf(Mm1 - Mc) + g * __expf(mtc - Mc);
      Mm1 = Mc;
    }
  }
}

// ---------------- Kernel P3: MERGED pair (t=2c, t=2c+1) per block -----------
// R18: amdgpu_waves_per_eu(4,4) — CAPS occupancy at 4 waves/EU (our actual
// 1-block/CU at grid 256). R16/R17 allocator chased 2 blocks/CU (LDS 50.9KB
// <= 80KB allows it), pinned VGPR=64, spilled qh/ql/hacc (WRITE 27.4MB vs
// 16.7MB output, VALUBusy 1.3%). With the cap it may take up to 128 VGPR.
__global__ __launch_bounds__(1024)
__attribute__((amdgpu_waves_per_eu(4, 4)))
void p3_kernel(const float* __restrict__ q, const float* __restrict__ k,
               const float* __restrict__ v, const float* __restrict__ a_g,
               const float* __restrict__ ms_g, const float* __restrict__ fl_g,
               const float* __restrict__ Mg_g, const float* __restrict__ pkx,
               const unsigned short* __restrict__ GXs, float* __restrict__ out) {
  __shared__ __align__(16) char pool[50944];
  _Float16* Ks_hi = (_Float16*)pool;             // [64 j][128 dk] 256B rows
  _Float16* Ks_lo = (_Float16*)(pool + 16384);
  _Float16* Vts   = (_Float16*)(pool + 32768);   // [128 dv][64 j] 128B rows
  float* a_s      = (float*)(pool + 49152);      // [64]
  float* rs_lds   = (float*)(pool + 49408);      // [128][2]
  float* pks      = (float*)(pool + 50432);      // [128]
  float* hex      = (float*)pool;                // epilogue reuse (32KB)

  const int bid = blockIdx.x;
  const int c = bid & 15;
  const int bh = bid >> 4;
  const int b = bh >> 3, h = bh & 7;
  const int tid = threadIdx.x;
  const int lane = tid & 63;
  const int wid = tid >> 6;          // 0..15
  const int tt = wid >> 3;           // 0..1: tile t = 2c+tt
  const int wr = (wid >> 1) & 3;     // 16-row group
  const int wc = wid & 1;            // half split (j in A, dk in B)
  const int l15 = lane & 15;
  const int lg = lane >> 4;
  const int t = 2 * c + tt;
  const int i0 = t * BM;
  const f32x4 z4 = {0.f, 0.f, 0.f, 0.f};

  // ---- Q fragments (QSCALE folded, hi/lo split) ----
  f16x8 qh[4], ql[4];
  {
    const float* qbase = q + (size_t)(b * SLEN + i0 + wr * 16 + l15) * DMODEL + h * DHEAD;
    #pragma unroll
    for (int ks = 0; ks < 4; ++ks) {
      f32x4 x0 = *(const f32x4*)(qbase + ks * 32 + lg * 8);
      f32x4 x1 = *(const f32x4*)(qbase + ks * 32 + lg * 8 + 4);
      f16x8 hi, lo;
      #pragma unroll
      for (int e = 0; e < 4; ++e) {
        float s0 = x0[e] * QSCALE, s1 = x1[e] * QSCALE;
        _Float16 h0 = (_Float16)s0, h1 = (_Float16)s1;
        hi[e] = h0;     hi[e + 4] = h1;
        lo[e] = (_Float16)(s0 - (float)h0);
        lo[e + 4] = (_Float16)(s1 - (float)h1);
      }
      qh[ks] = hi; ql[ks] = lo;
    }
  }
  const float m_reg = ms_g[bh * SLEN + i0 + wr * 16 + l15];
  const float fl_reg = fl_g[bh * SLEN + i0 + wr * 16 + l15];
  const float e_l = __expf(Mg_g[bh * 16 + c] - m_reg);   // 0 at c==0

  f32x4 hacc[8];
  #pragma unroll
  for (int cf = 0; cf < 8; ++cf) hacc[cf] = z4;
  float ps = 0.f;

  // ---- stage X -> LDS once (swizzled; fused load+store) + pks ----
  if (c > 0) {
    const char* gxs = (const char*)(GXs + (size_t)(bh * 16 + c) * 16384);
    const int xrow = tid >> 3;            // 0..127
    const int xcb = (tid & 7) * 32;       // byte col base
    const int sw = (xrow & 7) << 4;
    uint4 g0 = *(const uint4*)(gxs + xrow * 256 + xcb);
    uint4 g1 = *(const uint4*)(gxs + xrow * 256 + xcb + 16);
    *(uint4*)((char*)pool + xrow * 256 + ((xcb + 0) ^ sw)) = g0;
    *(uint4*)((char*)pool + xrow * 256 + ((xcb + 16) ^ sw)) = g1;
  }
  if (tid < 128) pks[tid] = pkx[(size_t)(bh * 16 + c) * 128 + tid];
  __syncthreads();

  // ---- Phase B (both tt): Q*e_l @ X (from LDS), + inter rowsum ----
  if (c > 0) {
    f16x8 qe[2];
    #pragma unroll
    for (int kss = 0; kss < 2; ++kss) {
      const int ks = wc * 2 + kss;
      #pragma unroll
      for (int e = 0; e < 8; ++e)
        qe[kss][e] = (_Float16)(((float)qh[ks][e] + (float)ql[ks][e]) * e_l);
    }
    #pragma unroll
    for (int cf = 0; cf < 8; ++cf) {
      const int row = cf * 16 + l15;
      const int sw = (row & 7) << 4;
      #pragma unroll
      for (int kss = 0; kss < 2; ++kss) {
        const int bc = (wc * 2 + kss) * 64 + lg * 16;
        f16x8 xh = *(const f16x8*)((char*)pool + row * 256 + (bc ^ sw));
        hacc[cf] = __builtin_amdgcn_mfma_f32_16x16x32_f16(qe[kss], xh, hacc[cf], 0, 0, 0);
      }
    }
    if (wc == 0) {   // inter rowsum partial: e_l * (q . pk_excl)
      float dot = 0.f;
      #pragma unroll
      for (int ks = 0; ks < 4; ++ks)
        #pragma unroll
        for (int e = 0; e < 8; ++e)
          dot += ((float)qh[ks][e] + (float)ql[ks][e]) * pks[ks * 32 + lg * 8 + e];
      ps += dot * e_l;
    }
  }

  // ---- Phase A: two 64-wide sub-tiles; wave active iff pss <= tt ----
  #pragma unroll
  for (int pss = 0; pss < 2; ++pss) {
    const int j0 = c * 128 + pss * 64;
    __syncthreads();   // X-LDS / prior-pass reads done before restage

    // ---- stage K raw hi/lo (1024 thr: 8 floats each), swizzled ----
    {
      const int krow = tid >> 4;            // 0..63
      const int kc0 = (tid & 15) * 8;       // float col base
      const float* kp = k + (size_t)(b * SLEN + j0 + krow) * DMODEL + h * DHEAD + kc0;
      char* bh_ = (char*)Ks_hi + krow * 256;
      char* bl_ = (char*)Ks_lo + krow * 256;
      const int sw = (krow & 7) << 4;
      #pragma unroll
      for (int e = 0; e < 2; ++e) {
        f32x4 xv = *(const f32x4*)(kp + e * 4);
        f16x4 hi, lo;
        #pragma unroll
        for (int u = 0; u < 4; ++u) {
          _Float16 hh = (_Float16)xv[u];
          hi[u] = hh; lo[u] = (_Float16)(xv[u] - (float)hh);
        }
        const int bc = (kc0 + e * 4) * 2;
        *(f16x4*)(bh_ + (bc ^ sw)) = hi;
        *(f16x4*)(bl_ + (bc ^ sw)) = lo;
      }
    }
    // ---- stage V (1024 thr: 8 j's each), packed 16B swizzled store ----
    {
      const int d = tid & 127;
      const int jq = tid >> 7;              // 0..7 (8 j each)
      const float* vp = v + (size_t)(b * SLEN + j0 + jq * 8) * DMODEL + h * DHEAD + d;
      float vv[8];
      #pragma unroll
      for (int jj = 0; jj < 8; ++jj)
        vv[jj] = vp[(size_t)jj * DMODEL];
      int pv[4];
      #pragma unroll
      for (int p = 0; p < 4; ++p) pv[p] = pk16(vv[2 * p], vv[2 * p + 1]);
      const int sw = (d & 7) << 4;
      const int b0 = d * 128 + jq * 16;
      *(f32x4*)((char*)Vts + (b0 ^ sw)) = *(f32x4*)&pv[0];
    }
    if (tid < BKT) a_s[tid] = a_g[bh * SLEN + j0 + tid];
    __syncthreads();

    if (pss <= tt) {
      // ---- swapped QK^T (3-leg split) ----
      f32x4 sacc[2];
      sacc[0] = z4; sacc[1] = z4;
      #pragma unroll
      for (int ks = 0; ks < 4; ++ks) {
        const int bc = ks * 64 + lg * 16;
        #pragma unroll
        for (int jfl = 0; jfl < 2; ++jfl) {
          const int arow = wc * 32 + jfl * 16 + l15;
          const int sw = (arow & 7) << 4;
          f16x8 kh8 = *(const f16x8*)((char*)Ks_hi + arow * 256 + (bc ^ sw));
          f16x8 kl8 = *(const f16x8*)((char*)Ks_lo + arow * 256 + (bc ^ sw));
          sacc[jfl] = __builtin_amdgcn_mfma_f32_16x16x32_f16(kh8, qh[ks], sacc[jfl], 0, 0, 0);
          sacc[jfl] = __builtin_amdgcn_mfma_f32_16x16x32_f16(kl8, qh[ks], sacc[jfl], 0, 0, 0);
          sacc[jfl] = __builtin_amdgcn_mfma_f32_16x16x32_f16(kh8, ql[ks], sacc[jfl], 0, 0, 0);
        }
      }
      // ---- decay + mask + rowsum (per-element exp, mask idle off-diag) ----
      float vals[2][4];
      {
        const int iG = i0 + wr * 16 + l15;
        #pragma unroll
        for (int jfl = 0; jfl < 2; ++jfl)
          #pragma unroll
          for (int r = 0; r < 4; ++r) {
            const int jl = wc * 32 + jfl * 16 + lg * 4 + r;
            float e = __expf(fminf(a_s[jl] - m_reg, 0.f));
            float vv = sacc[jfl][r] * e;
            if (j0 + jl > iG) vv = 0.f;
            ps += vv;
            vals[jfl][r] = vv;
          }
      }
      // ---- pack + repack to PV A-frag via bpermute ----
      const int lgand1 = lg & 1;
      const int idxA = (l15 + 16 * (2 * lgand1 + 0)) * 4;
      const int idxB = (l15 + 16 * (2 * lgand1 + 1)) * 4;
      const bool hi_half = ((lane & 63) >= 32);
      int c2[2][2];
      #pragma unroll
      for (int jfl = 0; jfl < 2; ++jfl) {
        c2[jfl][0] = pk16(vals[jfl][0], vals[jfl][1]);
        c2[jfl][1] = pk16(vals[jfl][2], vals[jfl][3]);
      }
      int pa32[4];
      #pragma unroll
      for (int p = 0; p < 4; ++p) {
        const int idx2 = (p < 2) ? idxA : idxB;
        int f0 = __builtin_amdgcn_ds_bpermute(idx2, c2[0][p & 1]);
        int f1 = __builtin_amdgcn_ds_bpermute(idx2, c2[1][p & 1]);
        pa32[p] = hi_half ? f1 : f0;
      }
      union { int i[4]; f16x8 v; } pu;
      pu.i[0] = pa32[0]; pu.i[1] = pa32[1]; pu.i[2] = pa32[2]; pu.i[3] = pa32[3];
      const f16x8 paf = pu.v;

      // ---- PV ----
      const int vbc = wc * 64 + lg * 16;
      #pragma unroll
      for (int cf = 0; cf < 8; ++cf) {
        const int vrow = cf * 16 + l15;
        const int sw = (vrow & 7) << 4;
        f16x8 vb8 = *(const f16x8*)((char*)Vts + vrow * 128 + (vbc ^ sw));
        hacc[cf] = __builtin_amdgcn_mfma_f32_16x16x32_f16(paf, vb8, hacc[cf], 0, 0, 0);
      }
    }
  }
  __syncthreads();   // all LDS reads done before epilogue reuses pool

  // ================= Epilogue (R8-verified, two tt-phases) ==================
  ps += __shfl_xor(ps, 16);
  ps += __shfl_xor(ps, 32);
  if (lane < 16) rs_lds[(tt * 64 + wr * 16 + l15) * 2 + wc] = ps;
  if (tt == 0 && wc == 1) {
    #pragma unroll
    for (int cf = 0; cf < 8; ++cf)
      *(f32x4*)&hex[wr * 2048 + cf * 256 + lane * 4] = hacc[cf];
  }
  __syncthreads();
  if (tt == 0 && wc == 0) {
    #pragma unroll
    for (int cf = 0; cf < 8; ++cf) {
      f32x4 o = *(const f32x4*)&hex[wr * 2048 + cf * 256 + lane * 4];
      hacc[cf][0] += o[0]; hacc[cf][1] += o[1];
      hacc[cf][2] += o[2]; hacc[cf][3] += o[3];
    }
    const float rsum = rs_lds[(wr * 16 + l15) * 2 + 0] + rs_lds[(wr * 16 + l15) * 2 + 1];
    const float inv = 1.0f / (fmaxf(fabsf(rsum), fl_reg) + 1e-6f);
    union { float f; int i; } uc; uc.f = inv;
    float invr[4];
    #pragma unroll
    for (int r = 0; r < 4; ++r) {
      union { float f; int i; } ur;
      ur.i = __builtin_amdgcn_ds_bpermute((lg * 4 + r) * 4, uc.i);
      invr[r] = ur.f;
    }
    #pragma unroll
    for (int r = 0; r < 4; ++r) {
      const size_t orow = (size_t)(b * SLEN + i0 + wr * 16 + lg * 4 + r) * DMODEL + h * DHEAD;
      #pragma unroll
      for (int cf = 0; cf < 8; ++cf)
        out[orow + cf * 16 + l15] = hacc[cf][r] * invr[r];
    }
  }
  __syncthreads();
  if (tt == 1 && wc == 1) {
    #pragma unroll
    for (int cf = 0; cf < 8; ++cf)
      *(f32x4*)&hex[wr * 2048 + cf * 256 + lane * 4] = hacc[cf];
  }
  __syncthreads();
  if (tt == 1 && wc == 0) {
    #pragma unroll
    for (int cf = 0; cf < 8; ++cf) {
      f32x4 o = *(const f32x4*)&hex[wr * 2048 + cf * 256 + lane * 4];
      hacc[cf][0] += o[0]; hacc[cf][1] += o[1];
      hacc[cf][2] += o[2]; hacc[cf][3] += o[3];
    }
    const float rsum = rs_lds[(64 + wr * 16 + l15) * 2 + 0] + rs_lds[(64 + wr * 16 + l15) * 2 + 1];
    const float inv = 1.0f / (fmaxf(fabsf(rsum), fl_reg) + 1e-6f);
    union { float f; int i; } uc; uc.f = inv;
    float invr[4];
    #pragma unroll
    for (int r = 0; r < 4; ++r) {
      union { float f; int i; } ur;
      ur.i = __builtin_amdgcn_ds_bpermute((lg * 4 + r) * 4, uc.i);
      invr[r] = ur.f;
    }
    #pragma unroll
    for (int r = 0; r < 4; ++r) {
      const size_t orow = (size_t)(b * SLEN + i0 + wr * 16 + lg * 4 + r) * DMODEL + h * DHEAD;
      #pragma unroll
      for (int cf = 0; cf < 8; ++cf)
        out[orow + cf * 16 + l15] = hacc[cf][r] * invr[r];
    }
  }
}

// ---------------- Fallback: R8 mlstm_main (verified, ws-light) --------------
__global__ __launch_bounds__(512)
void mlstm_main(const float* __restrict__ q, const float* __restrict__ k,
                const float* __restrict__ v, const float* __restrict__ a_g,
                const float* __restrict__ ms_g, const float* __restrict__ fl_g,
                const float* __restrict__ mt_g, float* __restrict__ out) {
  __shared__ __align__(16) char pool[50176];
  _Float16* Ks_hi = (_Float16*)pool;
  _Float16* Ks_lo = (_Float16*)(pool + 16384);
  _Float16* Vts   = (_Float16*)(pool + 32768);
  float* a_s      = (float*)(pool + 49152);
  float* rs_lds   = (float*)(pool + 49408);
  float* hex      = (float*)pool;

  const int bid = blockIdx.x;
  int t, bh;
  if (bid < 256) { t = 31 - (bid >> 4); bh = bid & 15; }
  else           { t = (bid - 256) >> 4; bh = (bid - 256) & 15; }
  const int b = bh >> 3, h = bh & 7;
  const int i0 = t * BM;
  const int tid = threadIdx.x;
  const int lane = tid & 63;
  const int wid = tid >> 6;
  const int wr = wid >> 1;
  const int wc = wid & 1;
  const int l15 = lane & 15;
  const int lg = lane >> 4;
  const f32x4 z4 = {0.f, 0.f, 0.f, 0.f};

  f16x8 qh[4], ql[4];
  {
    const float* qbase = q + (size_t)(b * SLEN + i0 + wr * 16 + l15) * DMODEL + h * DHEAD;
    #pragma unroll
    for (int ks = 0; ks < 4; ++ks) {
      f32x4 x0 = *(const f32x4*)(qbase + ks * 32 + lg * 8);
      f32x4 x1 = *(const f32x4*)(qbase + ks * 32 + lg * 8 + 4);
      f16x8 hi, lo;
      #pragma unroll
      for (int e = 0; e < 4; ++e) {
        float s0 = x0[e] * QSCALE, s1 = x1[e] * QSCALE;
        _Float16 h0 = (_Float16)s0, h1 = (_Float16)s1;
        hi[e] = h0;     hi[e + 4] = h1;
        lo[e] = (_Float16)(s0 - (float)h0);
        lo[e + 4] = (_Float16)(s1 - (float)h1);
      }
      qh[ks] = hi; ql[ks] = lo;
    }
  }
  const float m_reg = ms_g[bh * SLEN + i0 + wr * 16 + l15];
  const float fl_reg = fl_g[bh * SLEN + i0 + wr * 16 + l15];
  const int lgand1 = lg & 1;
  const int idxA = (l15 + 16 * (2 * lgand1 + 0)) * 4;
  const int idxB = (l15 + 16 * (2 * lgand1 + 1)) * 4;
  const bool hi_half = (lane >= 32);

  f32x4 hacc[8];
  #pragma unroll
  for (int cf = 0; cf < 8; ++cf) hacc[cf] = z4;
  float ps = 0.f;

  const int krow = tid >> 3;
  const int kc0 = (tid & 7) * 16;
  const int vdv = tid & 127;
  const int vjq = tid >> 7;

  for (int jt = 0; jt <= t; ++jt) {
    const int j0 = jt * BKT;
    const bool diag = (jt == t);
    const float mt = mt_g[bh * 32 + jt];
    {
      float es = 1.f;
      if (!diag) es = __expf(a_g[bh * SLEN + j0 + krow] - mt);
      const float* kp = k + (size_t)(b * SLEN + j0 + krow) * DMODEL + h * DHEAD + kc0;
      char* bh_ = (char*)Ks_hi + krow * 256;
      char* bl_ = (char*)Ks_lo + krow * 256;
      const int sw = (krow & 7) << 4;
      #pragma unroll
      for (int e = 0; e < 4; ++e) {
        f32x4 xv = *(const f32x4*)(kp + e * 4);
        f16x4 hi, lo;
        #pragma unroll
        for (int u = 0; u < 4; ++u) {
          float vv = xv[u] * es;
          _Float16 hh = (_Float16)vv;
          hi[u] = hh; lo[u] = (_Float16)(vv - (float)hh);
        }
        const int bc = (kc0 + e * 4) * 2;
        *(f16x4*)(bh_ + (bc ^ sw)) = hi;
        *(f16x4*)(bl_ + (bc ^ sw)) = lo;
      }
    }
    {
      const float* vp = v + (size_t)(b * SLEN + j0 + vjq * 16) * DMODEL + h * DHEAD + vdv;
      float vv[16];
      #pragma unroll
      for (int jj = 0; jj < 16; ++jj)
        vv[jj] = vp[(size_t)jj * DMODEL];
      int pk[8];
      #pragma unroll
      for (int p = 0; p < 8; ++p) pk[p] = pk16(vv[2 * p], vv[2 * p + 1]);
      const int sw = (vdv & 7) << 4;
      *(f32x4*)((char*)Vts + ((vdv * 128 + vjq * 32 + 0) ^ sw)) = *(f32x4*)&pk[0];
      *(f32x4*)((char*)Vts + ((vdv * 128 + vjq * 32 + 16) ^ sw)) = *(f32x4*)&pk[4];
    }
    if (diag && tid < BKT) a_s[tid] = a_g[bh * SLEN + j0 + tid];
    __syncthreads();

    f32x4 sacc[2];
    sacc[0] = z4; sacc[1] = z4;
    #pragma unroll
    for (int ks = 0; ks < 4; ++ks) {
      const int bc = ks * 64 + lg * 16;
      #pragma unroll
      for (int jfl = 0; jfl < 2; ++jfl) {
        const int arow = wc * 32 + jfl * 16 + l15;
        const int sw = (arow & 7) << 4;
        f16x8 kh8 = *(const f16x8*)((char*)Ks_hi + arow * 256 + (bc ^ sw));
        f16x8 kl8 = *(const f16x8*)((char*)Ks_lo + arow * 256 + (bc ^ sw));
        sacc[jfl] = __builtin_amdgcn_mfma_f32_16x16x32_f16(kh8, qh[ks], sacc[jfl], 0, 0, 0);
        sacc[jfl] = __builtin_amdgcn_mfma_f32_16x16x32_f16(kl8, qh[ks], sacc[jfl], 0, 0, 0);
        sacc[jfl] = __builtin_amdgcn_mfma_f32_16x16x32_f16(kh8, ql[ks], sacc[jfl], 0, 0, 0);
      }
    }
    float vals[2][4];
    if (diag) {
      const int iG = i0 + wr * 16 + l15;
      #pragma unroll
      for (int jfl = 0; jfl < 2; ++jfl)
        #pragma unroll
        for (int r = 0; r < 4; ++r) {
          const int jl = wc * 32 + jfl * 16 + lg * 4 + r;
          float e = __expf(fminf(a_s[jl] - m_reg, 0.f));
          float vv = sacc[jfl][r] * e;
          if (j0 + jl > iG) vv = 0.f;
          vals[jfl][r] = vv;
        }
    } else {
      const float em = __expf(fminf(mt - m_reg, 0.f));
      #pragma unroll
      for (int jfl = 0; jfl < 2; ++jfl)
        #pragma unroll
        for (int r = 0; r < 4; ++r)
          vals[jfl][r] = sacc[jfl][r] * em;
    }
    #pragma unroll
    for (int jfl = 0; jfl < 2; ++jfl)
      #pragma unroll
      for (int r = 0; r < 4; ++r) ps += vals[jfl][r];

    int c2[2][2];
    #pragma unroll
    for (int jfl = 0; jfl < 2; ++jfl) {
      c2[jfl][0] = pk16(vals[jfl][0], vals[jfl][1]);
      c2[jfl][1] = pk16(vals[jfl][2], vals[jfl][3]);
    }
    int pa32[4];
    #pragma unroll
    for (int p = 0; p < 4; ++p) {
      const int idx = (p < 2) ? idxA : idxB;
      int f0 = __builtin_amdgcn_ds_bpermute(idx, c2[0][p & 1]);
      int f1 = __builtin_amdgcn_ds_bpermute(idx, c2[1][p & 1]);
      pa32[p] = hi_half ? f1 : f0;
    }
    union { int i[4]; f16x8 v; } pu;
    pu.i[0] = pa32[0]; pu.i[1] = pa32[1]; pu.i[2] = pa32[2]; pu.i[3] = pa32[3];
    const f16x8 paf = pu.v;

    const int vbc = wc * 64 + lg * 16;
    #pragma unroll
    for (int cf = 0; cf < 8; ++cf) {
      const int vrow = cf * 16 + l15;
      const int sw = (vrow & 7) << 4;
      f16x8 vb8 = *(const f16x8*)((char*)Vts + vrow * 128 + (vbc ^ sw));
      hacc[cf] = __builtin_amdgcn_mfma_f32_16x16x32_f16(paf, vb8, hacc[cf], 0, 0, 0);
    }
    __syncthreads();
  }

  ps += __shfl_xor(ps, 16);
  ps += __shfl_xor(ps, 32);
  if (lane < 16) rs_lds[(wr * 16 + l15) * 2 + wc] = ps;
  if (wc == 1) {
    #pragma unroll
    for (int cf = 0; cf < 8; ++cf)
      *(f32x4*)&hex[wr * 2048 + cf * 256 + lane * 4] = hacc[cf];
  }
  __syncthreads();
  if (wc == 0) {
    #pragma unroll
    for (int cf = 0; cf < 8; ++cf) {
      f32x4 o = *(const f32x4*)&hex[wr * 2048 + cf * 256 + lane * 4];
      hacc[cf][0] += o[0]; hacc[cf][1] += o[1];
      hacc[cf][2] += o[2]; hacc[cf][3] += o[3];
    }
    const float rsum = rs_lds[(wr * 16 + l15) * 2 + 0] + rs_lds[(wr * 16 + l15) * 2 + 1];
    const float inv = 1.0f / (fmaxf(fabsf(rsum), fl_reg) + 1e-6f);
    union { float f; int i; } uc; uc.f = inv;
    float invr[4];
    #pragma unroll
    for (int r = 0; r < 4; ++r) {
      union { float f; int i; } ur;
      ur.i = __builtin_amdgcn_ds_bpermute((lg * 4 + r) * 4, uc.i);
      invr[r] = ur.f;
    }
    #pragma unroll
    for (int r = 0; r < 4; ++r) {
      const size_t orow = (size_t)(b * SLEN + i0 + wr * 16 + lg * 4 + r) * DMODEL + h * DHEAD;
      #pragma unroll
      for (int cf = 0; cf < 8; ++cf)
        out[orow + cf * 16 + l15] = hacc[cf][r] * invr[r];
    }
  }
}

// ---------------- Kernel 4: in-place LayerNorm on d_out ---------------------
__global__ __launch_bounds__(256)
void ln_kernel(float* __restrict__ out, const float* __restrict__ gamma) {
  const int row = blockIdx.x;
  const int tid = threadIdx.x;
  float* x = out + (size_t)row * DMODEL;
  f32x4 xv = ((const f32x4*)x)[tid];
  float s = xv[0] + xv[1] + xv[2] + xv[3];
  float qq = xv[0] * xv[0] + xv[1] * xv[1] + xv[2] * xv[2] + xv[3] * xv[3];
  #pragma unroll
  for (int m = 1; m < 64; m <<= 1) { s += __shfl_xor(s, m); qq += __shfl_xor(qq, m); }
  __shared__ float ss[4], sq[4];
  const int wid = tid >> 6;
  if ((tid & 63) == 0) { ss[wid] = s; sq[wid] = qq; }
  __syncthreads();
  s = ss[0] + ss[1] + ss[2] + ss[3];
  qq = sq[0] + sq[1] + sq[2] + sq[3];
  const float mu = s * (1.f / 1024.f);
  const float var = qq * (1.f / 1024.f) - mu * mu;
  const float rstd = rsqrtf(var + 1e-5f);
  f32x4 g = ((const f32x4*)gamma)[tid];
  f32x4 ov;
  ov[0] = (xv[0] - mu) * rstd * g[0];
  ov[1] = (xv[1] - mu) * rstd * g[1];
  ov[2] = (xv[2] - mu) * rstd * g[2];
  ov[3] = (xv[3] - mu) * rstd * g[3];
  ((f32x4*)x)[tid] = ov;
}

extern "C" void kernel_launch(void* const* d_in, const int* in_sizes, int n_in,
                              void* d_out, int out_size, void* d_ws, size_t ws_size,
                              hipStream_t stream) {
  (void)in_sizes; (void)n_in; (void)out_size;
  const float* q   = (const float*)d_in[0];
  const float* k   = (const float*)d_in[1];
  const float* v   = (const float*)d_in[2];
  const float* igw = (const float*)d_in[3];
  const float* igb = (const float*)d_in[4];
  const float* fgw = (const float*)d_in[5];
  const float* fgb = (const float*)d_in[6];
  const float* lns = (const float*)d_in[7];
  float* out = (float*)d_out;

  float* gpre  = (float*)d_ws;           // 65536 f32
  float* a_g   = gpre + 65536;           // 32768
  float* ms_g  = a_g + 32768;            // 32768
  float* fl_g  = ms_g + 32768;           // 32768
  float* mt64  = fl_g + 32768;           // 512   (16 x 32)
  float* mt128 = mt64 + 512;             // 256   (16 x 16)
  float* Mg_g  = mt128 + 256;            // 256
  float* pkt   = Mg_g + 256;             // 32768 (256 x 128)
  float* pkx   = pkt + 32768;            // 32768
  unsigned short* GXs = (unsigned short*)(pkx + 32768);  // 256 x 16384 fp16 = 8MB
  // total ≈ 9.31 MB

  const bool big = ws_size >= (size_t)10 * 1024 * 1024;

  gates_kernel<<<dim3(256), dim3(512), 0, stream>>>(q, k, v, igw, fgw, gpre);
  scan_kernel<<<dim3(16), dim3(256), 0, stream>>>(gpre, igb, fgb, a_g, ms_g, fl_g,
                                                  mt64, mt128, Mg_g);
  if (big) {
    p1_kernel<<<dim3(16, 16), dim3(512), 0, stream>>>(k, v, a_g, mt128, GXs, pkt);
    p2_kernel<<<dim3(9, 16), dim3(256), 0, stream>>>(mt128, GXs, pkt, pkx);
    p3_kernel<<<dim3(256), dim3(1024), 0, stream>>>(q, k, v, a_g, ms_g, fl_g,
                                                    Mg_g, pkx, GXs, out);
  } else {
    mlstm_main<<<dim3(512), dim3(512), 0, stream>>>(q, k, v, a_g, ms_g, fl_g, mt64, out);
  }
  ln_kernel<<<dim3(4096), dim3(256), 0, stream>>>(out, lns);
}

// Round 19
// 81.061 us; speedup vs baseline: 1.0284x; 1.0229x over previous
//
#include <hip/hip_runtime.h>
#include <hip/hip_bf16.h>

#define SLEN 2048
#define DMODEL 1024
#define NHEAD 8
#define DHEAD 128
#define BM 64
#define BKT 64
#define QSCALE 0.08838834764831845f  // 1/sqrt(128)

typedef __attribute__((ext_vector_type(4))) float f32x4;
typedef __attribute__((ext_vector_type(8))) _Float16 f16x8;
typedef __attribute__((ext_vector_type(4))) _Float16 f16x4;
typedef __attribute__((ext_vector_type(2))) _Float16 f16x2;

static __device__ __forceinline__ int pk16(float a, float b) {
  f16x2 t; t[0] = (_Float16)a; t[1] = (_Float16)b;
  union { f16x2 h; int i; } u; u.h = t; return u.i;
}
static __device__ __forceinline__ unsigned short f16bits(float x) {
  union { _Float16 h; unsigned short u; } u2; u2.h = (_Float16)x; return u2.u;
}

// ---------------- Kernel 1: gate preactivations via MFMA (R16, verified) ----
__global__ __launch_bounds__(512)
void gates_kernel(const float* __restrict__ q, const float* __restrict__ k,
                  const float* __restrict__ v, const float* __restrict__ igw,
                  const float* __restrict__ fgw, float* __restrict__ gpre) {
  __shared__ float red[8][16][16];
  const int row0 = blockIdx.x * 16;
  const int tid = threadIdx.x;
  const int lane = tid & 63, wid = tid >> 6;
  const int l15 = lane & 15, lg = lane >> 4;
  const f32x4 z4 = {0.f, 0.f, 0.f, 0.f};
  f32x4 acc = z4;
  const float* wbase = (l15 < 8) ? (igw + (size_t)l15 * 3072)
                                 : (fgw + (size_t)(l15 - 8) * 3072);
  #pragma unroll
  for (int ks = 0; ks < 12; ++ks) {
    const int kk = wid * 384 + ks * 32 + lg * 8;   // lane k base
    const int seg = kk >> 10;
    const int col = kk & 1023;
    const float* src = (seg == 0) ? q : (seg == 1) ? k : v;
    const float* xp = src + (size_t)(row0 + l15) * 1024 + col;
    f32x4 a0 = *(const f32x4*)xp;
    f32x4 a1 = *(const f32x4*)(xp + 4);
    f32x4 b0 = *(const f32x4*)(wbase + kk);
    f32x4 b1 = *(const f32x4*)(wbase + kk + 4);
    f16x8 ah, al, bhf, blf;
    #pragma unroll
    for (int e = 0; e < 4; ++e) {
      _Float16 h0 = (_Float16)a0[e], h1 = (_Float16)a1[e];
      ah[e] = h0; ah[e + 4] = h1;
      al[e] = (_Float16)(a0[e] - (float)h0);
      al[e + 4] = (_Float16)(a1[e] - (float)h1);
      _Float16 g0 = (_Float16)b0[e], g1 = (_Float16)b1[e];
      bhf[e] = g0; bhf[e + 4] = g1;
      blf[e] = (_Float16)(b0[e] - (float)g0);
      blf[e + 4] = (_Float16)(b1[e] - (float)g1);
    }
    acc = __builtin_amdgcn_mfma_f32_16x16x32_f16(ah, bhf, acc, 0, 0, 0);
    acc = __builtin_amdgcn_mfma_f32_16x16x32_f16(al, bhf, acc, 0, 0, 0);
    acc = __builtin_amdgcn_mfma_f32_16x16x32_f16(ah, blf, acc, 0, 0, 0);
  }
  #pragma unroll
  for (int r = 0; r < 4; ++r)
    red[wid][lg * 4 + r][l15] = acc[r];
  __syncthreads();
  if (tid < 256) {
    const int xrow = tid >> 4, g = tid & 15;
    float s = 0.f;
    #pragma unroll
    for (int w = 0; w < 8; ++w) s += red[w][xrow][g];
    gpre[(size_t)g * 4096 + row0 + xrow] = s;
  }
}

// ---------------- Kernel 2: scans + chunk maxima (64 and 128) ---------------
__global__ __launch_bounds__(256)
void scan_kernel(const float* __restrict__ gpre, const float* __restrict__ igb,
                 const float* __restrict__ fgb, float* __restrict__ a_out,
                 float* __restrict__ ms_out, float* __restrict__ fl_out,
                 float* __restrict__ mt64, float* __restrict__ mt128,
                 float* __restrict__ Mg_out) {
  const int bh = blockIdx.x;
  const int h = bh & 7;
  const int b = bh >> 3;
  const int tid = threadIdx.x;
  __shared__ double sbd[256];
  __shared__ float sbf[256];
  __shared__ float mt_l[16];
  const int base = b * 2048 + tid * 8;
  const float ig_b = igb[h], fg_b = fgb[h];
  double cs[8];
  float av[8];
  double tot = 0.0;
  #pragma unroll
  for (int e = 0; e < 8; ++e) {
    float x = gpre[(size_t)(8 + h) * 4096 + base + e] + fg_b;
    float l = fminf(x, 0.f) - log1pf(__expf(-fabsf(x)));   // log_sigmoid
    tot += (double)l;
    cs[e] = tot;
  }
  sbd[tid] = tot;
  __syncthreads();
  if (tid == 0) {
    double run = 0.0;
    for (int i = 0; i < 256; ++i) { double t2 = sbd[i]; sbd[i] = run; run += t2; }
  }
  __syncthreads();
  const double excl = sbd[tid];
  float mtot = -3.4e38f;
  #pragma unroll
  for (int e = 0; e < 8; ++e) {
    cs[e] += excl;
    float ig = gpre[(size_t)h * 4096 + base + e] + ig_b;
    av[e] = (float)((double)ig - cs[e]);
    mtot = fmaxf(mtot, av[e]);
  }
  // per-64 and per-128 window maxima
  {
    float w8 = mtot;
    w8 = fmaxf(w8, __shfl_xor(w8, 1));
    w8 = fmaxf(w8, __shfl_xor(w8, 2));
    w8 = fmaxf(w8, __shfl_xor(w8, 4));
    if ((tid & 7) == 0) mt64[bh * 32 + (tid >> 3)] = w8;
    float w16 = fmaxf(w8, __shfl_xor(w8, 8));
    if ((tid & 15) == 0) { mt128[bh * 16 + (tid >> 4)] = w16; mt_l[tid >> 4] = w16; }
  }
  sbf[tid] = mtot;
  __syncthreads();
  if (tid == 0) {
    float run = -3.4e38f;
    for (int i = 0; i < 256; ++i) { float t2 = sbf[i]; sbf[i] = run; run = fmaxf(run, t2); }
    float M = -3.4e38f;
    for (int c = 0; c < 16; ++c) { Mg_out[bh * 16 + c] = M; M = fmaxf(M, mt_l[c]); }
  }
  __syncthreads();
  float run = sbf[tid];
  const int obase = bh * 2048 + tid * 8;
  #pragma unroll
  for (int e = 0; e < 8; ++e) {
    run = fmaxf(run, av[e]);
    a_out[obase + e] = av[e];
    ms_out[obase + e] = run;
    fl_out[obase + e] = __expf(-(float)(cs[e] + (double)run));  // exp(-max_log_D)
  }
}

// ---------------- Kernel P1: per-128-chunk state G[dv][dk] (fp16) + ksum ----
__global__ __launch_bounds__(512)
void p1_kernel(const float* __restrict__ k, const float* __restrict__ v,
               const float* __restrict__ a_g, const float* __restrict__ mt128,
               unsigned short* __restrict__ GXs, float* __restrict__ pkt) {
  __shared__ __align__(16) char pool[33280];
  _Float16* Kts = (_Float16*)pool;             // [128 dk][64 j] 128B rows, swz
  _Float16* Vts = (_Float16*)(pool + 16384);   // [128 dv][64 j]
  float* w_s = (float*)(pool + 32768);         // [128]
  const int c = blockIdx.x, bh = blockIdx.y;
  const int b = bh >> 3, h = bh & 7;
  const int tid = threadIdx.x;
  const int lane = tid & 63, wid = tid >> 6;
  const int l15 = lane & 15, lg = lane >> 4;
  if (tid < 128) w_s[tid] = __expf(a_g[bh * SLEN + c * 128 + tid] - mt128[bh * 16 + c]);
  const f32x4 z4 = {0.f, 0.f, 0.f, 0.f};
  f32x4 acc[8];
  #pragma unroll
  for (int i = 0; i < 8; ++i) acc[i] = z4;
  float ks_acc = 0.f;
  for (int p = 0; p < 2; ++p) {
    const int j0 = c * 128 + p * 64;
    __syncthreads();   // w_s ready (p=0); prior pass reads done (p=1)
    {
      const int d = tid & 127;
      const int jq = tid >> 7;                 // 0..3 (16 j each)
      const size_t rowb = (size_t)(b * SLEN + j0 + jq * 16) * DMODEL + h * DHEAD + d;
      float kv[16], vv[16];
      #pragma unroll
      for (int jj = 0; jj < 16; ++jj) {
        kv[jj] = k[rowb + (size_t)jj * DMODEL] * w_s[p * 64 + jq * 16 + jj];
        vv[jj] = v[rowb + (size_t)jj * DMODEL];
      }
      int ph[8], pv[8];
      #pragma unroll
      for (int pp = 0; pp < 8; ++pp) {
        ph[pp] = pk16(kv[2 * pp], kv[2 * pp + 1]);
        pv[pp] = pk16(vv[2 * pp], vv[2 * pp + 1]);
      }
      const int sw = (d & 7) << 4;
      const int b0 = d * 128 + jq * 32;
      *(f32x4*)((char*)Kts + ((b0 + 0) ^ sw))  = *(f32x4*)&ph[0];
      *(f32x4*)((char*)Kts + ((b0 + 16) ^ sw)) = *(f32x4*)&ph[4];
      *(f32x4*)((char*)Vts + ((b0 + 0) ^ sw))  = *(f32x4*)&pv[0];
      *(f32x4*)((char*)Vts + ((b0 + 16) ^ sw)) = *(f32x4*)&pv[4];
    }
    __syncthreads();
    f16x8 avv[2];
    {
      const int row = wid * 16 + l15;
      const int sw = (l15 & 7) << 4;
      avv[0] = *(const f16x8*)((char*)Vts + row * 128 + ((lg * 16) ^ sw));
      avv[1] = *(const f16x8*)((char*)Vts + row * 128 + ((64 + lg * 16) ^ sw));
    }
    #pragma unroll
    for (int dkt = 0; dkt < 8; ++dkt) {
      const int row = dkt * 16 + l15;
      const int sw = (l15 & 7) << 4;
      #pragma unroll
      for (int ks = 0; ks < 2; ++ks) {
        const int bc = ks * 64 + lg * 16;
        f16x8 bh8 = *(const f16x8*)((char*)Kts + row * 128 + (bc ^ sw));
        acc[dkt] = __builtin_amdgcn_mfma_f32_16x16x32_f16(avv[ks], bh8, acc[dkt], 0, 0, 0);
      }
    }
    if (tid < 128) {   // ksum partial over this pass's 64 j
      const int sw = (tid & 7) << 4;
      #pragma unroll
      for (int g = 0; g < 8; ++g) {
        f16x8 hh = *(const f16x8*)((char*)Kts + tid * 128 + ((g * 16) ^ sw));
        #pragma unroll
        for (int e = 0; e < 8; ++e) ks_acc += (float)hh[e];
      }
    }
  }
  unsigned short* gxs = GXs + (size_t)(bh * 16 + c) * 16384;
  #pragma unroll
  for (int dkt = 0; dkt < 8; ++dkt)
    #pragma unroll
    for (int r = 0; r < 4; ++r)
      gxs[(wid * 16 + lg * 4 + r) * 128 + dkt * 16 + l15] = f16bits(acc[dkt][r]);
  if (tid < 128) pkt[(size_t)(bh * 16 + c) * 128 + tid] = ks_acc;
}

// ---------------- Kernel P2: exclusive prefix states (in-place, fp16) -------
__global__ __launch_bounds__(256)
void p2_kernel(const float* __restrict__ mt128, unsigned short* __restrict__ GXs,
               const float* __restrict__ pkt, float* __restrict__ pkx) {
  const int s = blockIdx.x, bh = blockIdx.y;
  const int tid = threadIdx.x;
  union U8 { uint4 q; _Float16 h[8]; };
  if (s < 8) {
    unsigned short* base = GXs + (size_t)bh * 16 * 16384 + s * 2048 + tid * 8;
    float X[8];
    #pragma unroll
    for (int e = 0; e < 8; ++e) X[e] = 0.f;
    float Mm1 = -3.4e38f;
    for (int c = 0; c < 16; ++c) {
      U8 cu; cu.q = *(const uint4*)(base + (size_t)c * 16384);
      const float mtc = mt128[bh * 16 + c];
      const float Mc = fmaxf(Mm1, mtc);
      const float s1 = __expf(Mm1 - Mc), s2 = __expf(mtc - Mc);
      U8 ou;
      #pragma unroll
      for (int e = 0; e < 8; ++e) ou.h[e] = (_Float16)X[e];
      *(uint4*)(base + (size_t)c * 16384) = ou.q;
      #pragma unroll
      for (int e = 0; e < 8; ++e) X[e] = X[e] * s1 + (float)cu.h[e] * s2;
      Mm1 = Mc;
    }
  } else if (tid < 128) {
    const float* pb = pkt + (size_t)bh * 16 * 128 + tid;
    float X = 0.f, Mm1 = -3.4e38f;
    for (int c = 0; c < 16; ++c) {
      const float g = pb[(size_t)c * 128];
      const float mtc = mt128[bh * 16 + c];
      const float Mc = fmaxf(Mm1, mtc);
      pkx[(size_t)bh * 16 * 128 + (size_t)c * 128 + tid] = X;
      X = X * __expf(Mm1 - Mc) + g * __expf(mtc - Mc);
      Mm1 = Mc;
    }
  }
}

// ---------------- Kernel P3: merged pair, single-barrier staging (R19) ------
// All global loads (Q frags, X, KV pass0+pass1 double-buffered, a, pks) issue
// BEFORE one barrier; then phase B + both phase-A passes run with no
// intervening barriers (distinct LDS buffers). Barriers 9 -> 6; stage-phase
// memory parallelism ~3x. LDS 130KB (1 block/CU, same residency as before).
__global__ __launch_bounds__(1024)
__attribute__((amdgpu_waves_per_eu(4, 4)))
void p3_kernel(const float* __restrict__ q, const float* __restrict__ k,
               const float* __restrict__ v, const float* __restrict__ a_g,
               const float* __restrict__ ms_g, const float* __restrict__ fl_g,
               const float* __restrict__ Mg_g, const float* __restrict__ pkx,
               const unsigned short* __restrict__ GXs, float* __restrict__ out) {
  __shared__ __align__(16) char pool[133120];
  // buf(pss) at pool + pss*49152: Ks_hi @+0, Ks_lo @+16384, Vts @+32768
  // X fp16 [128][128] swz @98304 (32KB); a_s0 @131072, a_s1 @131328;
  // rs_lds @131584 ([128][2] f32); pks @132608; hex overlays pool[0..32K].
  float* a_s0   = (float*)(pool + 131072);
  float* a_s1   = (float*)(pool + 131328);
  float* rs_lds = (float*)(pool + 131584);
  float* pks    = (float*)(pool + 132608);
  float* hex    = (float*)pool;
  char* const Xb = pool + 98304;

  const int bid = blockIdx.x;
  const int c = bid & 15;
  const int bh = bid >> 4;
  const int b = bh >> 3, h = bh & 7;
  const int tid = threadIdx.x;
  const int lane = tid & 63;
  const int wid = tid >> 6;          // 0..15
  const int tt = wid >> 3;           // 0..1: tile t = 2c+tt
  const int wr = (wid >> 1) & 3;     // 16-row group
  const int wc = wid & 1;            // half split (j in A, dk in B)
  const int l15 = lane & 15;
  const int lg = lane >> 4;
  const int t = 2 * c + tt;
  const int i0 = t * BM;
  const f32x4 z4 = {0.f, 0.f, 0.f, 0.f};

  // ---- Q fragments (QSCALE folded, hi/lo split) ----
  f16x8 qh[4], ql[4];
  {
    const float* qbase = q + (size_t)(b * SLEN + i0 + wr * 16 + l15) * DMODEL + h * DHEAD;
    #pragma unroll
    for (int ks = 0; ks < 4; ++ks) {
      f32x4 x0 = *(const f32x4*)(qbase + ks * 32 + lg * 8);
      f32x4 x1 = *(const f32x4*)(qbase + ks * 32 + lg * 8 + 4);
      f16x8 hi, lo;
      #pragma unroll
      for (int e = 0; e < 4; ++e) {
        float s0 = x0[e] * QSCALE, s1 = x1[e] * QSCALE;
        _Float16 h0 = (_Float16)s0, h1 = (_Float16)s1;
        hi[e] = h0;     hi[e + 4] = h1;
        lo[e] = (_Float16)(s0 - (float)h0);
        lo[e + 4] = (_Float16)(s1 - (float)h1);
      }
      qh[ks] = hi; ql[ks] = lo;
    }
  }
  const float m_reg = ms_g[bh * SLEN + i0 + wr * 16 + l15];
  const float fl_reg = fl_g[bh * SLEN + i0 + wr * 16 + l15];
  const float e_l = __expf(Mg_g[bh * 16 + c] - m_reg);   // 0 at c==0

  f32x4 hacc[8];
  #pragma unroll
  for (int cf = 0; cf < 8; ++cf) hacc[cf] = z4;
  float ps = 0.f;

  // ======== stage EVERYTHING, then one barrier ========
  #pragma unroll
  for (int pss = 0; pss < 2; ++pss) {
    const int j0 = c * 128 + pss * 64;
    char* KB = pool + pss * 49152;
    // K raw hi/lo (1024 thr: 8 floats each), swizzled
    {
      const int krow = tid >> 4;            // 0..63
      const int kc0 = (tid & 15) * 8;       // float col base
      const float* kp = k + (size_t)(b * SLEN + j0 + krow) * DMODEL + h * DHEAD + kc0;
      char* bh_ = KB + krow * 256;
      char* bl_ = KB + 16384 + krow * 256;
      const int sw = (krow & 7) << 4;
      #pragma unroll
      for (int e = 0; e < 2; ++e) {
        f32x4 xv = *(const f32x4*)(kp + e * 4);
        f16x4 hi, lo;
        #pragma unroll
        for (int u = 0; u < 4; ++u) {
          _Float16 hh = (_Float16)xv[u];
          hi[u] = hh; lo[u] = (_Float16)(xv[u] - (float)hh);
        }
        const int bc = (kc0 + e * 4) * 2;
        *(f16x4*)(bh_ + (bc ^ sw)) = hi;
        *(f16x4*)(bl_ + (bc ^ sw)) = lo;
      }
    }
    // V (1024 thr: 8 j's each), packed 16B swizzled store
    {
      const int d = tid & 127;
      const int jq = tid >> 7;              // 0..7 (8 j each)
      const float* vp = v + (size_t)(b * SLEN + j0 + jq * 8) * DMODEL + h * DHEAD + d;
      float vv[8];
      #pragma unroll
      for (int jj = 0; jj < 8; ++jj)
        vv[jj] = vp[(size_t)jj * DMODEL];
      int pv[4];
      #pragma unroll
      for (int p = 0; p < 4; ++p) pv[p] = pk16(vv[2 * p], vv[2 * p + 1]);
      const int sw = (d & 7) << 4;
      const int b0 = d * 128 + jq * 16;
      *(f32x4*)(KB + 32768 + (b0 ^ sw)) = *(f32x4*)&pv[0];
    }
  }
  if (tid < 64) a_s0[tid] = a_g[bh * SLEN + c * 128 + tid];
  else if (tid < 128) a_s1[tid - 64] = a_g[bh * SLEN + c * 128 + tid];
  else if (tid < 256) pks[tid - 128] = pkx[(size_t)(bh * 16 + c) * 128 + (tid - 128)];
  if (c > 0) {   // X -> LDS (swizzled; fused load+store)
    const char* gxs = (const char*)(GXs + (size_t)(bh * 16 + c) * 16384);
    const int xrow = tid >> 3;            // 0..127
    const int xcb = (tid & 7) * 32;       // byte col base
    const int sw = (xrow & 7) << 4;
    uint4 g0 = *(const uint4*)(gxs + xrow * 256 + xcb);
    uint4 g1 = *(const uint4*)(gxs + xrow * 256 + xcb + 16);
    *(uint4*)(Xb + xrow * 256 + ((xcb + 0) ^ sw)) = g0;
    *(uint4*)(Xb + xrow * 256 + ((xcb + 16) ^ sw)) = g1;
  }
  __syncthreads();

  // ---- Phase B (both tt): Q*e_l @ X (from LDS), + inter rowsum ----
  if (c > 0) {
    f16x8 qe[2];
    #pragma unroll
    for (int kss = 0; kss < 2; ++kss) {
      const int ks = wc * 2 + kss;
      #pragma unroll
      for (int e = 0; e < 8; ++e)
        qe[kss][e] = (_Float16)(((float)qh[ks][e] + (float)ql[ks][e]) * e_l);
    }
    #pragma unroll
    for (int cf = 0; cf < 8; ++cf) {
      const int row = cf * 16 + l15;
      const int sw = (row & 7) << 4;
      #pragma unroll
      for (int kss = 0; kss < 2; ++kss) {
        const int bc = (wc * 2 + kss) * 64 + lg * 16;
        f16x8 xh = *(const f16x8*)(Xb + row * 256 + (bc ^ sw));
        hacc[cf] = __builtin_amdgcn_mfma_f32_16x16x32_f16(qe[kss], xh, hacc[cf], 0, 0, 0);
      }
    }
    if (wc == 0) {   // inter rowsum partial: e_l * (q . pk_excl)
      float dot = 0.f;
      #pragma unroll
      for (int ks = 0; ks < 4; ++ks)
        #pragma unroll
        for (int e = 0; e < 8; ++e)
          dot += ((float)qh[ks][e] + (float)ql[ks][e]) * pks[ks * 32 + lg * 8 + e];
      ps += dot * e_l;
    }
  }

  // ---- Phase A: two sub-tiles, no barriers (distinct buffers) ----
  #pragma unroll
  for (int pss = 0; pss < 2; ++pss) {
    if (pss <= tt) {
      const int j0 = c * 128 + pss * 64;
      const char* KB = pool + pss * 49152;
      const float* a_s = (pss == 0) ? a_s0 : a_s1;
      // swapped QK^T (3-leg split)
      f32x4 sacc[2];
      sacc[0] = z4; sacc[1] = z4;
      #pragma unroll
      for (int ks = 0; ks < 4; ++ks) {
        const int bc = ks * 64 + lg * 16;
        #pragma unroll
        for (int jfl = 0; jfl < 2; ++jfl) {
          const int arow = wc * 32 + jfl * 16 + l15;
          const int sw = (arow & 7) << 4;
          f16x8 kh8 = *(const f16x8*)(KB + arow * 256 + (bc ^ sw));
          f16x8 kl8 = *(const f16x8*)(KB + 16384 + arow * 256 + (bc ^ sw));
          sacc[jfl] = __builtin_amdgcn_mfma_f32_16x16x32_f16(kh8, qh[ks], sacc[jfl], 0, 0, 0);
          sacc[jfl] = __builtin_amdgcn_mfma_f32_16x16x32_f16(kl8, qh[ks], sacc[jfl], 0, 0, 0);
          sacc[jfl] = __builtin_amdgcn_mfma_f32_16x16x32_f16(kh8, ql[ks], sacc[jfl], 0, 0, 0);
        }
      }
      // decay + mask + rowsum (lane-local, i = l15-row)
      float vals[2][4];
      {
        const int iG = i0 + wr * 16 + l15;
        #pragma unroll
        for (int jfl = 0; jfl < 2; ++jfl)
          #pragma unroll
          for (int r = 0; r < 4; ++r) {
            const int jl = wc * 32 + jfl * 16 + lg * 4 + r;
            float e = __expf(fminf(a_s[jl] - m_reg, 0.f));
            float vv = sacc[jfl][r] * e;
            if (j0 + jl > iG) vv = 0.f;
            ps += vv;
            vals[jfl][r] = vv;
          }
      }
      // pack + repack to PV A-frag via bpermute
      const int lgand1 = lg & 1;
      const int idxA = (l15 + 16 * (2 * lgand1 + 0)) * 4;
      const int idxB = (l15 + 16 * (2 * lgand1 + 1)) * 4;
      const bool hi_half = ((lane & 63) >= 32);
      int c2[2][2];
      #pragma unroll
      for (int jfl = 0; jfl < 2; ++jfl) {
        c2[jfl][0] = pk16(vals[jfl][0], vals[jfl][1]);
        c2[jfl][1] = pk16(vals[jfl][2], vals[jfl][3]);
      }
      int pa32[4];
      #pragma unroll
      for (int p = 0; p < 4; ++p) {
        const int idx2 = (p < 2) ? idxA : idxB;
        int f0 = __builtin_amdgcn_ds_bpermute(idx2, c2[0][p & 1]);
        int f1 = __builtin_amdgcn_ds_bpermute(idx2, c2[1][p & 1]);
        pa32[p] = hi_half ? f1 : f0;
      }
      union { int i[4]; f16x8 v; } pu;
      pu.i[0] = pa32[0]; pu.i[1] = pa32[1]; pu.i[2] = pa32[2]; pu.i[3] = pa32[3];
      const f16x8 paf = pu.v;

      // PV
      const int vbc = wc * 64 + lg * 16;
      #pragma unroll
      for (int cf = 0; cf < 8; ++cf) {
        const int vrow = cf * 16 + l15;
        const int sw = (vrow & 7) << 4;
        f16x8 vb8 = *(const f16x8*)(KB + 32768 + vrow * 128 + (vbc ^ sw));
        hacc[cf] = __builtin_amdgcn_mfma_f32_16x16x32_f16(paf, vb8, hacc[cf], 0, 0, 0);
      }
    }
  }
  __syncthreads();   // all LDS reads done before epilogue reuses pool

  // ================= Epilogue (R8-verified, two tt-phases) ==================
  ps += __shfl_xor(ps, 16);
  ps += __shfl_xor(ps, 32);
  if (lane < 16) rs_lds[(tt * 64 + wr * 16 + l15) * 2 + wc] = ps;
  if (tt == 0 && wc == 1) {
    #pragma unroll
    for (int cf = 0; cf < 8; ++cf)
      *(f32x4*)&hex[wr * 2048 + cf * 256 + lane * 4] = hacc[cf];
  }
  __syncthreads();
  if (tt == 0 && wc == 0) {
    #pragma unroll
    for (int cf = 0; cf < 8; ++cf) {
      f32x4 o = *(const f32x4*)&hex[wr * 2048 + cf * 256 + lane * 4];
      hacc[cf][0] += o[0]; hacc[cf][1] += o[1];
      hacc[cf][2] += o[2]; hacc[cf][3] += o[3];
    }
    const float rsum = rs_lds[(wr * 16 + l15) * 2 + 0] + rs_lds[(wr * 16 + l15) * 2 + 1];
    const float inv = 1.0f / (fmaxf(fabsf(rsum), fl_reg) + 1e-6f);
    union { float f; int i; } uc; uc.f = inv;
    float invr[4];
    #pragma unroll
    for (int r = 0; r < 4; ++r) {
      union { float f; int i; } ur;
      ur.i = __builtin_amdgcn_ds_bpermute((lg * 4 + r) * 4, uc.i);
      invr[r] = ur.f;
    }
    #pragma unroll
    for (int r = 0; r < 4; ++r) {
      const size_t orow = (size_t)(b * SLEN + i0 + wr * 16 + lg * 4 + r) * DMODEL + h * DHEAD;
      #pragma unroll
      for (int cf = 0; cf < 8; ++cf)
        out[orow + cf * 16 + l15] = hacc[cf][r] * invr[r];
    }
  }
  __syncthreads();
  if (tt == 1 && wc == 1) {
    #pragma unroll
    for (int cf = 0; cf < 8; ++cf)
      *(f32x4*)&hex[wr * 2048 + cf * 256 + lane * 4] = hacc[cf];
  }
  __syncthreads();
  if (tt == 1 && wc == 0) {
    #pragma unroll
    for (int cf = 0; cf < 8; ++cf) {
      f32x4 o = *(const f32x4*)&hex[wr * 2048 + cf * 256 + lane * 4];
      hacc[cf][0] += o[0]; hacc[cf][1] += o[1];
      hacc[cf][2] += o[2]; hacc[cf][3] += o[3];
    }
    const float rsum = rs_lds[(64 + wr * 16 + l15) * 2 + 0] + rs_lds[(64 + wr * 16 + l15) * 2 + 1];
    const float inv = 1.0f / (fmaxf(fabsf(rsum), fl_reg) + 1e-6f);
    union { float f; int i; } uc; uc.f = inv;
    float invr[4];
    #pragma unroll
    for (int r = 0; r < 4; ++r) {
      union { float f; int i; } ur;
      ur.i = __builtin_amdgcn_ds_bpermute((lg * 4 + r) * 4, uc.i);
      invr[r] = ur.f;
    }
    #pragma unroll
    for (int r = 0; r < 4; ++r) {
      const size_t orow = (size_t)(b * SLEN + i0 + wr * 16 + lg * 4 + r) * DMODEL + h * DHEAD;
      #pragma unroll
      for (int cf = 0; cf < 8; ++cf)
        out[orow + cf * 16 + l15] = hacc[cf][r] * invr[r];
    }
  }
}

// ---------------- Fallback: R8 mlstm_main (verified, ws-light) --------------
__global__ __launch_bounds__(512)
void mlstm_main(const float* __restrict__ q, const float* __restrict__ k,
                const float* __restrict__ v, const float* __restrict__ a_g,
                const float* __restrict__ ms_g, const float* __restrict__ fl_g,
                const float* __restrict__ mt_g, float* __restrict__ out) {
  __shared__ __align__(16) char pool[50176];
  _Float16* Ks_hi = (_Float16*)pool;
  _Float16* Ks_lo = (_Float16*)(pool + 16384);
  _Float16* Vts   = (_Float16*)(pool + 32768);
  float* a_s      = (float*)(pool + 49152);
  float* rs_lds   = (float*)(pool + 49408);
  float* hex      = (float*)pool;

  const int bid = blockIdx.x;
  int t, bh;
  if (bid < 256) { t = 31 - (bid >> 4); bh = bid & 15; }
  else           { t = (bid - 256) >> 4; bh = (bid - 256) & 15; }
  const int b = bh >> 3, h = bh & 7;
  const int i0 = t * BM;
  const int tid = threadIdx.x;
  const int lane = tid & 63;
  const int wid = tid >> 6;
  const int wr = wid >> 1;
  const int wc = wid & 1;
  const int l15 = lane & 15;
  const int lg = lane >> 4;
  const f32x4 z4 = {0.f, 0.f, 0.f, 0.f};

  f16x8 qh[4], ql[4];
  {
    const float* qbase = q + (size_t)(b * SLEN + i0 + wr * 16 + l15) * DMODEL + h * DHEAD;
    #pragma unroll
    for (int ks = 0; ks < 4; ++ks) {
      f32x4 x0 = *(const f32x4*)(qbase + ks * 32 + lg * 8);
      f32x4 x1 = *(const f32x4*)(qbase + ks * 32 + lg * 8 + 4);
      f16x8 hi, lo;
      #pragma unroll
      for (int e = 0; e < 4; ++e) {
        float s0 = x0[e] * QSCALE, s1 = x1[e] * QSCALE;
        _Float16 h0 = (_Float16)s0, h1 = (_Float16)s1;
        hi[e] = h0;     hi[e + 4] = h1;
        lo[e] = (_Float16)(s0 - (float)h0);
        lo[e + 4] = (_Float16)(s1 - (float)h1);
      }
      qh[ks] = hi; ql[ks] = lo;
    }
  }
  const float m_reg = ms_g[bh * SLEN + i0 + wr * 16 + l15];
  const float fl_reg = fl_g[bh * SLEN + i0 + wr * 16 + l15];
  const int lgand1 = lg & 1;
  const int idxA = (l15 + 16 * (2 * lgand1 + 0)) * 4;
  const int idxB = (l15 + 16 * (2 * lgand1 + 1)) * 4;
  const bool hi_half = (lane >= 32);

  f32x4 hacc[8];
  #pragma unroll
  for (int cf = 0; cf < 8; ++cf) hacc[cf] = z4;
  float ps = 0.f;

  const int krow = tid >> 3;
  const int kc0 = (tid & 7) * 16;
  const int vdv = tid & 127;
  const int vjq = tid >> 7;

  for (int jt = 0; jt <= t; ++jt) {
    const int j0 = jt * BKT;
    const bool diag = (jt == t);
    const float mt = mt_g[bh * 32 + jt];
    {
      float es = 1.f;
      if (!diag) es = __expf(a_g[bh * SLEN + j0 + krow] - mt);
      const float* kp = k + (size_t)(b * SLEN + j0 + krow) * DMODEL + h * DHEAD + kc0;
      char* bh_ = (char*)Ks_hi + krow * 256;
      char* bl_ = (char*)Ks_lo + krow * 256;
      const int sw = (krow & 7) << 4;
      #pragma unroll
      for (int e = 0; e < 4; ++e) {
        f32x4 xv = *(const f32x4*)(kp + e * 4);
        f16x4 hi, lo;
        #pragma unroll
        for (int u = 0; u < 4; ++u) {
          float vv = xv[u] * es;
          _Float16 hh = (_Float16)vv;
          hi[u] = hh; lo[u] = (_Float16)(vv - (float)hh);
        }
        const int bc = (kc0 + e * 4) * 2;
        *(f16x4*)(bh_ + (bc ^ sw)) = hi;
        *(f16x4*)(bl_ + (bc ^ sw)) = lo;
      }
    }
    {
      const float* vp = v + (size_t)(b * SLEN + j0 + vjq * 16) * DMODEL + h * DHEAD + vdv;
      float vv[16];
      #pragma unroll
      for (int jj = 0; jj < 16; ++jj)
        vv[jj] = vp[(size_t)jj * DMODEL];
      int pk[8];
      #pragma unroll
      for (int p = 0; p < 8; ++p) pk[p] = pk16(vv[2 * p], vv[2 * p + 1]);
      const int sw = (vdv & 7) << 4;
      *(f32x4*)((char*)Vts + ((vdv * 128 + vjq * 32 + 0) ^ sw)) = *(f32x4*)&pk[0];
      *(f32x4*)((char*)Vts + ((vdv * 128 + vjq * 32 + 16) ^ sw)) = *(f32x4*)&pk[4];
    }
    if (diag && tid < BKT) a_s[tid] = a_g[bh * SLEN + j0 + tid];
    __syncthreads();

    f32x4 sacc[2];
    sacc[0] = z4; sacc[1] = z4;
    #pragma unroll
    for (int ks = 0; ks < 4; ++ks) {
      const int bc = ks * 64 + lg * 16;
      #pragma unroll
      for (int jfl = 0; jfl < 2; ++jfl) {
        const int arow = wc * 32 + jfl * 16 + l15;
        const int sw = (arow & 7) << 4;
        f16x8 kh8 = *(const f16x8*)((char*)Ks_hi + arow * 256 + (bc ^ sw));
        f16x8 kl8 = *(const f16x8*)((char*)Ks_lo + arow * 256 + (bc ^ sw));
        sacc[jfl] = __builtin_amdgcn_mfma_f32_16x16x32_f16(kh8, qh[ks], sacc[jfl], 0, 0, 0);
        sacc[jfl] = __builtin_amdgcn_mfma_f32_16x16x32_f16(kl8, qh[ks], sacc[jfl], 0, 0, 0);
        sacc[jfl] = __builtin_amdgcn_mfma_f32_16x16x32_f16(kh8, ql[ks], sacc[jfl], 0, 0, 0);
      }
    }
    float vals[2][4];
    if (diag) {
      const int iG = i0 + wr * 16 + l15;
      #pragma unroll
      for (int jfl = 0; jfl < 2; ++jfl)
        #pragma unroll
        for (int r = 0; r < 4; ++r) {
          const int jl = wc * 32 + jfl * 16 + lg * 4 + r;
          float e = __expf(fminf(a_s[jl] - m_reg, 0.f));
          float vv = sacc[jfl][r] * e;
          if (j0 + jl > iG) vv = 0.f;
          vals[jfl][r] = vv;
        }
    } else {
      const float em = __expf(fminf(mt - m_reg, 0.f));
      #pragma unroll
      for (int jfl = 0; jfl < 2; ++jfl)
        #pragma unroll
        for (int r = 0; r < 4; ++r)
          vals[jfl][r] = sacc[jfl][r] * em;
    }
    #pragma unroll
    for (int jfl = 0; jfl < 2; ++jfl)
      #pragma unroll
      for (int r = 0; r < 4; ++r) ps += vals[jfl][r];

    int c2[2][2];
    #pragma unroll
    for (int jfl = 0; jfl < 2; ++jfl) {
      c2[jfl][0] = pk16(vals[jfl][0], vals[jfl][1]);
      c2[jfl][1] = pk16(vals[jfl][2], vals[jfl][3]);
    }
    int pa32[4];
    #pragma unroll
    for (int p = 0; p < 4; ++p) {
      const int idx = (p < 2) ? idxA : idxB;
      int f0 = __builtin_amdgcn_ds_bpermute(idx, c2[0][p & 1]);
      int f1 = __builtin_amdgcn_ds_bpermute(idx, c2[1][p & 1]);
      pa32[p] = hi_half ? f1 : f0;
    }
    union { int i[4]; f16x8 v; } pu;
    pu.i[0] = pa32[0]; pu.i[1] = pa32[1]; pu.i[2] = pa32[2]; pu.i[3] = pa32[3];
    const f16x8 paf = pu.v;

    const int vbc = wc * 64 + lg * 16;
    #pragma unroll
    for (int cf = 0; cf < 8; ++cf) {
      const int vrow = cf * 16 + l15;
      const int sw = (vrow & 7) << 4;
      f16x8 vb8 = *(const f16x8*)((char*)Vts + vrow * 128 + (vbc ^ sw));
      hacc[cf] = __builtin_amdgcn_mfma_f32_16x16x32_f16(paf, vb8, hacc[cf], 0, 0, 0);
    }
    __syncthreads();
  }

  ps += __shfl_xor(ps, 16);
  ps += __shfl_xor(ps, 32);
  if (lane < 16) rs_lds[(wr * 16 + l15) * 2 + wc] = ps;
  if (wc == 1) {
    #pragma unroll
    for (int cf = 0; cf < 8; ++cf)
      *(f32x4*)&hex[wr * 2048 + cf * 256 + lane * 4] = hacc[cf];
  }
  __syncthreads();
  if (wc == 0) {
    #pragma unroll
    for (int cf = 0; cf < 8; ++cf) {
      f32x4 o = *(const f32x4*)&hex[wr * 2048 + cf * 256 + lane * 4];
      hacc[cf][0] += o[0]; hacc[cf][1] += o[1];
      hacc[cf][2] += o[2]; hacc[cf][3] += o[3];
    }
    const float rsum = rs_lds[(wr * 16 + l15) * 2 + 0] + rs_lds[(wr * 16 + l15) * 2 + 1];
    const float inv = 1.0f / (fmaxf(fabsf(rsum), fl_reg) + 1e-6f);
    union { float f; int i; } uc; uc.f = inv;
    float invr[4];
    #pragma unroll
    for (int r = 0; r < 4; ++r) {
      union { float f; int i; } ur;
      ur.i = __builtin_amdgcn_ds_bpermute((lg * 4 + r) * 4, uc.i);
      invr[r] = ur.f;
    }
    #pragma unroll
    for (int r = 0; r < 4; ++r) {
      const size_t orow = (size_t)(b * SLEN + i0 + wr * 16 + lg * 4 + r) * DMODEL + h * DHEAD;
      #pragma unroll
      for (int cf = 0; cf < 8; ++cf)
        out[orow + cf * 16 + l15] = hacc[cf][r] * invr[r];
    }
  }
}

// ---------------- Kernel 4: in-place LayerNorm on d_out ---------------------
__global__ __launch_bounds__(256)
void ln_kernel(float* __restrict__ out, const float* __restrict__ gamma) {
  const int row = blockIdx.x;
  const int tid = threadIdx.x;
  float* x = out + (size_t)row * DMODEL;
  f32x4 xv = ((const f32x4*)x)[tid];
  float s = xv[0] + xv[1] + xv[2] + xv[3];
  float qq = xv[0] * xv[0] + xv[1] * xv[1] + xv[2] * xv[2] + xv[3] * xv[3];
  #pragma unroll
  for (int m = 1; m < 64; m <<= 1) { s += __shfl_xor(s, m); qq += __shfl_xor(qq, m); }
  __shared__ float ss[4], sq[4];
  const int wid = tid >> 6;
  if ((tid & 63) == 0) { ss[wid] = s; sq[wid] = qq; }
  __syncthreads();
  s = ss[0] + ss[1] + ss[2] + ss[3];
  qq = sq[0] + sq[1] + sq[2] + sq[3];
  const float mu = s * (1.f / 1024.f);
  const float var = qq * (1.f / 1024.f) - mu * mu;
  const float rstd = rsqrtf(var + 1e-5f);
  f32x4 g = ((const f32x4*)gamma)[tid];
  f32x4 ov;
  ov[0] = (xv[0] - mu) * rstd * g[0];
  ov[1] = (xv[1] - mu) * rstd * g[1];
  ov[2] = (xv[2] - mu) * rstd * g[2];
  ov[3] = (xv[3] - mu) * rstd * g[3];
  ((f32x4*)x)[tid] = ov;
}

extern "C" void kernel_launch(void* const* d_in, const int* in_sizes, int n_in,
                              void* d_out, int out_size, void* d_ws, size_t ws_size,
                              hipStream_t stream) {
  (void)in_sizes; (void)n_in; (void)out_size;
  const float* q   = (const float*)d_in[0];
  const float* k   = (const float*)d_in[1];
  const float* v   = (const float*)d_in[2];
  const float* igw = (const float*)d_in[3];
  const float* igb = (const float*)d_in[4];
  const float* fgw = (const float*)d_in[5];
  const float* fgb = (const float*)d_in[6];
  const float* lns = (const float*)d_in[7];
  float* out = (float*)d_out;

  float* gpre  = (float*)d_ws;           // 65536 f32
  float* a_g   = gpre + 65536;           // 32768
  float* ms_g  = a_g + 32768;            // 32768
  float* fl_g  = ms_g + 32768;           // 32768
  float* mt64  = fl_g + 32768;           // 512   (16 x 32)
  float* mt128 = mt64 + 512;             // 256   (16 x 16)
  float* Mg_g  = mt128 + 256;            // 256
  float* pkt   = Mg_g + 256;             // 32768 (256 x 128)
  float* pkx   = pkt + 32768;            // 32768
  unsigned short* GXs = (unsigned short*)(pkx + 32768);  // 256 x 16384 fp16 = 8MB
  // total ≈ 9.31 MB

  const bool big = ws_size >= (size_t)10 * 1024 * 1024;

  gates_kernel<<<dim3(256), dim3(512), 0, stream>>>(q, k, v, igw, fgw, gpre);
  scan_kernel<<<dim3(16), dim3(256), 0, stream>>>(gpre, igb, fgb, a_g, ms_g, fl_g,
                                                  mt64, mt128, Mg_g);
  if (big) {
    p1_kernel<<<dim3(16, 16), dim3(512), 0, stream>>>(k, v, a_g, mt128, GXs, pkt);
    p2_kernel<<<dim3(9, 16), dim3(256), 0, stream>>>(mt128, GXs, pkt, pkx);
    p3_kernel<<<dim3(256), dim3(1024), 0, stream>>>(q, k, v, a_g, ms_g, fl_g,
                                                    Mg_g, pkx, GXs, out);
  } else {
    mlstm_main<<<dim3(512), dim3(512), 0, stream>>>(q, k, v, a_g, ms_g, fl_g, mt64, out);
  }
  ln_kernel<<<dim3(4096), dim3(256), 0, stream>>>(out, lns);
}

// Round 20
// 74.621 us; speedup vs baseline: 1.1171x; 1.0863x over previous
//
#include <hip/hip_runtime.h>
#include <hip/hip_bf16.h>

#define SLEN 2048
#define DMODEL 1024
#define NHEAD 8
#define DHEAD 128
#define BM 64
#define BKT 64
#define QSCALE 0.08838834764831845f  // 1/sqrt(128)

typedef __attribute__((ext_vector_type(4))) float f32x4;
typedef __attribute__((ext_vector_type(8))) _Float16 f16x8;
typedef __attribute__((ext_vector_type(4))) _Float16 f16x4;
typedef __attribute__((ext_vector_type(2))) _Float16 f16x2;

static __device__ __forceinline__ int pk16(float a, float b) {
  f16x2 t; t[0] = (_Float16)a; t[1] = (_Float16)b;
  union { f16x2 h; int i; } u; u.h = t; return u.i;
}
static __device__ __forceinline__ unsigned short f16bits(float x) {
  union { _Float16 h; unsigned short u; } u2; u2.h = (_Float16)x; return u2.u;
}

// ---------------- Kernel 1: gate preactivations via MFMA (R16, verified) ----
__global__ __launch_bounds__(512)
void gates_kernel(const float* __restrict__ q, const float* __restrict__ k,
                  const float* __restrict__ v, const float* __restrict__ igw,
                  const float* __restrict__ fgw, float* __restrict__ gpre) {
  __shared__ float red[8][16][16];
  const int row0 = blockIdx.x * 16;
  const int tid = threadIdx.x;
  const int lane = tid & 63, wid = tid >> 6;
  const int l15 = lane & 15, lg = lane >> 4;
  const f32x4 z4 = {0.f, 0.f, 0.f, 0.f};
  f32x4 acc = z4;
  const float* wbase = (l15 < 8) ? (igw + (size_t)l15 * 3072)
                                 : (fgw + (size_t)(l15 - 8) * 3072);
  #pragma unroll
  for (int ks = 0; ks < 12; ++ks) {
    const int kk = wid * 384 + ks * 32 + lg * 8;   // lane k base
    const int seg = kk >> 10;
    const int col = kk & 1023;
    const float* src = (seg == 0) ? q : (seg == 1) ? k : v;
    const float* xp = src + (size_t)(row0 + l15) * 1024 + col;
    f32x4 a0 = *(const f32x4*)xp;
    f32x4 a1 = *(const f32x4*)(xp + 4);
    f32x4 b0 = *(const f32x4*)(wbase + kk);
    f32x4 b1 = *(const f32x4*)(wbase + kk + 4);
    f16x8 ah, al, bhf, blf;
    #pragma unroll
    for (int e = 0; e < 4; ++e) {
      _Float16 h0 = (_Float16)a0[e], h1 = (_Float16)a1[e];
      ah[e] = h0; ah[e + 4] = h1;
      al[e] = (_Float16)(a0[e] - (float)h0);
      al[e + 4] = (_Float16)(a1[e] - (float)h1);
      _Float16 g0 = (_Float16)b0[e], g1 = (_Float16)b1[e];
      bhf[e] = g0; bhf[e + 4] = g1;
      blf[e] = (_Float16)(b0[e] - (float)g0);
      blf[e + 4] = (_Float16)(b1[e] - (float)g1);
    }
    acc = __builtin_amdgcn_mfma_f32_16x16x32_f16(ah, bhf, acc, 0, 0, 0);
    acc = __builtin_amdgcn_mfma_f32_16x16x32_f16(al, bhf, acc, 0, 0, 0);
    acc = __builtin_amdgcn_mfma_f32_16x16x32_f16(ah, blf, acc, 0, 0, 0);
  }
  #pragma unroll
  for (int r = 0; r < 4; ++r)
    red[wid][lg * 4 + r][l15] = acc[r];
  __syncthreads();
  if (tid < 256) {
    const int xrow = tid >> 4, g = tid & 15;
    float s = 0.f;
    #pragma unroll
    for (int w = 0; w < 8; ++w) s += red[w][xrow][g];
    gpre[(size_t)g * 4096 + row0 + xrow] = s;
  }
}

// ---------------- Kernel 2: scans + chunk maxima (R20: parallel prefix) -----
__global__ __launch_bounds__(256)
void scan_kernel(const float* __restrict__ gpre, const float* __restrict__ igb,
                 const float* __restrict__ fgb, float* __restrict__ a_out,
                 float* __restrict__ ms_out, float* __restrict__ fl_out,
                 float* __restrict__ mt64, float* __restrict__ mt128,
                 float* __restrict__ Mg_out) {
  const int bh = blockIdx.x;
  const int h = bh & 7;
  const int b = bh >> 3;
  const int tid = threadIdx.x;
  const int lane = tid & 63, wv = tid >> 6;
  __shared__ float mt_l[16];
  __shared__ double wsumd[4];
  __shared__ float wmaxf[4];
  const int base = b * 2048 + tid * 8;
  const float ig_b = igb[h], fg_b = fgb[h];
  double cs[8];
  float av[8];
  double tot = 0.0;
  #pragma unroll
  for (int e = 0; e < 8; ++e) {
    float x = gpre[(size_t)(8 + h) * 4096 + base + e] + fg_b;
    float l = fminf(x, 0.f) - log1pf(__expf(-fabsf(x)));   // log_sigmoid
    tot += (double)l;
    cs[e] = tot;
  }
  // parallel exclusive prefix SUM across 256 threads (wave shfl + LDS)
  double isum = tot;
  #pragma unroll
  for (int off = 1; off < 64; off <<= 1) {
    double o = __shfl_up(isum, off);
    if (lane >= off) isum += o;
  }
  if (lane == 63) wsumd[wv] = isum;
  __syncthreads();
  double based = 0.0;
  #pragma unroll
  for (int w = 0; w < 4; ++w) if (w < wv) based += wsumd[w];
  const double excl = based + isum - tot;

  float mtot = -3.4e38f;
  #pragma unroll
  for (int e = 0; e < 8; ++e) {
    cs[e] += excl;
    float ig = gpre[(size_t)h * 4096 + base + e] + ig_b;
    av[e] = (float)((double)ig - cs[e]);
    mtot = fmaxf(mtot, av[e]);
  }
  // per-64 and per-128 window maxima
  {
    float w8 = mtot;
    w8 = fmaxf(w8, __shfl_xor(w8, 1));
    w8 = fmaxf(w8, __shfl_xor(w8, 2));
    w8 = fmaxf(w8, __shfl_xor(w8, 4));
    if ((tid & 7) == 0) mt64[bh * 32 + (tid >> 3)] = w8;
    float w16 = fmaxf(w8, __shfl_xor(w8, 8));
    if ((tid & 15) == 0) { mt128[bh * 16 + (tid >> 4)] = w16; mt_l[tid >> 4] = w16; }
  }
  // parallel exclusive prefix MAX across 256 threads
  float prev = __shfl_up(mtot, 1);
  if (lane == 0) prev = -3.4e38f;
  float imax = prev;
  #pragma unroll
  for (int off = 1; off < 64; off <<= 1) {
    float o = __shfl_up(imax, off);
    if (lane >= off) imax = fmaxf(imax, o);
  }
  if (lane == 63) wmaxf[wv] = fmaxf(imax, mtot);   // inclusive wave max
  __syncthreads();
  float run = imax;
  #pragma unroll
  for (int w = 0; w < 4; ++w) if (w < wv) run = fmaxf(run, wmaxf[w]);

  if (tid == 0) {   // exclusive running max over 128-chunks (16 iters, trivial)
    float M = -3.4e38f;
    for (int c = 0; c < 16; ++c) { Mg_out[bh * 16 + c] = M; M = fmaxf(M, mt_l[c]); }
  }
  const int obase = bh * 2048 + tid * 8;
  #pragma unroll
  for (int e = 0; e < 8; ++e) {
    run = fmaxf(run, av[e]);
    a_out[obase + e] = av[e];
    ms_out[obase + e] = run;
    fl_out[obase + e] = __expf(-(float)(cs[e] + (double)run));  // exp(-max_log_D)
  }
}

// ---------------- Kernel P1: per-128-chunk state G[dv][dk] (fp16) + ksum ----
__global__ __launch_bounds__(512)
void p1_kernel(const float* __restrict__ k, const float* __restrict__ v,
               const float* __restrict__ a_g, const float* __restrict__ mt128,
               unsigned short* __restrict__ GXs, float* __restrict__ pkt) {
  __shared__ __align__(16) char pool[33280];
  _Float16* Kts = (_Float16*)pool;             // [128 dk][64 j] 128B rows, swz
  _Float16* Vts = (_Float16*)(pool + 16384);   // [128 dv][64 j]
  float* w_s = (float*)(pool + 32768);         // [128]
  const int c = blockIdx.x, bh = blockIdx.y;
  const int b = bh >> 3, h = bh & 7;
  const int tid = threadIdx.x;
  const int lane = tid & 63, wid = tid >> 6;
  const int l15 = lane & 15, lg = lane >> 4;
  if (tid < 128) w_s[tid] = __expf(a_g[bh * SLEN + c * 128 + tid] - mt128[bh * 16 + c]);
  const f32x4 z4 = {0.f, 0.f, 0.f, 0.f};
  f32x4 acc[8];
  #pragma unroll
  for (int i = 0; i < 8; ++i) acc[i] = z4;
  float ks_acc = 0.f;
  for (int p = 0; p < 2; ++p) {
    const int j0 = c * 128 + p * 64;
    __syncthreads();   // w_s ready (p=0); prior pass reads done (p=1)
    {
      const int d = tid & 127;
      const int jq = tid >> 7;                 // 0..3 (16 j each)
      const size_t rowb = (size_t)(b * SLEN + j0 + jq * 16) * DMODEL + h * DHEAD + d;
      float kv[16], vv[16];
      #pragma unroll
      for (int jj = 0; jj < 16; ++jj) {
        kv[jj] = k[rowb + (size_t)jj * DMODEL] * w_s[p * 64 + jq * 16 + jj];
        vv[jj] = v[rowb + (size_t)jj * DMODEL];
      }
      int ph[8], pv[8];
      #pragma unroll
      for (int pp = 0; pp < 8; ++pp) {
        ph[pp] = pk16(kv[2 * pp], kv[2 * pp + 1]);
        pv[pp] = pk16(vv[2 * pp], vv[2 * pp + 1]);
      }
      const int sw = (d & 7) << 4;
      const int b0 = d * 128 + jq * 32;
      *(f32x4*)((char*)Kts + ((b0 + 0) ^ sw))  = *(f32x4*)&ph[0];
      *(f32x4*)((char*)Kts + ((b0 + 16) ^ sw)) = *(f32x4*)&ph[4];
      *(f32x4*)((char*)Vts + ((b0 + 0) ^ sw))  = *(f32x4*)&pv[0];
      *(f32x4*)((char*)Vts + ((b0 + 16) ^ sw)) = *(f32x4*)&pv[4];
    }
    __syncthreads();
    f16x8 avv[2];
    {
      const int row = wid * 16 + l15;
      const int sw = (l15 & 7) << 4;
      avv[0] = *(const f16x8*)((char*)Vts + row * 128 + ((lg * 16) ^ sw));
      avv[1] = *(const f16x8*)((char*)Vts + row * 128 + ((64 + lg * 16) ^ sw));
    }
    #pragma unroll
    for (int dkt = 0; dkt < 8; ++dkt) {
      const int row = dkt * 16 + l15;
      const int sw = (l15 & 7) << 4;
      #pragma unroll
      for (int ks = 0; ks < 2; ++ks) {
        const int bc = ks * 64 + lg * 16;
        f16x8 bh8 = *(const f16x8*)((char*)Kts + row * 128 + (bc ^ sw));
        acc[dkt] = __builtin_amdgcn_mfma_f32_16x16x32_f16(avv[ks], bh8, acc[dkt], 0, 0, 0);
      }
    }
    if (tid < 128) {   // ksum partial over this pass's 64 j
      const int sw = (tid & 7) << 4;
      #pragma unroll
      for (int g = 0; g < 8; ++g) {
        f16x8 hh = *(const f16x8*)((char*)Kts + tid * 128 + ((g * 16) ^ sw));
        #pragma unroll
        for (int e = 0; e < 8; ++e) ks_acc += (float)hh[e];
      }
    }
  }
  unsigned short* gxs = GXs + (size_t)(bh * 16 + c) * 16384;
  #pragma unroll
  for (int dkt = 0; dkt < 8; ++dkt)
    #pragma unroll
    for (int r = 0; r < 4; ++r)
      gxs[(wid * 16 + lg * 4 + r) * 128 + dkt * 16 + l15] = f16bits(acc[dkt][r]);
  if (tid < 128) pkt[(size_t)(bh * 16 + c) * 128 + tid] = ks_acc;
}

// ---------------- Kernel P2: exclusive prefix states (R20: prefetched) ------
// All 16 G-slice loads are independent inputs (writes go to already-consumed
// slots) -> issue upfront, kill the 16-deep HBM latency chain.
__global__ __launch_bounds__(256)
__attribute__((amdgpu_waves_per_eu(1, 4)))
void p2_kernel(const float* __restrict__ mt128, unsigned short* __restrict__ GXs,
               const float* __restrict__ pkt, float* __restrict__ pkx) {
  const int s = blockIdx.x, bh = blockIdx.y;
  const int tid = threadIdx.x;
  union U8 { uint4 q; _Float16 h[8]; };
  if (s < 8) {
    unsigned short* base = GXs + (size_t)bh * 16 * 16384 + s * 2048 + tid * 8;
    uint4 g[16];
    #pragma unroll
    for (int c = 0; c < 16; ++c)
      g[c] = *(const uint4*)(base + (size_t)c * 16384);
    float X[8];
    #pragma unroll
    for (int e = 0; e < 8; ++e) X[e] = 0.f;
    float Mm1 = -3.4e38f;
    #pragma unroll
    for (int c = 0; c < 16; ++c) {
      U8 cu; cu.q = g[c];
      const float mtc = mt128[bh * 16 + c];
      const float Mc = fmaxf(Mm1, mtc);
      const float s1 = __expf(Mm1 - Mc), s2 = __expf(mtc - Mc);
      U8 ou;
      #pragma unroll
      for (int e = 0; e < 8; ++e) ou.h[e] = (_Float16)X[e];
      *(uint4*)(base + (size_t)c * 16384) = ou.q;
      #pragma unroll
      for (int e = 0; e < 8; ++e) X[e] = X[e] * s1 + (float)cu.h[e] * s2;
      Mm1 = Mc;
    }
  } else if (tid < 128) {
    const float* pb = pkt + (size_t)bh * 16 * 128 + tid;
    float g[16];
    #pragma unroll
    for (int c = 0; c < 16; ++c) g[c] = pb[(size_t)c * 128];
    float X = 0.f, Mm1 = -3.4e38f;
    #pragma unroll
    for (int c = 0; c < 16; ++c) {
      const float mtc = mt128[bh * 16 + c];
      const float Mc = fmaxf(Mm1, mtc);
      pkx[(size_t)bh * 16 * 128 + (size_t)c * 128 + tid] = X;
      X = X * __expf(Mm1 - Mc) + g[c] * __expf(mtc - Mc);
      Mm1 = Mc;
    }
  }
}

// ---------------- Kernel P3: merged pair, single-barrier staging (R19) ------
__global__ __launch_bounds__(1024)
__attribute__((amdgpu_waves_per_eu(4, 4)))
void p3_kernel(const float* __restrict__ q, const float* __restrict__ k,
               const float* __restrict__ v, const float* __restrict__ a_g,
               const float* __restrict__ ms_g, const float* __restrict__ fl_g,
               const float* __restrict__ Mg_g, const float* __restrict__ pkx,
               const unsigned short* __restrict__ GXs, float* __restrict__ out) {
  __shared__ __align__(16) char pool[133120];
  float* a_s0   = (float*)(pool + 131072);
  float* a_s1   = (float*)(pool + 131328);
  float* rs_lds = (float*)(pool + 131584);
  float* pks    = (float*)(pool + 132608);
  float* hex    = (float*)pool;
  char* const Xb = pool + 98304;

  const int bid = blockIdx.x;
  const int c = bid & 15;
  const int bh = bid >> 4;
  const int b = bh >> 3, h = bh & 7;
  const int tid = threadIdx.x;
  const int lane = tid & 63;
  const int wid = tid >> 6;          // 0..15
  const int tt = wid >> 3;           // 0..1: tile t = 2c+tt
  const int wr = (wid >> 1) & 3;     // 16-row group
  const int wc = wid & 1;            // half split (j in A, dk in B)
  const int l15 = lane & 15;
  const int lg = lane >> 4;
  const int t = 2 * c + tt;
  const int i0 = t * BM;
  const f32x4 z4 = {0.f, 0.f, 0.f, 0.f};

  // ---- Q fragments (QSCALE folded, hi/lo split) ----
  f16x8 qh[4], ql[4];
  {
    const float* qbase = q + (size_t)(b * SLEN + i0 + wr * 16 + l15) * DMODEL + h * DHEAD;
    #pragma unroll
    for (int ks = 0; ks < 4; ++ks) {
      f32x4 x0 = *(const f32x4*)(qbase + ks * 32 + lg * 8);
      f32x4 x1 = *(const f32x4*)(qbase + ks * 32 + lg * 8 + 4);
      f16x8 hi, lo;
      #pragma unroll
      for (int e = 0; e < 4; ++e) {
        float s0 = x0[e] * QSCALE, s1 = x1[e] * QSCALE;
        _Float16 h0 = (_Float16)s0, h1 = (_Float16)s1;
        hi[e] = h0;     hi[e + 4] = h1;
        lo[e] = (_Float16)(s0 - (float)h0);
        lo[e + 4] = (_Float16)(s1 - (float)h1);
      }
      qh[ks] = hi; ql[ks] = lo;
    }
  }
  const float m_reg = ms_g[bh * SLEN + i0 + wr * 16 + l15];
  const float fl_reg = fl_g[bh * SLEN + i0 + wr * 16 + l15];
  const float e_l = __expf(Mg_g[bh * 16 + c] - m_reg);   // 0 at c==0

  f32x4 hacc[8];
  #pragma unroll
  for (int cf = 0; cf < 8; ++cf) hacc[cf] = z4;
  float ps = 0.f;

  // ======== stage EVERYTHING, then one barrier ========
  #pragma unroll
  for (int pss = 0; pss < 2; ++pss) {
    const int j0 = c * 128 + pss * 64;
    char* KB = pool + pss * 49152;
    {
      const int krow = tid >> 4;            // 0..63
      const int kc0 = (tid & 15) * 8;       // float col base
      const float* kp = k + (size_t)(b * SLEN + j0 + krow) * DMODEL + h * DHEAD + kc0;
      char* bh_ = KB + krow * 256;
      char* bl_ = KB + 16384 + krow * 256;
      const int sw = (krow & 7) << 4;
      #pragma unroll
      for (int e = 0; e < 2; ++e) {
        f32x4 xv = *(const f32x4*)(kp + e * 4);
        f16x4 hi, lo;
        #pragma unroll
        for (int u = 0; u < 4; ++u) {
          _Float16 hh = (_Float16)xv[u];
          hi[u] = hh; lo[u] = (_Float16)(xv[u] - (float)hh);
        }
        const int bc = (kc0 + e * 4) * 2;
        *(f16x4*)(bh_ + (bc ^ sw)) = hi;
        *(f16x4*)(bl_ + (bc ^ sw)) = lo;
      }
    }
    {
      const int d = tid & 127;
      const int jq = tid >> 7;              // 0..7 (8 j each)
      const float* vp = v + (size_t)(b * SLEN + j0 + jq * 8) * DMODEL + h * DHEAD + d;
      float vv[8];
      #pragma unroll
      for (int jj = 0; jj < 8; ++jj)
        vv[jj] = vp[(size_t)jj * DMODEL];
      int pv[4];
      #pragma unroll
      for (int p = 0; p < 4; ++p) pv[p] = pk16(vv[2 * p], vv[2 * p + 1]);
      const int sw = (d & 7) << 4;
      const int b0 = d * 128 + jq * 16;
      *(f32x4*)(KB + 32768 + (b0 ^ sw)) = *(f32x4*)&pv[0];
    }
  }
  if (tid < 64) a_s0[tid] = a_g[bh * SLEN + c * 128 + tid];
  else if (tid < 128) a_s1[tid - 64] = a_g[bh * SLEN + c * 128 + tid];
  else if (tid < 256) pks[tid - 128] = pkx[(size_t)(bh * 16 + c) * 128 + (tid - 128)];
  if (c > 0) {   // X -> LDS (swizzled; fused load+store)
    const char* gxs = (const char*)(GXs + (size_t)(bh * 16 + c) * 16384);
    const int xrow = tid >> 3;            // 0..127
    const int xcb = (tid & 7) * 32;       // byte col base
    const int sw = (xrow & 7) << 4;
    uint4 g0 = *(const uint4*)(gxs + xrow * 256 + xcb);
    uint4 g1 = *(const uint4*)(gxs + xrow * 256 + xcb + 16);
    *(uint4*)(Xb + xrow * 256 + ((xcb + 0) ^ sw)) = g0;
    *(uint4*)(Xb + xrow * 256 + ((xcb + 16) ^ sw)) = g1;
  }
  __syncthreads();

  // ---- Phase B (both tt): Q*e_l @ X (from LDS), + inter rowsum ----
  if (c > 0) {
    f16x8 qe[2];
    #pragma unroll
    for (int kss = 0; kss < 2; ++kss) {
      const int ks = wc * 2 + kss;
      #pragma unroll
      for (int e = 0; e < 8; ++e)
        qe[kss][e] = (_Float16)(((float)qh[ks][e] + (float)ql[ks][e]) * e_l);
    }
    #pragma unroll
    for (int cf = 0; cf < 8; ++cf) {
      const int row = cf * 16 + l15;
      const int sw = (row & 7) << 4;
      #pragma unroll
      for (int kss = 0; kss < 2; ++kss) {
        const int bc = (wc * 2 + kss) * 64 + lg * 16;
        f16x8 xh = *(const f16x8*)(Xb + row * 256 + (bc ^ sw));
        hacc[cf] = __builtin_amdgcn_mfma_f32_16x16x32_f16(qe[kss], xh, hacc[cf], 0, 0, 0);
      }
    }
    if (wc == 0) {   // inter rowsum partial: e_l * (q . pk_excl)
      float dot = 0.f;
      #pragma unroll
      for (int ks = 0; ks < 4; ++ks)
        #pragma unroll
        for (int e = 0; e < 8; ++e)
          dot += ((float)qh[ks][e] + (float)ql[ks][e]) * pks[ks * 32 + lg * 8 + e];
      ps += dot * e_l;
    }
  }

  // ---- Phase A: two sub-tiles, no barriers (distinct buffers) ----
  #pragma unroll
  for (int pss = 0; pss < 2; ++pss) {
    if (pss <= tt) {
      const int j0 = c * 128 + pss * 64;
      const char* KB = pool + pss * 49152;
      const float* a_s = (pss == 0) ? a_s0 : a_s1;
      f32x4 sacc[2];
      sacc[0] = z4; sacc[1] = z4;
      #pragma unroll
      for (int ks = 0; ks < 4; ++ks) {
        const int bc = ks * 64 + lg * 16;
        #pragma unroll
        for (int jfl = 0; jfl < 2; ++jfl) {
          const int arow = wc * 32 + jfl * 16 + l15;
          const int sw = (arow & 7) << 4;
          f16x8 kh8 = *(const f16x8*)(KB + arow * 256 + (bc ^ sw));
          f16x8 kl8 = *(const f16x8*)(KB + 16384 + arow * 256 + (bc ^ sw));
          sacc[jfl] = __builtin_amdgcn_mfma_f32_16x16x32_f16(kh8, qh[ks], sacc[jfl], 0, 0, 0);
          sacc[jfl] = __builtin_amdgcn_mfma_f32_16x16x32_f16(kl8, qh[ks], sacc[jfl], 0, 0, 0);
          sacc[jfl] = __builtin_amdgcn_mfma_f32_16x16x32_f16(kh8, ql[ks], sacc[jfl], 0, 0, 0);
        }
      }
      float vals[2][4];
      {
        const int iG = i0 + wr * 16 + l15;
        #pragma unroll
        for (int jfl = 0; jfl < 2; ++jfl)
          #pragma unroll
          for (int r = 0; r < 4; ++r) {
            const int jl = wc * 32 + jfl * 16 + lg * 4 + r;
            float e = __expf(fminf(a_s[jl] - m_reg, 0.f));
            float vv = sacc[jfl][r] * e;
            if (j0 + jl > iG) vv = 0.f;
            ps += vv;
            vals[jfl][r] = vv;
          }
      }
      const int lgand1 = lg & 1;
      const int idxA = (l15 + 16 * (2 * lgand1 + 0)) * 4;
      const int idxB = (l15 + 16 * (2 * lgand1 + 1)) * 4;
      const bool hi_half = ((lane & 63) >= 32);
      int c2[2][2];
      #pragma unroll
      for (int jfl = 0; jfl < 2; ++jfl) {
        c2[jfl][0] = pk16(vals[jfl][0], vals[jfl][1]);
        c2[jfl][1] = pk16(vals[jfl][2], vals[jfl][3]);
      }
      int pa32[4];
      #pragma unroll
      for (int p = 0; p < 4; ++p) {
        const int idx2 = (p < 2) ? idxA : idxB;
        int f0 = __builtin_amdgcn_ds_bpermute(idx2, c2[0][p & 1]);
        int f1 = __builtin_amdgcn_ds_bpermute(idx2, c2[1][p & 1]);
        pa32[p] = hi_half ? f1 : f0;
      }
      union { int i[4]; f16x8 v; } pu;
      pu.i[0] = pa32[0]; pu.i[1] = pa32[1]; pu.i[2] = pa32[2]; pu.i[3] = pa32[3];
      const f16x8 paf = pu.v;

      const int vbc = wc * 64 + lg * 16;
      #pragma unroll
      for (int cf = 0; cf < 8; ++cf) {
        const int vrow = cf * 16 + l15;
        const int sw = (vrow & 7) << 4;
        f16x8 vb8 = *(const f16x8*)(KB + 32768 + vrow * 128 + (vbc ^ sw));
        hacc[cf] = __builtin_amdgcn_mfma_f32_16x16x32_f16(paf, vb8, hacc[cf], 0, 0, 0);
      }
    }
  }
  __syncthreads();   // all LDS reads done before epilogue reuses pool

  // ================= Epilogue (R8-verified, two tt-phases) ==================
  ps += __shfl_xor(ps, 16);
  ps += __shfl_xor(ps, 32);
  if (lane < 16) rs_lds[(tt * 64 + wr * 16 + l15) * 2 + wc] = ps;
  if (tt == 0 && wc == 1) {
    #pragma unroll
    for (int cf = 0; cf < 8; ++cf)
      *(f32x4*)&hex[wr * 2048 + cf * 256 + lane * 4] = hacc[cf];
  }
  __syncthreads();
  if (tt == 0 && wc == 0) {
    #pragma unroll
    for (int cf = 0; cf < 8; ++cf) {
      f32x4 o = *(const f32x4*)&hex[wr * 2048 + cf * 256 + lane * 4];
      hacc[cf][0] += o[0]; hacc[cf][1] += o[1];
      hacc[cf][2] += o[2]; hacc[cf][3] += o[3];
    }
    const float rsum = rs_lds[(wr * 16 + l15) * 2 + 0] + rs_lds[(wr * 16 + l15) * 2 + 1];
    const float inv = 1.0f / (fmaxf(fabsf(rsum), fl_reg) + 1e-6f);
    union { float f; int i; } uc; uc.f = inv;
    float invr[4];
    #pragma unroll
    for (int r = 0; r < 4; ++r) {
      union { float f; int i; } ur;
      ur.i = __builtin_amdgcn_ds_bpermute((lg * 4 + r) * 4, uc.i);
      invr[r] = ur.f;
    }
    #pragma unroll
    for (int r = 0; r < 4; ++r) {
      const size_t orow = (size_t)(b * SLEN + i0 + wr * 16 + lg * 4 + r) * DMODEL + h * DHEAD;
      #pragma unroll
      for (int cf = 0; cf < 8; ++cf)
        out[orow + cf * 16 + l15] = hacc[cf][r] * invr[r];
    }
  }
  __syncthreads();
  if (tt == 1 && wc == 1) {
    #pragma unroll
    for (int cf = 0; cf < 8; ++cf)
      *(f32x4*)&hex[wr * 2048 + cf * 256 + lane * 4] = hacc[cf];
  }
  __syncthreads();
  if (tt == 1 && wc == 0) {
    #pragma unroll
    for (int cf = 0; cf < 8; ++cf) {
      f32x4 o = *(const f32x4*)&hex[wr * 2048 + cf * 256 + lane * 4];
      hacc[cf][0] += o[0]; hacc[cf][1] += o[1];
      hacc[cf][2] += o[2]; hacc[cf][3] += o[3];
    }
    const float rsum = rs_lds[(64 + wr * 16 + l15) * 2 + 0] + rs_lds[(64 + wr * 16 + l15) * 2 + 1];
    const float inv = 1.0f / (fmaxf(fabsf(rsum), fl_reg) + 1e-6f);
    union { float f; int i; } uc; uc.f = inv;
    float invr[4];
    #pragma unroll
    for (int r = 0; r < 4; ++r) {
      union { float f; int i; } ur;
      ur.i = __builtin_amdgcn_ds_bpermute((lg * 4 + r) * 4, uc.i);
      invr[r] = ur.f;
    }
    #pragma unroll
    for (int r = 0; r < 4; ++r) {
      const size_t orow = (size_t)(b * SLEN + i0 + wr * 16 + lg * 4 + r) * DMODEL + h * DHEAD;
      #pragma unroll
      for (int cf = 0; cf < 8; ++cf)
        out[orow + cf * 16 + l15] = hacc[cf][r] * invr[r];
    }
  }
}

// ---------------- Fallback: R8 mlstm_main (verified, ws-light) --------------
__global__ __launch_bounds__(512)
void mlstm_main(const float* __restrict__ q, const float* __restrict__ k,
                const float* __restrict__ v, const float* __restrict__ a_g,
                const float* __restrict__ ms_g, const float* __restrict__ fl_g,
                const float* __restrict__ mt_g, float* __restrict__ out) {
  __shared__ __align__(16) char pool[50176];
  _Float16* Ks_hi = (_Float16*)pool;
  _Float16* Ks_lo = (_Float16*)(pool + 16384);
  _Float16* Vts   = (_Float16*)(pool + 32768);
  float* a_s      = (float*)(pool + 49152);
  float* rs_lds   = (float*)(pool + 49408);
  float* hex      = (float*)pool;

  const int bid = blockIdx.x;
  int t, bh;
  if (bid < 256) { t = 31 - (bid >> 4); bh = bid & 15; }
  else           { t = (bid - 256) >> 4; bh = (bid - 256) & 15; }
  const int b = bh >> 3, h = bh & 7;
  const int i0 = t * BM;
  const int tid = threadIdx.x;
  const int lane = tid & 63;
  const int wid = tid >> 6;
  const int wr = wid >> 1;
  const int wc = wid & 1;
  const int l15 = lane & 15;
  const int lg = lane >> 4;
  const f32x4 z4 = {0.f, 0.f, 0.f, 0.f};

  f16x8 qh[4], ql[4];
  {
    const float* qbase = q + (size_t)(b * SLEN + i0 + wr * 16 + l15) * DMODEL + h * DHEAD;
    #pragma unroll
    for (int ks = 0; ks < 4; ++ks) {
      f32x4 x0 = *(const f32x4*)(qbase + ks * 32 + lg * 8);
      f32x4 x1 = *(const f32x4*)(qbase + ks * 32 + lg * 8 + 4);
      f16x8 hi, lo;
      #pragma unroll
      for (int e = 0; e < 4; ++e) {
        float s0 = x0[e] * QSCALE, s1 = x1[e] * QSCALE;
        _Float16 h0 = (_Float16)s0, h1 = (_Float16)s1;
        hi[e] = h0;     hi[e + 4] = h1;
        lo[e] = (_Float16)(s0 - (float)h0);
        lo[e + 4] = (_Float16)(s1 - (float)h1);
      }
      qh[ks] = hi; ql[ks] = lo;
    }
  }
  const float m_reg = ms_g[bh * SLEN + i0 + wr * 16 + l15];
  const float fl_reg = fl_g[bh * SLEN + i0 + wr * 16 + l15];
  const int lgand1 = lg & 1;
  const int idxA = (l15 + 16 * (2 * lgand1 + 0)) * 4;
  const int idxB = (l15 + 16 * (2 * lgand1 + 1)) * 4;
  const bool hi_half = (lane >= 32);

  f32x4 hacc[8];
  #pragma unroll
  for (int cf = 0; cf < 8; ++cf) hacc[cf] = z4;
  float ps = 0.f;

  const int krow = tid >> 3;
  const int kc0 = (tid & 7) * 16;
  const int vdv = tid & 127;
  const int vjq = tid >> 7;

  for (int jt = 0; jt <= t; ++jt) {
    const int j0 = jt * BKT;
    const bool diag = (jt == t);
    const float mt = mt_g[bh * 32 + jt];
    {
      float es = 1.f;
      if (!diag) es = __expf(a_g[bh * SLEN + j0 + krow] - mt);
      const float* kp = k + (size_t)(b * SLEN + j0 + krow) * DMODEL + h * DHEAD + kc0;
      char* bh_ = (char*)Ks_hi + krow * 256;
      char* bl_ = (char*)Ks_lo + krow * 256;
      const int sw = (krow & 7) << 4;
      #pragma unroll
      for (int e = 0; e < 4; ++e) {
        f32x4 xv = *(const f32x4*)(kp + e * 4);
        f16x4 hi, lo;
        #pragma unroll
        for (int u = 0; u < 4; ++u) {
          float vv = xv[u] * es;
          _Float16 hh = (_Float16)vv;
          hi[u] = hh; lo[u] = (_Float16)(vv - (float)hh);
        }
        const int bc = (kc0 + e * 4) * 2;
        *(f16x4*)(bh_ + (bc ^ sw)) = hi;
        *(f16x4*)(bl_ + (bc ^ sw)) = lo;
      }
    }
    {
      const float* vp = v + (size_t)(b * SLEN + j0 + vjq * 16) * DMODEL + h * DHEAD + vdv;
      float vv[16];
      #pragma unroll
      for (int jj = 0; jj < 16; ++jj)
        vv[jj] = vp[(size_t)jj * DMODEL];
      int pk[8];
      #pragma unroll
      for (int p = 0; p < 8; ++p) pk[p] = pk16(vv[2 * p], vv[2 * p + 1]);
      const int sw = (vdv & 7) << 4;
      *(f32x4*)((char*)Vts + ((vdv * 128 + vjq * 32 + 0) ^ sw)) = *(f32x4*)&pk[0];
      *(f32x4*)((char*)Vts + ((vdv * 128 + vjq * 32 + 16) ^ sw)) = *(f32x4*)&pk[4];
    }
    if (diag && tid < BKT) a_s[tid] = a_g[bh * SLEN + j0 + tid];
    __syncthreads();

    f32x4 sacc[2];
    sacc[0] = z4; sacc[1] = z4;
    #pragma unroll
    for (int ks = 0; ks < 4; ++ks) {
      const int bc = ks * 64 + lg * 16;
      #pragma unroll
      for (int jfl = 0; jfl < 2; ++jfl) {
        const int arow = wc * 32 + jfl * 16 + l15;
        const int sw = (arow & 7) << 4;
        f16x8 kh8 = *(const f16x8*)((char*)Ks_hi + arow * 256 + (bc ^ sw));
        f16x8 kl8 = *(const f16x8*)((char*)Ks_lo + arow * 256 + (bc ^ sw));
        sacc[jfl] = __builtin_amdgcn_mfma_f32_16x16x32_f16(kh8, qh[ks], sacc[jfl], 0, 0, 0);
        sacc[jfl] = __builtin_amdgcn_mfma_f32_16x16x32_f16(kl8, qh[ks], sacc[jfl], 0, 0, 0);
        sacc[jfl] = __builtin_amdgcn_mfma_f32_16x16x32_f16(kh8, ql[ks], sacc[jfl], 0, 0, 0);
      }
    }
    float vals[2][4];
    if (diag) {
      const int iG = i0 + wr * 16 + l15;
      #pragma unroll
      for (int jfl = 0; jfl < 2; ++jfl)
        #pragma unroll
        for (int r = 0; r < 4; ++r) {
          const int jl = wc * 32 + jfl * 16 + lg * 4 + r;
          float e = __expf(fminf(a_s[jl] - m_reg, 0.f));
          float vv = sacc[jfl][r] * e;
          if (j0 + jl > iG) vv = 0.f;
          vals[jfl][r] = vv;
        }
    } else {
      const float em = __expf(fminf(mt - m_reg, 0.f));
      #pragma unroll
      for (int jfl = 0; jfl < 2; ++jfl)
        #pragma unroll
        for (int r = 0; r < 4; ++r)
          vals[jfl][r] = sacc[jfl][r] * em;
    }
    #pragma unroll
    for (int jfl = 0; jfl < 2; ++jfl)
      #pragma unroll
      for (int r = 0; r < 4; ++r) ps += vals[jfl][r];

    int c2[2][2];
    #pragma unroll
    for (int jfl = 0; jfl < 2; ++jfl) {
      c2[jfl][0] = pk16(vals[jfl][0], vals[jfl][1]);
      c2[jfl][1] = pk16(vals[jfl][2], vals[jfl][3]);
    }
    int pa32[4];
    #pragma unroll
    for (int p = 0; p < 4; ++p) {
      const int idx = (p < 2) ? idxA : idxB;
      int f0 = __builtin_amdgcn_ds_bpermute(idx, c2[0][p & 1]);
      int f1 = __builtin_amdgcn_ds_bpermute(idx, c2[1][p & 1]);
      pa32[p] = hi_half ? f1 : f0;
    }
    union { int i[4]; f16x8 v; } pu;
    pu.i[0] = pa32[0]; pu.i[1] = pa32[1]; pu.i[2] = pa32[2]; pu.i[3] = pa32[3];
    const f16x8 paf = pu.v;

    const int vbc = wc * 64 + lg * 16;
    #pragma unroll
    for (int cf = 0; cf < 8; ++cf) {
      const int vrow = cf * 16 + l15;
      const int sw = (vrow & 7) << 4;
      f16x8 vb8 = *(const f16x8*)((char*)Vts + vrow * 128 + (vbc ^ sw));
      hacc[cf] = __builtin_amdgcn_mfma_f32_16x16x32_f16(paf, vb8, hacc[cf], 0, 0, 0);
    }
    __syncthreads();
  }

  ps += __shfl_xor(ps, 16);
  ps += __shfl_xor(ps, 32);
  if (lane < 16) rs_lds[(wr * 16 + l15) * 2 + wc] = ps;
  if (wc == 1) {
    #pragma unroll
    for (int cf = 0; cf < 8; ++cf)
      *(f32x4*)&hex[wr * 2048 + cf * 256 + lane * 4] = hacc[cf];
  }
  __syncthreads();
  if (wc == 0) {
    #pragma unroll
    for (int cf = 0; cf < 8; ++cf) {
      f32x4 o = *(const f32x4*)&hex[wr * 2048 + cf * 256 + lane * 4];
      hacc[cf][0] += o[0]; hacc[cf][1] += o[1];
      hacc[cf][2] += o[2]; hacc[cf][3] += o[3];
    }
    const float rsum = rs_lds[(wr * 16 + l15) * 2 + 0] + rs_lds[(wr * 16 + l15) * 2 + 1];
    const float inv = 1.0f / (fmaxf(fabsf(rsum), fl_reg) + 1e-6f);
    union { float f; int i; } uc; uc.f = inv;
    float invr[4];
    #pragma unroll
    for (int r = 0; r < 4; ++r) {
      union { float f; int i; } ur;
      ur.i = __builtin_amdgcn_ds_bpermute((lg * 4 + r) * 4, uc.i);
      invr[r] = ur.f;
    }
    #pragma unroll
    for (int r = 0; r < 4; ++r) {
      const size_t orow = (size_t)(b * SLEN + i0 + wr * 16 + lg * 4 + r) * DMODEL + h * DHEAD;
      #pragma unroll
      for (int cf = 0; cf < 8; ++cf)
        out[orow + cf * 16 + l15] = hacc[cf][r] * invr[r];
    }
  }
}

// ---------------- Kernel 4: in-place LayerNorm on d_out ---------------------
__global__ __launch_bounds__(256)
void ln_kernel(float* __restrict__ out, const float* __restrict__ gamma) {
  const int row = blockIdx.x;
  const int tid = threadIdx.x;
  float* x = out + (size_t)row * DMODEL;
  f32x4 xv = ((const f32x4*)x)[tid];
  float s = xv[0] + xv[1] + xv[2] + xv[3];
  float qq = xv[0] * xv[0] + xv[1] * xv[1] + xv[2] * xv[2] + xv[3] * xv[3];
  #pragma unroll
  for (int m = 1; m < 64; m <<= 1) { s += __shfl_xor(s, m); qq += __shfl_xor(qq, m); }
  __shared__ float ss[4], sq[4];
  const int wid = tid >> 6;
  if ((tid & 63) == 0) { ss[wid] = s; sq[wid] = qq; }
  __syncthreads();
  s = ss[0] + ss[1] + ss[2] + ss[3];
  qq = sq[0] + sq[1] + sq[2] + sq[3];
  const float mu = s * (1.f / 1024.f);
  const float var = qq * (1.f / 1024.f) - mu * mu;
  const float rstd = rsqrtf(var + 1e-5f);
  f32x4 g = ((const f32x4*)gamma)[tid];
  f32x4 ov;
  ov[0] = (xv[0] - mu) * rstd * g[0];
  ov[1] = (xv[1] - mu) * rstd * g[1];
  ov[2] = (xv[2] - mu) * rstd * g[2];
  ov[3] = (xv[3] - mu) * rstd * g[3];
  ((f32x4*)x)[tid] = ov;
}

extern "C" void kernel_launch(void* const* d_in, const int* in_sizes, int n_in,
                              void* d_out, int out_size, void* d_ws, size_t ws_size,
                              hipStream_t stream) {
  (void)in_sizes; (void)n_in; (void)out_size;
  const float* q   = (const float*)d_in[0];
  const float* k   = (const float*)d_in[1];
  const float* v   = (const float*)d_in[2];
  const float* igw = (const float*)d_in[3];
  const float* igb = (const float*)d_in[4];
  const float* fgw = (const float*)d_in[5];
  const float* fgb = (const float*)d_in[6];
  const float* lns = (const float*)d_in[7];
  float* out = (float*)d_out;

  float* gpre  = (float*)d_ws;           // 65536 f32
  float* a_g   = gpre + 65536;           // 32768
  float* ms_g  = a_g + 32768;            // 32768
  float* fl_g  = ms_g + 32768;           // 32768
  float* mt64  = fl_g + 32768;           // 512   (16 x 32)
  float* mt128 = mt64 + 512;             // 256   (16 x 16)
  float* Mg_g  = mt128 + 256;            // 256
  float* pkt   = Mg_g + 256;             // 32768 (256 x 128)
  float* pkx   = pkt + 32768;            // 32768
  unsigned short* GXs = (unsigned short*)(pkx + 32768);  // 256 x 16384 fp16 = 8MB
  // total ≈ 9.31 MB

  const bool big = ws_size >= (size_t)10 * 1024 * 1024;

  gates_kernel<<<dim3(256), dim3(512), 0, stream>>>(q, k, v, igw, fgw, gpre);
  scan_kernel<<<dim3(16), dim3(256), 0, stream>>>(gpre, igb, fgb, a_g, ms_g, fl_g,
                                                  mt64, mt128, Mg_g);
  if (big) {
    p1_kernel<<<dim3(16, 16), dim3(512), 0, stream>>>(k, v, a_g, mt128, GXs, pkt);
    p2_kernel<<<dim3(9, 16), dim3(256), 0, stream>>>(mt128, GXs, pkt, pkx);
    p3_kernel<<<dim3(256), dim3(1024), 0, stream>>>(q, k, v, a_g, ms_g, fl_g,
                                                    Mg_g, pkx, GXs, out);
  } else {
    mlstm_main<<<dim3(512), dim3(512), 0, stream>>>(q, k, v, a_g, ms_g, fl_g, mt64, out);
  }
  ln_kernel<<<dim3(4096), dim3(256), 0, stream>>>(out, lns);
}

// Round 21
// 73.918 us; speedup vs baseline: 1.1278x; 1.0095x over previous
//
#include <hip/hip_runtime.h>
#include <hip/hip_bf16.h>

#define SLEN 2048
#define DMODEL 1024
#define NHEAD 8
#define DHEAD 128
#define BM 64
#define BKT 64
#define QSCALE 0.08838834764831845f  // 1/sqrt(128)

typedef __attribute__((ext_vector_type(4))) float f32x4;
typedef __attribute__((ext_vector_type(8))) _Float16 f16x8;
typedef __attribute__((ext_vector_type(4))) _Float16 f16x4;
typedef __attribute__((ext_vector_type(2))) _Float16 f16x2;

static __device__ __forceinline__ int pk16(float a, float b) {
  f16x2 t; t[0] = (_Float16)a; t[1] = (_Float16)b;
  union { f16x2 h; int i; } u; u.h = t; return u.i;
}
static __device__ __forceinline__ unsigned short f16bits(float x) {
  union { _Float16 h; unsigned short u; } u2; u2.h = (_Float16)x; return u2.u;
}

// ---------------- Kernel 1: gate preactivations via MFMA (R21: 2-leg) -------
// Dropped W-lo leg: W-lo/W-hi ~ 2^-11 relative on preacts -> ~6e-3 on cs
// after 2048-cumsum random walk, inside the 4x absmax margin.
__global__ __launch_bounds__(512)
void gates_kernel(const float* __restrict__ q, const float* __restrict__ k,
                  const float* __restrict__ v, const float* __restrict__ igw,
                  const float* __restrict__ fgw, float* __restrict__ gpre) {
  __shared__ float red[8][16][16];
  const int row0 = blockIdx.x * 16;
  const int tid = threadIdx.x;
  const int lane = tid & 63, wid = tid >> 6;
  const int l15 = lane & 15, lg = lane >> 4;
  const f32x4 z4 = {0.f, 0.f, 0.f, 0.f};
  f32x4 acc = z4;
  const float* wbase = (l15 < 8) ? (igw + (size_t)l15 * 3072)
                                 : (fgw + (size_t)(l15 - 8) * 3072);
  #pragma unroll
  for (int ks = 0; ks < 12; ++ks) {
    const int kk = wid * 384 + ks * 32 + lg * 8;   // lane k base
    const int seg = kk >> 10;
    const int col = kk & 1023;
    const float* src = (seg == 0) ? q : (seg == 1) ? k : v;
    const float* xp = src + (size_t)(row0 + l15) * 1024 + col;
    f32x4 a0 = *(const f32x4*)xp;
    f32x4 a1 = *(const f32x4*)(xp + 4);
    f32x4 b0 = *(const f32x4*)(wbase + kk);
    f32x4 b1 = *(const f32x4*)(wbase + kk + 4);
    f16x8 ah, al, bhf;
    #pragma unroll
    for (int e = 0; e < 4; ++e) {
      _Float16 h0 = (_Float16)a0[e], h1 = (_Float16)a1[e];
      ah[e] = h0; ah[e + 4] = h1;
      al[e] = (_Float16)(a0[e] - (float)h0);
      al[e + 4] = (_Float16)(a1[e] - (float)h1);
      bhf[e] = (_Float16)b0[e]; bhf[e + 4] = (_Float16)b1[e];
    }
    acc = __builtin_amdgcn_mfma_f32_16x16x32_f16(ah, bhf, acc, 0, 0, 0);
    acc = __builtin_amdgcn_mfma_f32_16x16x32_f16(al, bhf, acc, 0, 0, 0);
  }
  #pragma unroll
  for (int r = 0; r < 4; ++r)
    red[wid][lg * 4 + r][l15] = acc[r];
  __syncthreads();
  if (tid < 256) {
    const int xrow = tid >> 4, g = tid & 15;
    float s = 0.f;
    #pragma unroll
    for (int w = 0; w < 8; ++w) s += red[w][xrow][g];
    gpre[(size_t)g * 4096 + row0 + xrow] = s;
  }
}

// ---------------- Kernel 2: scans + chunk maxima (R20: parallel prefix) -----
__global__ __launch_bounds__(256)
void scan_kernel(const float* __restrict__ gpre, const float* __restrict__ igb,
                 const float* __restrict__ fgb, float* __restrict__ a_out,
                 float* __restrict__ ms_out, float* __restrict__ fl_out,
                 float* __restrict__ mt64, float* __restrict__ mt128,
                 float* __restrict__ Mg_out) {
  const int bh = blockIdx.x;
  const int h = bh & 7;
  const int b = bh >> 3;
  const int tid = threadIdx.x;
  const int lane = tid & 63, wv = tid >> 6;
  __shared__ float mt_l[16];
  __shared__ double wsumd[4];
  __shared__ float wmaxf[4];
  const int base = b * 2048 + tid * 8;
  const float ig_b = igb[h], fg_b = fgb[h];
  double cs[8];
  float av[8];
  double tot = 0.0;
  #pragma unroll
  for (int e = 0; e < 8; ++e) {
    float x = gpre[(size_t)(8 + h) * 4096 + base + e] + fg_b;
    float l = fminf(x, 0.f) - log1pf(__expf(-fabsf(x)));   // log_sigmoid
    tot += (double)l;
    cs[e] = tot;
  }
  // parallel exclusive prefix SUM across 256 threads (wave shfl + LDS)
  double isum = tot;
  #pragma unroll
  for (int off = 1; off < 64; off <<= 1) {
    double o = __shfl_up(isum, off);
    if (lane >= off) isum += o;
  }
  if (lane == 63) wsumd[wv] = isum;
  __syncthreads();
  double based = 0.0;
  #pragma unroll
  for (int w = 0; w < 4; ++w) if (w < wv) based += wsumd[w];
  const double excl = based + isum - tot;

  float mtot = -3.4e38f;
  #pragma unroll
  for (int e = 0; e < 8; ++e) {
    cs[e] += excl;
    float ig = gpre[(size_t)h * 4096 + base + e] + ig_b;
    av[e] = (float)((double)ig - cs[e]);
    mtot = fmaxf(mtot, av[e]);
  }
  // per-64 and per-128 window maxima
  {
    float w8 = mtot;
    w8 = fmaxf(w8, __shfl_xor(w8, 1));
    w8 = fmaxf(w8, __shfl_xor(w8, 2));
    w8 = fmaxf(w8, __shfl_xor(w8, 4));
    if ((tid & 7) == 0) mt64[bh * 32 + (tid >> 3)] = w8;
    float w16 = fmaxf(w8, __shfl_xor(w8, 8));
    if ((tid & 15) == 0) { mt128[bh * 16 + (tid >> 4)] = w16; mt_l[tid >> 4] = w16; }
  }
  // parallel exclusive prefix MAX across 256 threads
  float prev = __shfl_up(mtot, 1);
  if (lane == 0) prev = -3.4e38f;
  float imax = prev;
  #pragma unroll
  for (int off = 1; off < 64; off <<= 1) {
    float o = __shfl_up(imax, off);
    if (lane >= off) imax = fmaxf(imax, o);
  }
  if (lane == 63) wmaxf[wv] = fmaxf(imax, mtot);   // inclusive wave max
  __syncthreads();
  float run = imax;
  #pragma unroll
  for (int w = 0; w < 4; ++w) if (w < wv) run = fmaxf(run, wmaxf[w]);

  if (tid == 0) {   // exclusive running max over 128-chunks (16 iters, trivial)
    float M = -3.4e38f;
    for (int c = 0; c < 16; ++c) { Mg_out[bh * 16 + c] = M; M = fmaxf(M, mt_l[c]); }
  }
  const int obase = bh * 2048 + tid * 8;
  #pragma unroll
  for (int e = 0; e < 8; ++e) {
    run = fmaxf(run, av[e]);
    a_out[obase + e] = av[e];
    ms_out[obase + e] = run;
    fl_out[obase + e] = __expf(-(float)(cs[e] + (double)run));  // exp(-max_log_D)
  }
}

// ---------------- Kernel P1: per-128-chunk state G[dv][dk] (fp16) + ksum ----
__global__ __launch_bounds__(512)
void p1_kernel(const float* __restrict__ k, const float* __restrict__ v,
               const float* __restrict__ a_g, const float* __restrict__ mt128,
               unsigned short* __restrict__ GXs, float* __restrict__ pkt) {
  __shared__ __align__(16) char pool[33280];
  _Float16* Kts = (_Float16*)pool;             // [128 dk][64 j] 128B rows, swz
  _Float16* Vts = (_Float16*)(pool + 16384);   // [128 dv][64 j]
  float* w_s = (float*)(pool + 32768);         // [128]
  const int c = blockIdx.x, bh = blockIdx.y;
  const int b = bh >> 3, h = bh & 7;
  const int tid = threadIdx.x;
  const int lane = tid & 63, wid = tid >> 6;
  const int l15 = lane & 15, lg = lane >> 4;
  if (tid < 128) w_s[tid] = __expf(a_g[bh * SLEN + c * 128 + tid] - mt128[bh * 16 + c]);
  const f32x4 z4 = {0.f, 0.f, 0.f, 0.f};
  f32x4 acc[8];
  #pragma unroll
  for (int i = 0; i < 8; ++i) acc[i] = z4;
  float ks_acc = 0.f;
  for (int p = 0; p < 2; ++p) {
    const int j0 = c * 128 + p * 64;
    __syncthreads();   // w_s ready (p=0); prior pass reads done (p=1)
    {
      const int d = tid & 127;
      const int jq = tid >> 7;                 // 0..3 (16 j each)
      const size_t rowb = (size_t)(b * SLEN + j0 + jq * 16) * DMODEL + h * DHEAD + d;
      float kv[16], vv[16];
      #pragma unroll
      for (int jj = 0; jj < 16; ++jj) {
        kv[jj] = k[rowb + (size_t)jj * DMODEL] * w_s[p * 64 + jq * 16 + jj];
        vv[jj] = v[rowb + (size_t)jj * DMODEL];
      }
      int ph[8], pv[8];
      #pragma unroll
      for (int pp = 0; pp < 8; ++pp) {
        ph[pp] = pk16(kv[2 * pp], kv[2 * pp + 1]);
        pv[pp] = pk16(vv[2 * pp], vv[2 * pp + 1]);
      }
      const int sw = (d & 7) << 4;
      const int b0 = d * 128 + jq * 32;
      *(f32x4*)((char*)Kts + ((b0 + 0) ^ sw))  = *(f32x4*)&ph[0];
      *(f32x4*)((char*)Kts + ((b0 + 16) ^ sw)) = *(f32x4*)&ph[4];
      *(f32x4*)((char*)Vts + ((b0 + 0) ^ sw))  = *(f32x4*)&pv[0];
      *(f32x4*)((char*)Vts + ((b0 + 16) ^ sw)) = *(f32x4*)&pv[4];
    }
    __syncthreads();
    f16x8 avv[2];
    {
      const int row = wid * 16 + l15;
      const int sw = (l15 & 7) << 4;
      avv[0] = *(const f16x8*)((char*)Vts + row * 128 + ((lg * 16) ^ sw));
      avv[1] = *(const f16x8*)((char*)Vts + row * 128 + ((64 + lg * 16) ^ sw));
    }
    #pragma unroll
    for (int dkt = 0; dkt < 8; ++dkt) {
      const int row = dkt * 16 + l15;
      const int sw = (l15 & 7) << 4;
      #pragma unroll
      for (int ks = 0; ks < 2; ++ks) {
        const int bc = ks * 64 + lg * 16;
        f16x8 bh8 = *(const f16x8*)((char*)Kts + row * 128 + (bc ^ sw));
        acc[dkt] = __builtin_amdgcn_mfma_f32_16x16x32_f16(avv[ks], bh8, acc[dkt], 0, 0, 0);
      }
    }
    if (tid < 128) {   // ksum partial over this pass's 64 j
      const int sw = (tid & 7) << 4;
      #pragma unroll
      for (int g = 0; g < 8; ++g) {
        f16x8 hh = *(const f16x8*)((char*)Kts + tid * 128 + ((g * 16) ^ sw));
        #pragma unroll
        for (int e = 0; e < 8; ++e) ks_acc += (float)hh[e];
      }
    }
  }
  unsigned short* gxs = GXs + (size_t)(bh * 16 + c) * 16384;
  #pragma unroll
  for (int dkt = 0; dkt < 8; ++dkt)
    #pragma unroll
    for (int r = 0; r < 4; ++r)
      gxs[(wid * 16 + lg * 4 + r) * 128 + dkt * 16 + l15] = f16bits(acc[dkt][r]);
  if (tid < 128) pkt[(size_t)(bh * 16 + c) * 128 + tid] = ks_acc;
}

// ---------------- Kernel P2: exclusive prefix states (R20: prefetched) ------
__global__ __launch_bounds__(256)
__attribute__((amdgpu_waves_per_eu(1, 4)))
void p2_kernel(const float* __restrict__ mt128, unsigned short* __restrict__ GXs,
               const float* __restrict__ pkt, float* __restrict__ pkx) {
  const int s = blockIdx.x, bh = blockIdx.y;
  const int tid = threadIdx.x;
  union U8 { uint4 q; _Float16 h[8]; };
  if (s < 8) {
    unsigned short* base = GXs + (size_t)bh * 16 * 16384 + s * 2048 + tid * 8;
    uint4 g[16];
    #pragma unroll
    for (int c = 0; c < 16; ++c)
      g[c] = *(const uint4*)(base + (size_t)c * 16384);
    float X[8];
    #pragma unroll
    for (int e = 0; e < 8; ++e) X[e] = 0.f;
    float Mm1 = -3.4e38f;
    #pragma unroll
    for (int c = 0; c < 16; ++c) {
      U8 cu; cu.q = g[c];
      const float mtc = mt128[bh * 16 + c];
      const float Mc = fmaxf(Mm1, mtc);
      const float s1 = __expf(Mm1 - Mc), s2 = __expf(mtc - Mc);
      U8 ou;
      #pragma unroll
      for (int e = 0; e < 8; ++e) ou.h[e] = (_Float16)X[e];
      *(uint4*)(base + (size_t)c * 16384) = ou.q;
      #pragma unroll
      for (int e = 0; e < 8; ++e) X[e] = X[e] * s1 + (float)cu.h[e] * s2;
      Mm1 = Mc;
    }
  } else if (tid < 128) {
    const float* pb = pkt + (size_t)bh * 16 * 128 + tid;
    float g[16];
    #pragma unroll
    for (int c = 0; c < 16; ++c) g[c] = pb[(size_t)c * 128];
    float X = 0.f, Mm1 = -3.4e38f;
    #pragma unroll
    for (int c = 0; c < 16; ++c) {
      const float mtc = mt128[bh * 16 + c];
      const float Mc = fmaxf(Mm1, mtc);
      pkx[(size_t)bh * 16 * 128 + (size_t)c * 128 + tid] = X;
      X = X * __expf(Mm1 - Mc) + g[c] * __expf(mtc - Mc);
      Mm1 = Mc;
    }
  }
}

// ---------------- Kernel P3: merged pair, single-barrier staging ------------
// R21: epilogue tt-parallel — each tt reduces into its own dead K/V buffer
// (pool + tt*49152), 4 barriers -> 2.
__global__ __launch_bounds__(1024)
__attribute__((amdgpu_waves_per_eu(4, 4)))
void p3_kernel(const float* __restrict__ q, const float* __restrict__ k,
               const float* __restrict__ v, const float* __restrict__ a_g,
               const float* __restrict__ ms_g, const float* __restrict__ fl_g,
               const float* __restrict__ Mg_g, const float* __restrict__ pkx,
               const unsigned short* __restrict__ GXs, float* __restrict__ out) {
  __shared__ __align__(16) char pool[133120];
  float* a_s0   = (float*)(pool + 131072);
  float* a_s1   = (float*)(pool + 131328);
  float* rs_lds = (float*)(pool + 131584);
  float* pks    = (float*)(pool + 132608);
  char* const Xb = pool + 98304;

  const int bid = blockIdx.x;
  const int c = bid & 15;
  const int bh = bid >> 4;
  const int b = bh >> 3, h = bh & 7;
  const int tid = threadIdx.x;
  const int lane = tid & 63;
  const int wid = tid >> 6;          // 0..15
  const int tt = wid >> 3;           // 0..1: tile t = 2c+tt
  const int wr = (wid >> 1) & 3;     // 16-row group
  const int wc = wid & 1;            // half split (j in A, dk in B)
  const int l15 = lane & 15;
  const int lg = lane >> 4;
  const int t = 2 * c + tt;
  const int i0 = t * BM;
  const f32x4 z4 = {0.f, 0.f, 0.f, 0.f};

  // ---- Q fragments (QSCALE folded, hi/lo split) ----
  f16x8 qh[4], ql[4];
  {
    const float* qbase = q + (size_t)(b * SLEN + i0 + wr * 16 + l15) * DMODEL + h * DHEAD;
    #pragma unroll
    for (int ks = 0; ks < 4; ++ks) {
      f32x4 x0 = *(const f32x4*)(qbase + ks * 32 + lg * 8);
      f32x4 x1 = *(const f32x4*)(qbase + ks * 32 + lg * 8 + 4);
      f16x8 hi, lo;
      #pragma unroll
      for (int e = 0; e < 4; ++e) {
        float s0 = x0[e] * QSCALE, s1 = x1[e] * QSCALE;
        _Float16 h0 = (_Float16)s0, h1 = (_Float16)s1;
        hi[e] = h0;     hi[e + 4] = h1;
        lo[e] = (_Float16)(s0 - (float)h0);
        lo[e + 4] = (_Float16)(s1 - (float)h1);
      }
      qh[ks] = hi; ql[ks] = lo;
    }
  }
  const float m_reg = ms_g[bh * SLEN + i0 + wr * 16 + l15];
  const float fl_reg = fl_g[bh * SLEN + i0 + wr * 16 + l15];
  const float e_l = __expf(Mg_g[bh * 16 + c] - m_reg);   // 0 at c==0

  f32x4 hacc[8];
  #pragma unroll
  for (int cf = 0; cf < 8; ++cf) hacc[cf] = z4;
  float ps = 0.f;

  // ======== stage EVERYTHING, then one barrier ========
  #pragma unroll
  for (int pss = 0; pss < 2; ++pss) {
    const int j0 = c * 128 + pss * 64;
    char* KB = pool + pss * 49152;
    {
      const int krow = tid >> 4;            // 0..63
      const int kc0 = (tid & 15) * 8;       // float col base
      const float* kp = k + (size_t)(b * SLEN + j0 + krow) * DMODEL + h * DHEAD + kc0;
      char* bh_ = KB + krow * 256;
      char* bl_ = KB + 16384 + krow * 256;
      const int sw = (krow & 7) << 4;
      #pragma unroll
      for (int e = 0; e < 2; ++e) {
        f32x4 xv = *(const f32x4*)(kp + e * 4);
        f16x4 hi, lo;
        #pragma unroll
        for (int u = 0; u < 4; ++u) {
          _Float16 hh = (_Float16)xv[u];
          hi[u] = hh; lo[u] = (_Float16)(xv[u] - (float)hh);
        }
        const int bc = (kc0 + e * 4) * 2;
        *(f16x4*)(bh_ + (bc ^ sw)) = hi;
        *(f16x4*)(bl_ + (bc ^ sw)) = lo;
      }
    }
    {
      const int d = tid & 127;
      const int jq = tid >> 7;              // 0..7 (8 j each)
      const float* vp = v + (size_t)(b * SLEN + j0 + jq * 8) * DMODEL + h * DHEAD + d;
      float vv[8];
      #pragma unroll
      for (int jj = 0; jj < 8; ++jj)
        vv[jj] = vp[(size_t)jj * DMODEL];
      int pv[4];
      #pragma unroll
      for (int p = 0; p < 4; ++p) pv[p] = pk16(vv[2 * p], vv[2 * p + 1]);
      const int sw = (d & 7) << 4;
      const int b0 = d * 128 + jq * 16;
      *(f32x4*)(KB + 32768 + (b0 ^ sw)) = *(f32x4*)&pv[0];
    }
  }
  if (tid < 64) a_s0[tid] = a_g[bh * SLEN + c * 128 + tid];
  else if (tid < 128) a_s1[tid - 64] = a_g[bh * SLEN + c * 128 + tid];
  else if (tid < 256) pks[tid - 128] = pkx[(size_t)(bh * 16 + c) * 128 + (tid - 128)];
  if (c > 0) {   // X -> LDS (swizzled; fused load+store)
    const char* gxs = (const char*)(GXs + (size_t)(bh * 16 + c) * 16384);
    const int xrow = tid >> 3;            // 0..127
    const int xcb = (tid & 7) * 32;       // byte col base
    const int sw = (xrow & 7) << 4;
    uint4 g0 = *(const uint4*)(gxs + xrow * 256 + xcb);
    uint4 g1 = *(const uint4*)(gxs + xrow * 256 + xcb + 16);
    *(uint4*)(Xb + xrow * 256 + ((xcb + 0) ^ sw)) = g0;
    *(uint4*)(Xb + xrow * 256 + ((xcb + 16) ^ sw)) = g1;
  }
  __syncthreads();

  // ---- Phase B (both tt): Q*e_l @ X (from LDS), + inter rowsum ----
  if (c > 0) {
    f16x8 qe[2];
    #pragma unroll
    for (int kss = 0; kss < 2; ++kss) {
      const int ks = wc * 2 + kss;
      #pragma unroll
      for (int e = 0; e < 8; ++e)
        qe[kss][e] = (_Float16)(((float)qh[ks][e] + (float)ql[ks][e]) * e_l);
    }
    #pragma unroll
    for (int cf = 0; cf < 8; ++cf) {
      const int row = cf * 16 + l15;
      const int sw = (row & 7) << 4;
      #pragma unroll
      for (int kss = 0; kss < 2; ++kss) {
        const int bc = (wc * 2 + kss) * 64 + lg * 16;
        f16x8 xh = *(const f16x8*)(Xb + row * 256 + (bc ^ sw));
        hacc[cf] = __builtin_amdgcn_mfma_f32_16x16x32_f16(qe[kss], xh, hacc[cf], 0, 0, 0);
      }
    }
    if (wc == 0) {   // inter rowsum partial: e_l * (q . pk_excl)
      float dot = 0.f;
      #pragma unroll
      for (int ks = 0; ks < 4; ++ks)
        #pragma unroll
        for (int e = 0; e < 8; ++e)
          dot += ((float)qh[ks][e] + (float)ql[ks][e]) * pks[ks * 32 + lg * 8 + e];
      ps += dot * e_l;
    }
  }

  // ---- Phase A: two sub-tiles, no barriers (distinct buffers) ----
  #pragma unroll
  for (int pss = 0; pss < 2; ++pss) {
    if (pss <= tt) {
      const int j0 = c * 128 + pss * 64;
      const char* KB = pool + pss * 49152;
      const float* a_s = (pss == 0) ? a_s0 : a_s1;
      f32x4 sacc[2];
      sacc[0] = z4; sacc[1] = z4;
      #pragma unroll
      for (int ks = 0; ks < 4; ++ks) {
        const int bc = ks * 64 + lg * 16;
        #pragma unroll
        for (int jfl = 0; jfl < 2; ++jfl) {
          const int arow = wc * 32 + jfl * 16 + l15;
          const int sw = (arow & 7) << 4;
          f16x8 kh8 = *(const f16x8*)(KB + arow * 256 + (bc ^ sw));
          f16x8 kl8 = *(const f16x8*)(KB + 16384 + arow * 256 + (bc ^ sw));
          sacc[jfl] = __builtin_amdgcn_mfma_f32_16x16x32_f16(kh8, qh[ks], sacc[jfl], 0, 0, 0);
          sacc[jfl] = __builtin_amdgcn_mfma_f32_16x16x32_f16(kl8, qh[ks], sacc[jfl], 0, 0, 0);
          sacc[jfl] = __builtin_amdgcn_mfma_f32_16x16x32_f16(kh8, ql[ks], sacc[jfl], 0, 0, 0);
        }
      }
      float vals[2][4];
      {
        const int iG = i0 + wr * 16 + l15;
        #pragma unroll
        for (int jfl = 0; jfl < 2; ++jfl)
          #pragma unroll
          for (int r = 0; r < 4; ++r) {
            const int jl = wc * 32 + jfl * 16 + lg * 4 + r;
            float e = __expf(fminf(a_s[jl] - m_reg, 0.f));
            float vv = sacc[jfl][r] * e;
            if (j0 + jl > iG) vv = 0.f;
            ps += vv;
            vals[jfl][r] = vv;
          }
      }
      const int lgand1 = lg & 1;
      const int idxA = (l15 + 16 * (2 * lgand1 + 0)) * 4;
      const int idxB = (l15 + 16 * (2 * lgand1 + 1)) * 4;
      const bool hi_half = ((lane & 63) >= 32);
      int c2[2][2];
      #pragma unroll
      for (int jfl = 0; jfl < 2; ++jfl) {
        c2[jfl][0] = pk16(vals[jfl][0], vals[jfl][1]);
        c2[jfl][1] = pk16(vals[jfl][2], vals[jfl][3]);
      }
      int pa32[4];
      #pragma unroll
      for (int p = 0; p < 4; ++p) {
        const int idx2 = (p < 2) ? idxA : idxB;
        int f0 = __builtin_amdgcn_ds_bpermute(idx2, c2[0][p & 1]);
        int f1 = __builtin_amdgcn_ds_bpermute(idx2, c2[1][p & 1]);
        pa32[p] = hi_half ? f1 : f0;
      }
      union { int i[4]; f16x8 v; } pu;
      pu.i[0] = pa32[0]; pu.i[1] = pa32[1]; pu.i[2] = pa32[2]; pu.i[3] = pa32[3];
      const f16x8 paf = pu.v;

      const int vbc = wc * 64 + lg * 16;
      #pragma unroll
      for (int cf = 0; cf < 8; ++cf) {
        const int vrow = cf * 16 + l15;
        const int sw = (vrow & 7) << 4;
        f16x8 vb8 = *(const f16x8*)(KB + 32768 + vrow * 128 + (vbc ^ sw));
        hacc[cf] = __builtin_amdgcn_mfma_f32_16x16x32_f16(paf, vb8, hacc[cf], 0, 0, 0);
      }
    }
  }
  __syncthreads();   // all LDS reads done before epilogue reuses pool

  // ====== Epilogue (R21: tt-parallel via disjoint dead K/V regions) ======
  ps += __shfl_xor(ps, 16);
  ps += __shfl_xor(ps, 32);
  if (lane < 16) rs_lds[(tt * 64 + wr * 16 + l15) * 2 + wc] = ps;
  float* hex_t = (float*)(pool + tt * 49152);   // 32KB used of each 48KB region
  if (wc == 1) {
    #pragma unroll
    for (int cf = 0; cf < 8; ++cf)
      *(f32x4*)&hex_t[wr * 2048 + cf * 256 + lane * 4] = hacc[cf];
  }
  __syncthreads();
  if (wc == 0) {
    #pragma unroll
    for (int cf = 0; cf < 8; ++cf) {
      f32x4 o = *(const f32x4*)&hex_t[wr * 2048 + cf * 256 + lane * 4];
      hacc[cf][0] += o[0]; hacc[cf][1] += o[1];
      hacc[cf][2] += o[2]; hacc[cf][3] += o[3];
    }
    const float rsum = rs_lds[(tt * 64 + wr * 16 + l15) * 2 + 0]
                     + rs_lds[(tt * 64 + wr * 16 + l15) * 2 + 1];
    const float inv = 1.0f / (fmaxf(fabsf(rsum), fl_reg) + 1e-6f);
    union { float f; int i; } uc; uc.f = inv;
    float invr[4];
    #pragma unroll
    for (int r = 0; r < 4; ++r) {
      union { float f; int i; } ur;
      ur.i = __builtin_amdgcn_ds_bpermute((lg * 4 + r) * 4, uc.i);
      invr[r] = ur.f;
    }
    #pragma unroll
    for (int r = 0; r < 4; ++r) {
      const size_t orow = (size_t)(b * SLEN + i0 + wr * 16 + lg * 4 + r) * DMODEL + h * DHEAD;
      #pragma unroll
      for (int cf = 0; cf < 8; ++cf)
        out[orow + cf * 16 + l15] = hacc[cf][r] * invr[r];
    }
  }
}

// ---------------- Fallback: R8 mlstm_main (verified, ws-light) --------------
__global__ __launch_bounds__(512)
void mlstm_main(const float* __restrict__ q, const float* __restrict__ k,
                const float* __restrict__ v, const float* __restrict__ a_g,
                const float* __restrict__ ms_g, const float* __restrict__ fl_g,
                const float* __restrict__ mt_g, float* __restrict__ out) {
  __shared__ __align__(16) char pool[50176];
  _Float16* Ks_hi = (_Float16*)pool;
  _Float16* Ks_lo = (_Float16*)(pool + 16384);
  _Float16* Vts   = (_Float16*)(pool + 32768);
  float* a_s      = (float*)(pool + 49152);
  float* rs_lds   = (float*)(pool + 49408);
  float* hex      = (float*)pool;

  const int bid = blockIdx.x;
  int t, bh;
  if (bid < 256) { t = 31 - (bid >> 4); bh = bid & 15; }
  else           { t = (bid - 256) >> 4; bh = (bid - 256) & 15; }
  const int b = bh >> 3, h = bh & 7;
  const int i0 = t * BM;
  const int tid = threadIdx.x;
  const int lane = tid & 63;
  const int wid = tid >> 6;
  const int wr = wid >> 1;
  const int wc = wid & 1;
  const int l15 = lane & 15;
  const int lg = lane >> 4;
  const f32x4 z4 = {0.f, 0.f, 0.f, 0.f};

  f16x8 qh[4], ql[4];
  {
    const float* qbase = q + (size_t)(b * SLEN + i0 + wr * 16 + l15) * DMODEL + h * DHEAD;
    #pragma unroll
    for (int ks = 0; ks < 4; ++ks) {
      f32x4 x0 = *(const f32x4*)(qbase + ks * 32 + lg * 8);
      f32x4 x1 = *(const f32x4*)(qbase + ks * 32 + lg * 8 + 4);
      f16x8 hi, lo;
      #pragma unroll
      for (int e = 0; e < 4; ++e) {
        float s0 = x0[e] * QSCALE, s1 = x1[e] * QSCALE;
        _Float16 h0 = (_Float16)s0, h1 = (_Float16)s1;
        hi[e] = h0;     hi[e + 4] = h1;
        lo[e] = (_Float16)(s0 - (float)h0);
        lo[e + 4] = (_Float16)(s1 - (float)h1);
      }
      qh[ks] = hi; ql[ks] = lo;
    }
  }
  const float m_reg = ms_g[bh * SLEN + i0 + wr * 16 + l15];
  const float fl_reg = fl_g[bh * SLEN + i0 + wr * 16 + l15];
  const int lgand1 = lg & 1;
  const int idxA = (l15 + 16 * (2 * lgand1 + 0)) * 4;
  const int idxB = (l15 + 16 * (2 * lgand1 + 1)) * 4;
  const bool hi_half = (lane >= 32);

  f32x4 hacc[8];
  #pragma unroll
  for (int cf = 0; cf < 8; ++cf) hacc[cf] = z4;
  float ps = 0.f;

  const int krow = tid >> 3;
  const int kc0 = (tid & 7) * 16;
  const int vdv = tid & 127;
  const int vjq = tid >> 7;

  for (int jt = 0; jt <= t; ++jt) {
    const int j0 = jt * BKT;
    const bool diag = (jt == t);
    const float mt = mt_g[bh * 32 + jt];
    {
      float es = 1.f;
      if (!diag) es = __expf(a_g[bh * SLEN + j0 + krow] - mt);
      const float* kp = k + (size_t)(b * SLEN + j0 + krow) * DMODEL + h * DHEAD + kc0;
      char* bh_ = (char*)Ks_hi + krow * 256;
      char* bl_ = (char*)Ks_lo + krow * 256;
      const int sw = (krow & 7) << 4;
      #pragma unroll
      for (int e = 0; e < 4; ++e) {
        f32x4 xv = *(const f32x4*)(kp + e * 4);
        f16x4 hi, lo;
        #pragma unroll
        for (int u = 0; u < 4; ++u) {
          float vv = xv[u] * es;
          _Float16 hh = (_Float16)vv;
          hi[u] = hh; lo[u] = (_Float16)(vv - (float)hh);
        }
        const int bc = (kc0 + e * 4) * 2;
        *(f16x4*)(bh_ + (bc ^ sw)) = hi;
        *(f16x4*)(bl_ + (bc ^ sw)) = lo;
      }
    }
    {
      const float* vp = v + (size_t)(b * SLEN + j0 + vjq * 16) * DMODEL + h * DHEAD + vdv;
      float vv[16];
      #pragma unroll
      for (int jj = 0; jj < 16; ++jj)
        vv[jj] = vp[(size_t)jj * DMODEL];
      int pk[8];
      #pragma unroll
      for (int p = 0; p < 8; ++p) pk[p] = pk16(vv[2 * p], vv[2 * p + 1]);
      const int sw = (vdv & 7) << 4;
      *(f32x4*)((char*)Vts + ((vdv * 128 + vjq * 32 + 0) ^ sw)) = *(f32x4*)&pk[0];
      *(f32x4*)((char*)Vts + ((vdv * 128 + vjq * 32 + 16) ^ sw)) = *(f32x4*)&pk[4];
    }
    if (diag && tid < BKT) a_s[tid] = a_g[bh * SLEN + j0 + tid];
    __syncthreads();

    f32x4 sacc[2];
    sacc[0] = z4; sacc[1] = z4;
    #pragma unroll
    for (int ks = 0; ks < 4; ++ks) {
      const int bc = ks * 64 + lg * 16;
      #pragma unroll
      for (int jfl = 0; jfl < 2; ++jfl) {
        const int arow = wc * 32 + jfl * 16 + l15;
        const int sw = (arow & 7) << 4;
        f16x8 kh8 = *(const f16x8*)((char*)Ks_hi + arow * 256 + (bc ^ sw));
        f16x8 kl8 = *(const f16x8*)((char*)Ks_lo + arow * 256 + (bc ^ sw));
        sacc[jfl] = __builtin_amdgcn_mfma_f32_16x16x32_f16(kh8, qh[ks], sacc[jfl], 0, 0, 0);
        sacc[jfl] = __builtin_amdgcn_mfma_f32_16x16x32_f16(kl8, qh[ks], sacc[jfl], 0, 0, 0);
        sacc[jfl] = __builtin_amdgcn_mfma_f32_16x16x32_f16(kh8, ql[ks], sacc[jfl], 0, 0, 0);
      }
    }
    float vals[2][4];
    if (diag) {
      const int iG = i0 + wr * 16 + l15;
      #pragma unroll
      for (int jfl = 0; jfl < 2; ++jfl)
        #pragma unroll
        for (int r = 0; r < 4; ++r) {
          const int jl = wc * 32 + jfl * 16 + lg * 4 + r;
          float e = __expf(fminf(a_s[jl] - m_reg, 0.f));
          float vv = sacc[jfl][r] * e;
          if (j0 + jl > iG) vv = 0.f;
          vals[jfl][r] = vv;
        }
    } else {
      const float em = __expf(fminf(mt - m_reg, 0.f));
      #pragma unroll
      for (int jfl = 0; jfl < 2; ++jfl)
        #pragma unroll
        for (int r = 0; r < 4; ++r)
          vals[jfl][r] = sacc[jfl][r] * em;
    }
    #pragma unroll
    for (int jfl = 0; jfl < 2; ++jfl)
      #pragma unroll
      for (int r = 0; r < 4; ++r) ps += vals[jfl][r];

    int c2[2][2];
    #pragma unroll
    for (int jfl = 0; jfl < 2; ++jfl) {
      c2[jfl][0] = pk16(vals[jfl][0], vals[jfl][1]);
      c2[jfl][1] = pk16(vals[jfl][2], vals[jfl][3]);
    }
    int pa32[4];
    #pragma unroll
    for (int p = 0; p < 4; ++p) {
      const int idx = (p < 2) ? idxA : idxB;
      int f0 = __builtin_amdgcn_ds_bpermute(idx, c2[0][p & 1]);
      int f1 = __builtin_amdgcn_ds_bpermute(idx, c2[1][p & 1]);
      pa32[p] = hi_half ? f1 : f0;
    }
    union { int i[4]; f16x8 v; } pu;
    pu.i[0] = pa32[0]; pu.i[1] = pa32[1]; pu.i[2] = pa32[2]; pu.i[3] = pa32[3];
    const f16x8 paf = pu.v;

    const int vbc = wc * 64 + lg * 16;
    #pragma unroll
    for (int cf = 0; cf < 8; ++cf) {
      const int vrow = cf * 16 + l15;
      const int sw = (vrow & 7) << 4;
      f16x8 vb8 = *(const f16x8*)((char*)Vts + vrow * 128 + (vbc ^ sw));
      hacc[cf] = __builtin_amdgcn_mfma_f32_16x16x32_f16(paf, vb8, hacc[cf], 0, 0, 0);
    }
    __syncthreads();
  }

  ps += __shfl_xor(ps, 16);
  ps += __shfl_xor(ps, 32);
  if (lane < 16) rs_lds[(wr * 16 + l15) * 2 + wc] = ps;
  if (wc == 1) {
    #pragma unroll
    for (int cf = 0; cf < 8; ++cf)
      *(f32x4*)&hex[wr * 2048 + cf * 256 + lane * 4] = hacc[cf];
  }
  __syncthreads();
  if (wc == 0) {
    #pragma unroll
    for (int cf = 0; cf < 8; ++cf) {
      f32x4 o = *(const f32x4*)&hex[wr * 2048 + cf * 256 + lane * 4];
      hacc[cf][0] += o[0]; hacc[cf][1] += o[1];
      hacc[cf][2] += o[2]; hacc[cf][3] += o[3];
    }
    const float rsum = rs_lds[(wr * 16 + l15) * 2 + 0] + rs_lds[(wr * 16 + l15) * 2 + 1];
    const float inv = 1.0f / (fmaxf(fabsf(rsum), fl_reg) + 1e-6f);
    union { float f; int i; } uc; uc.f = inv;
    float invr[4];
    #pragma unroll
    for (int r = 0; r < 4; ++r) {
      union { float f; int i; } ur;
      ur.i = __builtin_amdgcn_ds_bpermute((lg * 4 + r) * 4, uc.i);
      invr[r] = ur.f;
    }
    #pragma unroll
    for (int r = 0; r < 4; ++r) {
      const size_t orow = (size_t)(b * SLEN + i0 + wr * 16 + lg * 4 + r) * DMODEL + h * DHEAD;
      #pragma unroll
      for (int cf = 0; cf < 8; ++cf)
        out[orow + cf * 16 + l15] = hacc[cf][r] * invr[r];
    }
  }
}

// ---------------- Kernel 4: in-place LayerNorm on d_out ---------------------
__global__ __launch_bounds__(256)
void ln_kernel(float* __restrict__ out, const float* __restrict__ gamma) {
  const int row = blockIdx.x;
  const int tid = threadIdx.x;
  float* x = out + (size_t)row * DMODEL;
  f32x4 xv = ((const f32x4*)x)[tid];
  float s = xv[0] + xv[1] + xv[2] + xv[3];
  float qq = xv[0] * xv[0] + xv[1] * xv[1] + xv[2] * xv[2] + xv[3] * xv[3];
  #pragma unroll
  for (int m = 1; m < 64; m <<= 1) { s += __shfl_xor(s, m); qq += __shfl_xor(qq, m); }
  __shared__ float ss[4], sq[4];
  const int wid = tid >> 6;
  if ((tid & 63) == 0) { ss[wid] = s; sq[wid] = qq; }
  __syncthreads();
  s = ss[0] + ss[1] + ss[2] + ss[3];
  qq = sq[0] + sq[1] + sq[2] + sq[3];
  const float mu = s * (1.f / 1024.f);
  const float var = qq * (1.f / 1024.f) - mu * mu;
  const float rstd = rsqrtf(var + 1e-5f);
  f32x4 g = ((const f32x4*)gamma)[tid];
  f32x4 ov;
  ov[0] = (xv[0] - mu) * rstd * g[0];
  ov[1] = (xv[1] - mu) * rstd * g[1];
  ov[2] = (xv[2] - mu) * rstd * g[2];
  ov[3] = (xv[3] - mu) * rstd * g[3];
  ((f32x4*)x)[tid] = ov;
}

extern "C" void kernel_launch(void* const* d_in, const int* in_sizes, int n_in,
                              void* d_out, int out_size, void* d_ws, size_t ws_size,
                              hipStream_t stream) {
  (void)in_sizes; (void)n_in; (void)out_size;
  const float* q   = (const float*)d_in[0];
  const float* k   = (const float*)d_in[1];
  const float* v   = (const float*)d_in[2];
  const float* igw = (const float*)d_in[3];
  const float* igb = (const float*)d_in[4];
  const float* fgw = (const float*)d_in[5];
  const float* fgb = (const float*)d_in[6];
  const float* lns = (const float*)d_in[7];
  float* out = (float*)d_out;

  float* gpre  = (float*)d_ws;           // 65536 f32
  float* a_g   = gpre + 65536;           // 32768
  float* ms_g  = a_g + 32768;            // 32768
  float* fl_g  = ms_g + 32768;           // 32768
  float* mt64  = fl_g + 32768;           // 512   (16 x 32)
  float* mt128 = mt64 + 512;             // 256   (16 x 16)
  float* Mg_g  = mt128 + 256;            // 256
  float* pkt   = Mg_g + 256;             // 32768 (256 x 128)
  float* pkx   = pkt + 32768;            // 32768
  unsigned short* GXs = (unsigned short*)(pkx + 32768);  // 256 x 16384 fp16 = 8MB
  // total ≈ 9.31 MB

  const bool big = ws_size >= (size_t)10 * 1024 * 1024;

  gates_kernel<<<dim3(256), dim3(512), 0, stream>>>(q, k, v, igw, fgw, gpre);
  scan_kernel<<<dim3(16), dim3(256), 0, stream>>>(gpre, igb, fgb, a_g, ms_g, fl_g,
                                                  mt64, mt128, Mg_g);
  if (big) {
    p1_kernel<<<dim3(16, 16), dim3(512), 0, stream>>>(k, v, a_g, mt128, GXs, pkt);
    p2_kernel<<<dim3(9, 16), dim3(256), 0, stream>>>(mt128, GXs, pkt, pkx);
    p3_kernel<<<dim3(256), dim3(1024), 0, stream>>>(q, k, v, a_g, ms_g, fl_g,
                                                    Mg_g, pkx, GXs, out);
  } else {
    mlstm_main<<<dim3(512), dim3(512), 0, stream>>>(q, k, v, a_g, ms_g, fl_g, mt64, out);
  }
  ln_kernel<<<dim3(4096), dim3(256), 0, stream>>>(out, lns);
}